// Round 2
// baseline (1531.312 us; speedup 1.0000x reference)
//
#include <hip/hip_runtime.h>
#include <stdint.h>

typedef unsigned int u32;
typedef unsigned short u16;
typedef __attribute__((ext_vector_type(8))) short short8;
typedef __attribute__((ext_vector_type(4))) float f32x4;

#define N_NODESC 30522
#define HIDC 768
#define NEC 488352
#define TOKM 2048
#define LLAY 12
#define NCLS 101
#define M_PAD 30720     // 120*256
#define ZNC (LLAY*HIDC) // 9216
#define OUT_SET (LLAY*4*513*HIDC)
#define PN_KCHUNK 512
#define NBLK 120
#define NN1 (N_NODESC+1)
#define G8_LDS 131072

// slab-partitioned SpMM geometry (column slabs of 128, XCD-affine)
#define SP_NB   7631          // ceil(30522/4) node-blocks
#define SP_MAIN 5723          // node-blocks handled by the slab's primary XCD
#define SP_HELP 1908          // remainder handled by helper XCDs 6/7
#define SP_J    5724          // 3*SP_HELP  (per-XCD block budget)
#define SP_GRID (8*SP_J)      // 45792

// ---------- helpers ----------
__device__ __forceinline__ float bl(u32 u){ return __uint_as_float(u<<16); }
__device__ __forceinline__ float bh(u32 u){ return __uint_as_float(u & 0xffff0000u); }
__device__ __forceinline__ u32 f2b1(float f){ u32 x=__float_as_uint(f); return (x + 0x7fffu + ((x>>16)&1u))>>16; }
__device__ __forceinline__ u32 pack2(float a, float b){ return f2b1(a) | (f2b1(b)<<16); }

__device__ __forceinline__ void mfma16(f32x4& d, short8 a, short8 b){
  asm volatile("v_mfma_f32_16x16x32_bf16 %0, %1, %2, %0" : "+v"(d) : "v"(a), "v"(b));
}
__device__ __forceinline__ void async16(const void* g, void* l){
  __builtin_amdgcn_global_load_lds((const __attribute__((address_space(1))) u32*)g,
                                   (__attribute__((address_space(3))) u32*)l, 16, 0, 0);
}
__device__ __forceinline__ void em_dec(double d, int& s, float& w){
  unsigned long long b = __double_as_longlong(d);
  s = (int)(u32)b;
  w = __uint_as_float((u32)(b>>32));
}

// ---------- mask normalize ----------
__global__ void k_invmask(const void* __restrict__ mask, float* __restrict__ invm){
  __shared__ int s_byte, s_flt;
  int t = threadIdx.x;
  const unsigned char* mb = (const unsigned char*)mask;
  const u32* mw = (const u32*)mask;
  int lb=0, lf=0;
  for(int i=t;i<2048;i+=256) if((i&3)!=0 && mb[i]!=0) lb=1;
  for(int i=t;i<512;i+=256) if(mw[i]==0x3F800000u) lf=1;
  if(t==0){ s_byte=0; s_flt=0; }
  __syncthreads();
  if(lb) s_byte=1;
  if(lf) s_flt=1;
  __syncthreads();
  int mode = s_flt ? 2 : (s_byte ? 1 : 0);
  for(int p=t;p<2048;p+=256){
    int mv = (mode==1) ? (int)mb[p] : (int)(mw[p]!=0u);
    invm[p] = mv ? 0.f : 1.f;
  }
}

__global__ void k_needed(const int* __restrict__ ids, u32* __restrict__ needed){
  int p = blockIdx.x*256 + threadIdx.x;
  if(p < TOKM){ int id = ids[p]; if(id < N_NODESC) needed[id] = 1u; }
}

// ---------- converts ----------
__global__ void k_conv(const float* __restrict__ src, u16* __restrict__ dst, int ndw){
  int i = blockIdx.x*256 + threadIdx.x;
  if(i < ndw) ((u32*)dst)[i] = pack2(src[2*i], src[2*i+1]);
}
__global__ void k_conv_pad(const float* __restrict__ src, u16* __restrict__ dst, int srcRows, int padRows){
  int i = blockIdx.x*256 + threadIdx.x;
  if(i >= padRows*384) return;
  int row = i/384; int c2 = (i - row*384)*2;
  float lo=0.f, hi=0.f;
  if(row < srcRows){ const float* s = src + (size_t)row*HIDC + c2; lo=s[0]; hi=s[1]; }
  ((u32*)dst)[i] = pack2(lo, hi);
}
__global__ void k_pnb(const float* __restrict__ png, u16* __restrict__ pnb){
  int i = blockIdx.x*256 + threadIdx.x;
  if(i >= 128*(M_PAD/2)) return;
  int row = i/(M_PAD/2); int k2 = (i - row*(M_PAD/2))*2;
  float lo=0.f, hi=0.f;
  if(row < NCLS){
    const float* s = png + (size_t)row*N_NODESC;
    if(k2 < N_NODESC) lo = s[k2];
    if(k2+1 < N_NODESC) hi = s[k2+1];
  }
  ((u32*)pnb)[i] = pack2(lo, hi);
}
__global__ void k_transposeW2(const float* __restrict__ coW, const float* __restrict__ reW,
                              u16* __restrict__ Wt2){
  int g = blockIdx.y;
  int i = blockIdx.x*256 + threadIdx.x;
  if(i >= 3*HIDC*384) return;
  const float* W = g ? reW : coW;
  int mat = i/(HIDC*384); int rem = i - mat*HIDC*384;
  int n = rem/384; int kd = rem - n*384;
  const float* Wm = W + (size_t)mat*HIDC*HIDC;
  float lo = Wm[(size_t)(2*kd)*HIDC + n];
  float hi = Wm[(size_t)(2*kd+1)*HIDC + n];
  ((u32*)Wt2)[(size_t)g*3*HIDC*384 + (size_t)mat*HIDC*384 + (size_t)n*384 + kd] = pack2(lo, hi);
}

// ---------- batched graph prep ----------
__global__ void k_degcnt2(const int* __restrict__ coei, const int* __restrict__ reei,
                          const float* __restrict__ coew, const float* __restrict__ reew,
                          float* __restrict__ deg2, int* __restrict__ cnt2){
  int g = blockIdx.y;
  const int* ei = g ? reei : coei;
  const float* ew = g ? reew : coew;
  int e = blockIdx.x*256 + threadIdx.x;
  if(e < NEC){ int d = ei[NEC+e]; atomicAdd(&deg2[(size_t)g*N_NODESC + d], ew[e]); atomicAdd(&cnt2[(size_t)g*N_NODESC + d], 1); }
}
__global__ void k_dinv2(const float* __restrict__ deg2, float* __restrict__ dinvA, float* __restrict__ dinvB){
  int g = blockIdx.y;
  int v = blockIdx.x*256 + threadIdx.x;
  if(v < N_NODESC){
    float d = deg2[(size_t)g*N_NODESC + v] + 1.f;
    dinvA[(size_t)g*N_NODESC + v] = rsqrtf(d);
    dinvB[(size_t)g*N_NODESC + v] = 1.f/d;
  }
}
__global__ void k_scan1(const int* __restrict__ cnt2, int* __restrict__ part2){
  __shared__ int wt[4];
  int g = blockIdx.y, b = blockIdx.x, t = threadIdx.x;
  int lane = t & 63, w = t >> 6;
  int i = b*256 + t;
  int v = (i < N_NODESC) ? cnt2[(size_t)g*N_NODESC + i] : 0;
  int x = v;
  #pragma unroll
  for(int off=1; off<64; off<<=1){ int y = __shfl_up(x, off); if(lane>=off) x += y; }
  if(lane==63) wt[w] = x;
  __syncthreads();
  if(t==0) part2[g*NBLK + b] = wt[0]+wt[1]+wt[2]+wt[3];
}
__global__ void k_scan2(int* __restrict__ part2, int* __restrict__ rp2){
  __shared__ int w0tot;
  int g = blockIdx.x, t = threadIdx.x;   // 128 threads
  int lane = t & 63, w = t >> 6;
  int v = (t < NBLK) ? part2[g*NBLK + t] : 0;
  int x = v;
  #pragma unroll
  for(int off=1; off<64; off<<=1){ int y = __shfl_up(x, off); if(lane>=off) x += y; }
  if(w==0 && lane==63) w0tot = x;
  __syncthreads();
  int incl = x + (w ? w0tot : 0);
  int excl = incl - v;
  if(t < NBLK) part2[g*NBLK + t] = excl;
  if(t == 127) rp2[(size_t)g*NN1 + N_NODESC] = incl;
}
__global__ void k_scan3(const int* __restrict__ cnt2, const int* __restrict__ part2,
                        int* __restrict__ rp2, int* __restrict__ cur2){
  __shared__ int wt[4];
  int g = blockIdx.y, b = blockIdx.x, t = threadIdx.x;
  int lane = t & 63, w = t >> 6;
  int i = b*256 + t;
  int v = (i < N_NODESC) ? cnt2[(size_t)g*N_NODESC + i] : 0;
  int x = v;
  #pragma unroll
  for(int off=1; off<64; off<<=1){ int y = __shfl_up(x, off); if(lane>=off) x += y; }
  if(lane==63) wt[w] = x;
  __syncthreads();
  int wpre = 0;
  #pragma unroll
  for(int j=0;j<4;j++) if(j<w) wpre += wt[j];
  int excl = x - v + wpre + part2[g*NBLK + b];
  if(i < N_NODESC){ rp2[(size_t)g*NN1 + i] = excl; cur2[(size_t)g*N_NODESC + i] = excl; }
}
__global__ void k_scatter2(const int* __restrict__ coei, const int* __restrict__ reei,
                           const float* __restrict__ coew, const float* __restrict__ reew,
                           const float* __restrict__ dinvA, int* __restrict__ cur2,
                           float2* __restrict__ emeta){
  int g = blockIdx.y;
  const int* ei = g ? reei : coei;
  const float* ew = g ? reew : coew;
  int e = blockIdx.x*256 + threadIdx.x;
  if(e < NEC){
    int s = ei[e], d = ei[NEC+e];
    int pos = atomicAdd(&cur2[(size_t)g*N_NODESC + d], 1);
    float nrm = dinvA[(size_t)g*N_NODESC + s]*ew[e]*dinvA[(size_t)g*N_NODESC + d];
    emeta[(size_t)g*NEC + pos] = make_float2(__int_as_float(s), nrm);
  }
}

// ---------- SpMM (full-row variant, used for NEED-filtered last layer) ----------
__global__ __launch_bounds__(256)
void k_spmm(const u16* __restrict__ hW, const int* __restrict__ rp,
            const float2* __restrict__ emeta, const float* __restrict__ dinv2,
            const float* __restrict__ bias, u16* __restrict__ hout,
            const u32* __restrict__ needed){
  int v = blockIdx.x*4 + (threadIdx.x>>6);
  if(v >= N_NODESC) return;
  if(needed && !needed[v]) return;
  int lane = threadIdx.x & 63;
  const u32* H = (const u32*)hW;
  float acc[12];
  #pragma unroll
  for(int q=0;q<12;q++) acc[q]=0.f;
  int e0 = rp[v], e1 = rp[v+1];
  int e = e0;
  for(; e+4<=e1; e+=4){
    float2 m0=emeta[e], m1=emeta[e+1], m2=emeta[e+2], m3=emeta[e+3];
    const u32* r0 = H + (size_t)__float_as_int(m0.x)*384 + lane;
    const u32* r1 = H + (size_t)__float_as_int(m1.x)*384 + lane;
    const u32* r2 = H + (size_t)__float_as_int(m2.x)*384 + lane;
    const u32* r3 = H + (size_t)__float_as_int(m3.x)*384 + lane;
    u32 u0[6],u1[6],u2[6],u3[6];
    #pragma unroll
    for(int q=0;q<6;q++){ u0[q]=r0[q*64]; u1[q]=r1[q*64]; u2[q]=r2[q*64]; u3[q]=r3[q*64]; }
    #pragma unroll
    for(int q=0;q<6;q++){
      acc[2*q]   += m0.y*bl(u0[q]) + m1.y*bl(u1[q]) + m2.y*bl(u2[q]) + m3.y*bl(u3[q]);
      acc[2*q+1] += m0.y*bh(u0[q]) + m1.y*bh(u1[q]) + m2.y*bh(u2[q]) + m3.y*bh(u3[q]);
    }
  }
  for(; e<e1; ++e){
    float2 mm = emeta[e];
    const u32* r = H + (size_t)__float_as_int(mm.x)*384 + lane;
    #pragma unroll
    for(int q=0;q<6;q++){ u32 u = r[q*64]; acc[2*q] += mm.y*bl(u); acc[2*q+1] += mm.y*bh(u); }
  }
  { float wgt = dinv2[v];
    const u32* r = H + (size_t)v*384 + lane;
    #pragma unroll
    for(int q=0;q<6;q++){ u32 u = r[q*64]; acc[2*q] += wgt*bl(u); acc[2*q+1] += wgt*bh(u); }
  }
  const float2* B2 = (const float2*)bias;
  u32* O = (u32*)hout + (size_t)v*384 + lane;
  #pragma unroll
  for(int q=0;q<6;q++){
    float2 bb = B2[lane + 64*q];
    float x0 = fmaxf(acc[2*q]+bb.x, 0.f);
    float x1 = fmaxf(acc[2*q+1]+bb.y, 0.f);
    O[q*64] = pack2(x0, x1);
  }
}

// ---------- SpMM, column-slab partitioned with XCD affinity ----------
// 6 slabs of 128 cols (one 256B wave-coalesced segment each). bid%8 -> XCD
// (round-robin heuristic, same mapping the T1 swizzle relies on):
//   xcd s<6 : slab s, node-blocks [0, SP_MAIN)
//   xcd 6   : slabs 0..2, node-blocks [SP_MAIN, SP_NB)  (1908 each, sequential phases)
//   xcd 7   : slabs 3..5, same
// Per-XCD working set = 30720 rows x 256 B = 7.9 MB (vs 47 MB unpartitioned).
// emeta/rp streamed nontemporal so they don't evict the H slab; output stores
// nontemporal (full 256B lines, no partial-line hazards).
// FP order matches k_spmm exactly (4-term groups, singles tail, self-loop,
// bias, relu) -> bit-identical output.
__global__ __launch_bounds__(256)
void k_spmm_slab(const u16* __restrict__ hW, const int* __restrict__ rp,
                 const float2* __restrict__ emeta, const float* __restrict__ dinv2,
                 const float* __restrict__ bias, u16* __restrict__ hout){
  int bid = (int)blockIdx.x;
  int xcd = bid & 7, j = bid >> 3;
  int q, nb;
  if(xcd < 6){
    if(j >= SP_MAIN) return;
    q = xcd; nb = j;
  } else {
    int s3 = j / SP_HELP;               // 0..2
    if(s3 > 2) return;
    q = (xcd==6) ? s3 : 3+s3;
    nb = SP_MAIN + (j - s3*SP_HELP);
    if(nb >= SP_NB) return;
  }
  int v = nb*4 + (threadIdx.x>>6);
  if(v >= N_NODESC) return;
  int lane = threadIdx.x & 63;
  const u32* Hq = (const u32*)hW + q*64 + lane;
  const double* em8 = (const double*)emeta;
  float a0 = 0.f, a1 = 0.f;
  int e0 = rp[v], e1 = rp[v+1];
  int e = e0;
  for(; e+4<=e1; e+=4){
    int s0,s1,s2,s3; float w0,w1,w2,w3;
    em_dec(__builtin_nontemporal_load(em8+e  ), s0, w0);
    em_dec(__builtin_nontemporal_load(em8+e+1), s1, w1);
    em_dec(__builtin_nontemporal_load(em8+e+2), s2, w2);
    em_dec(__builtin_nontemporal_load(em8+e+3), s3, w3);
    u32 u0 = Hq[(size_t)s0*384];
    u32 u1 = Hq[(size_t)s1*384];
    u32 u2 = Hq[(size_t)s2*384];
    u32 u3 = Hq[(size_t)s3*384];
    a0 += w0*bl(u0) + w1*bl(u1) + w2*bl(u2) + w3*bl(u3);
    a1 += w0*bh(u0) + w1*bh(u1) + w2*bh(u2) + w3*bh(u3);
  }
  for(; e<e1; ++e){
    int ss; float ww;
    em_dec(__builtin_nontemporal_load(em8+e), ss, ww);
    u32 u = Hq[(size_t)ss*384];
    a0 += ww*bl(u); a1 += ww*bh(u);
  }
  { u32 u = Hq[(size_t)v*384];
    float wgt = dinv2[v];
    a0 += wgt*bl(u); a1 += wgt*bh(u); }
  float2 bb = ((const float2*)bias)[q*64 + lane];
  float x0 = fmaxf(a0+bb.x, 0.f);
  float x1 = fmaxf(a1+bb.y, 0.f);
  __builtin_nontemporal_store(pack2(x0,x1), (u32*)hout + (size_t)v*384 + q*64 + lane);
}

// ---------- token gather ----------
__global__ void k_gather(const u16* __restrict__ h, const int* __restrict__ ids,
                         float2* __restrict__ tokf, u16* __restrict__ tokb, int phase){
  int d = blockIdx.x*256 + threadIdx.x;
  if(d >= TOKM*384) return;
  int p = d/384, q = d - p*384;
  int id = ids[p];
  float x0=0.f, x1=0.f;
  if(id < N_NODESC){ u32 u = ((const u32*)h)[(size_t)id*384 + q]; x0 = bl(u)*(1.f/3.f); x1 = bh(u)*(1.f/3.f); }
  float2 cur;
  if(phase==0){ cur.x=x0; cur.y=x1; }
  else { cur = tokf[d]; cur.x += x0; cur.y += x1; }
  if(phase==2) ((u32*)tokb)[d] = pack2(cur.x, cur.y);
  else tokf[d] = cur;
}

__global__ void k_gather_pn(const float* __restrict__ GT, const int* __restrict__ cids, u16* __restrict__ tokb){
  int d = blockIdx.x*256 + threadIdx.x;
  if(d >= TOKM*384) return;
  int p = d/384, q = d - p*384;
  int cid = cids[p];
  float lo = GT[(size_t)(2*q)*128 + cid];
  float hi = GT[(size_t)(2*q+1)*128 + cid];
  ((u32*)tokb)[d] = pack2(lo, hi);
}

__global__ void k_zerocol(float* __restrict__ out){
  int i = blockIdx.x*256 + threadIdx.x;
  if(i >= 3*LLAY*4*HIDC) return;
  int set = i/(LLAY*4*HIDC); int rem = i - set*(LLAY*4*HIDC);
  int l = rem/(4*HIDC); int rem2 = rem - l*(4*HIDC);
  int b = rem2/HIDC; int o = rem2 - b*HIDC;
  out[(size_t)set*OUT_SET + (size_t)(l*4+b)*513*HIDC + o] = 0.f;
}

// ================= 8-phase 256x256 GEMM core =================
// LDS map (bytes): A buf b: b*65536 + half*16384 ; B buf b: b*65536+32768 + half*16384
// swizzle: byte ^= ((row&7)<<4)  -> staged via pre-swizzled global source (involution)
#define G8_AOFF(b) ((b)*65536)
#define G8_BOFF(b) ((b)*65536 + 32768)

__device__ __forceinline__ void g8_stage(const u16* __restrict__ src, int ldk, int g0, int kt,
                                         char* half_base, int tid){
  const int lane = tid & 63;
  const int csw = ((lane&7) ^ (lane>>3)) << 3;   // pre-swizzled source col (elements)
  const u16* s0 = src + (size_t)(g0 + (tid>>3))*ldk + (kt + csw);
  const u16* s1 = src + (size_t)(g0 + 64 + (tid>>3))*ldk + (kt + csw);
  async16(s0, half_base + (size_t)tid*16);
  async16(s1, half_base + 8192 + (size_t)tid*16);
}

__device__ __forceinline__ void g8_core(const u16* __restrict__ A, const u16* __restrict__ Bt,
                                        int K, int m0, int n0,
                                        f32x4 (&acc)[8][4], char* LDS, int tid){
  const int lane = tid & 63;
  const int wid = tid >> 6;
  const int wr = wid >> 2, wc = wid & 3;
  const int NK = K >> 6;   // K-tiles (BK=64); requires NK>=3, even

  // prologue: B(0)h0,h1 A(0)h0,h1 B(1)h0,h1 ; vmcnt(4) ; barrier
  g8_stage(Bt, K, n0,      0, LDS + G8_BOFF(0),         tid);
  g8_stage(Bt, K, n0+128,  0, LDS + G8_BOFF(0) + 16384, tid);
  g8_stage(A,  K, m0,      0, LDS + G8_AOFF(0),         tid);
  g8_stage(A,  K, m0+128,  0, LDS + G8_AOFF(0) + 16384, tid);
  g8_stage(Bt, K, n0,     64, LDS + G8_BOFF(1),         tid);
  g8_stage(Bt, K, n0+128, 64, LDS + G8_BOFF(1) + 16384, tid);
  asm volatile("s_waitcnt vmcnt(4)" ::: "memory");
  __builtin_amdgcn_sched_barrier(0);
  __builtin_amdgcn_s_barrier();
  __builtin_amdgcn_sched_barrier(0);

  short8 bf8[8];
  for(int T=0; T<NK; ++T){
    const int buf = T & 1;
    const char* Ab = LDS + G8_AOFF(buf) + wr*16384;
    const char* Bb = LDS + G8_BOFF(buf) + (wc>>1)*16384;
    #pragma unroll
    for(int q=0; q<4; ++q){
      // ---- ds-reads for this phase ----
      if(q==0){
        #pragma unroll
        for(int n=0;n<4;n++){
          #pragma unroll
          for(int kk=0;kk<2;kk++){
            int row = ((wc&1)<<6) + (n<<4) + (lane&15);
            int cb = ((kk<<6) + ((lane>>4)<<4)) ^ ((lane&7)<<4);
            bf8[n*2+kk] = *(const short8*)(Bb + row*128 + cb);
          }
        }
      }
      short8 af[2][2];
      #pragma unroll
      for(int j=0;j<2;j++){
        #pragma unroll
        for(int kk=0;kk<2;kk++){
          int row = ((2*q+j)<<4) + (lane&15);
          int cb = ((kk<<6) + ((lane>>4)<<4)) ^ ((lane&7)<<4);
          af[j][kk] = *(const short8*)(Ab + row*128 + cb);
        }
      }
      // ---- stage schedule: q0:A(T+1)h0 q1:A(T+1)h1 q2:B(T+2)h0 q3:B(T+2)h1 ----
      if(q==0 && T+1<NK) g8_stage(A,  K, m0,      (T+1)<<6, LDS + G8_AOFF((T+1)&1),         tid);
      if(q==1 && T+1<NK) g8_stage(A,  K, m0+128,  (T+1)<<6, LDS + G8_AOFF((T+1)&1) + 16384, tid);
      if(q==2 && T+2<NK) g8_stage(Bt, K, n0,      (T+2)<<6, LDS + G8_BOFF(buf),             tid);
      if(q==3 && T+2<NK) g8_stage(Bt, K, n0+128,  (T+2)<<6, LDS + G8_BOFF(buf) + 16384,     tid);
      if(q==3){
        if(T <= NK-3)      asm volatile("s_waitcnt vmcnt(4)" ::: "memory");
        else if(T == NK-2) asm volatile("s_waitcnt vmcnt(0)" ::: "memory");
      }
      __builtin_amdgcn_sched_barrier(0);
      __builtin_amdgcn_s_barrier();
      __builtin_amdgcn_sched_barrier(0);
      __builtin_amdgcn_s_setprio(1);
      #pragma unroll
      for(int j=0;j<2;j++){
        #pragma unroll
        for(int n=0;n<4;n++){
          #pragma unroll
          for(int kk=0;kk<2;kk++) mfma16(acc[2*q+j][n], af[j][kk], bf8[n*2+kk]);
        }
      }
      __builtin_amdgcn_s_setprio(0);
      __builtin_amdgcn_sched_barrier(0);
      __builtin_amdgcn_s_barrier();
      __builtin_amdgcn_sched_barrier(0);
    }
  }
}

__device__ __forceinline__ void g8_split(int ntM, int ntN, int& bm, int& bn){
  int nwg = ntM*ntN;                       // must be %8==0 (360, 288)
  int bid = (int)blockIdx.x;
  int wg = (bid & 7)*(nwg>>3) + (bid>>3);  // XCD-chunked, bijective
  if(ntN <= ntM){ bm = wg/ntN; bn = wg - bm*ntN; }
  else          { bn = wg/ntM; bm = wg - bn*ntM; }
}

// MODE 0: bf16 out [M,N] ; MODE 2: bf16 out + per-row bias
template<int MODE>
__global__ __launch_bounds__(512,2)
void gemm8p_bf16(const u16* __restrict__ A, const u16* __restrict__ Bt,
                 int M, int N, int K,
                 u16* __restrict__ outB, const float* __restrict__ bias){
  extern __shared__ char LDS[];
  const int tid = threadIdx.x;
  const int lane = tid & 63;
  const int wid = tid >> 6;
  const int wr = wid >> 2, wc = wid & 3;
  int bm, bn;
  g8_split(M>>8, N>>8, bm, bn);
  const int m0 = bm << 8, n0 = bn << 8;

  f32x4 acc[8][4];
  f32x4 zv = {0.f,0.f,0.f,0.f};
  #pragma unroll
  for(int m=0;m<8;m++){
    #pragma unroll
    for(int n=0;n<4;n++) acc[m][n] = zv;
  }
  g8_core(A, Bt, K, m0, n0, acc, LDS, tid);

  const int rbase = (lane>>4)<<2;
  const int cbase = lane & 15;
  #pragma unroll
  for(int m=0;m<8;m++){
    int row0 = m0 + (wr<<7) + (m<<4) + rbase;
    #pragma unroll
    for(int n=0;n<4;n++){
      int col = n0 + (wc<<6) + (n<<4) + cbase;
      #pragma unroll
      for(int r=0;r<4;r++){
        float v = acc[m][n][r];
        if(MODE==2) v += bias[row0+r];
        outB[(size_t)(row0+r)*N + col] = (u16)f2b1(v);
      }
    }
  }
}

// zero-conv epilogue version (3 sets via blockIdx.z)
// Epilogue v2: LDS-staged coalesced fp32 stores.
__global__ __launch_bounds__(512,2)
void gemm8p_zc(const u16* __restrict__ TOKALL, const u16* __restrict__ ZWALL,
               const float* __restrict__ zb, const float* __restrict__ zbp,
               const float* __restrict__ invm, float* __restrict__ out){
  extern __shared__ char LDS[];
  const int set = blockIdx.z;
  const u16* A  = TOKALL + (size_t)set*TOKM*HIDC;
  const u16* Bt = ZWALL + (set==2 ? (size_t)ZNC*HIDC : 0);
  const float* bias = (set==2) ? zbp : zb;
  const bool use_mask = (set != 2);
  float* o = out + (size_t)set*OUT_SET;

  const int tid = threadIdx.x;
  const int lane = tid & 63;
  const int wid = tid >> 6;
  const int wr = wid >> 2, wc = wid & 3;
  int bm, bn;
  g8_split(TOKM>>8, ZNC>>8, bm, bn);     // 8 x 36
  const int m0 = bm << 8, n0 = bn << 8;

  f32x4 acc[8][4];
  f32x4 zv = {0.f,0.f,0.f,0.f};
  #pragma unroll
  for(int m=0;m<8;m++){
    #pragma unroll
    for(int n=0;n<4;n++) acc[m][n] = zv;
  }
  g8_core(A, Bt, HIDC, m0, n0, acc, LDS, tid);

  // block-constant output decomposition of the 256-col span
  const int l = n0 / HIDC;
  const int oc0 = n0 - l*HIDC;
  const int lo = lane & 15, hi = lane >> 4;

  #pragma unroll
  for(int pass=0; pass<2; ++pass){
    __syncthreads();            // all mainloop (or prev-pass) LDS reads done
    if(wr == pass){
      #pragma unroll
      for(int m=0;m<8;m++){
        #pragma unroll
        for(int n=0;n<4;n++){
          int col = (wc<<6) + (n<<4) + lo;      // 0..255
          float badd = bias[n0 + col];
          #pragma unroll
          for(int r=0;r<4;r++){
            int lr = (m<<4) + (hi<<2) + r;      // 0..127
            *(float*)(LDS + (size_t)lr*1024 + ((col<<2) ^ ((lr&7)<<4))) = acc[m][n][r] + badd;
          }
        }
      }
    }
    __syncthreads();
    // 128 rows x 1024B ; wave wid stores rows wid, wid+8, ...
    #pragma unroll
    for(int i=0;i<16;i++){
      int lr = (i<<3) + wid;
      int rr = m0 + (pass<<7) + lr;             // global token row
      int b = rr >> 9, s = rr & 511;
      f32x4 v = *(const f32x4*)(LDS + (size_t)lr*1024 + ((lane<<4) ^ ((lr&7)<<4)));
      if(use_mask){ float w = invm[rr]; v = v * w; }
      *(f32x4*)(o + (size_t)((l*4+b)*513 + (s+1))*HIDC + oc0 + (lane<<2)) = v;
    }
  }
}

// ---------- split-K GEMM (m97-style): atomics into GT ----------
__global__ __launch_bounds__(256,2)
void gemm_splitk(const u16* __restrict__ A, const u16* __restrict__ Bt,
                 int M, int N, int K, float* __restrict__ outF, int kchunk){
  __shared__ u16 As[128*64];
  __shared__ u16 Bs[128*64];
  const int t = threadIdx.x;
  const int lane = t & 63;
  const int w = t >> 6;
  const int wr = w >> 1, wc = w & 1;
  int nchunks = (K + kchunk - 1)/kchunk;
  int bm = (int)blockIdx.x / nchunks;
  int ch = (int)blockIdx.x - bm*nchunks;
  int k0 = ch*kchunk, k1 = k0 + kchunk; if(k1 > K) k1 = K;
  const int m0 = bm << 7, n0 = 0;

  f32x4 zv = {0.f,0.f,0.f,0.f};
  f32x4 acc[4][4];
  #pragma unroll
  for(int m=0;m<4;m++){
    #pragma unroll
    for(int n=0;n<4;n++) acc[m][n] = zv;
  }
  const int srow = t >> 3;
  const int scol = (t & 7) << 3;
  const u16* Ag = A + (size_t)(m0 + srow)*K + scol;
  const u16* Bg = Bt + (size_t)(n0 + srow)*K + scol;
  u16* Al = &As[t*8];
  u16* Bl = &Bs[t*8];

  for(int kt=k0; kt<k1; kt+=64){
    __syncthreads();
    #pragma unroll
    for(int i=0;i<4;i++){
      async16(Ag + (size_t)(i*32)*K + kt, Al + i*2048);
      async16(Bg + (size_t)(i*32)*K + kt, Bl + i*2048);
    }
    __syncthreads();
    #pragma unroll
    for(int kk=0; kk<64; kk+=32){
      const int ko = kk + ((lane>>4)<<3);
      short8 af[4], bfv[4];
      #pragma unroll
      for(int m=0;m<4;m++) af[m] = *(const short8*)&As[((wr<<6)+(m<<4)+(lane&15))*64 + ko];
      #pragma unroll
      for(int n=0;n<4;n++) bfv[n] = *(const short8*)&Bs[((wc<<6)+(n<<4)+(lane&15))*64 + ko];
      #pragma unroll
      for(int m=0;m<4;m++){
        #pragma unroll
        for(int n=0;n<4;n++) mfma16(acc[m][n], af[m], bfv[n]);
      }
    }
  }
  const int rbase = (lane>>4)<<2;
  const int cbase = lane & 15;
  #pragma unroll
  for(int m=0;m<4;m++){
    int row0 = m0 + (wr<<6) + (m<<4) + rbase;
    #pragma unroll
    for(int n=0;n<4;n++){
      int col = n0 + (wc<<6) + (n<<4) + cbase;
      #pragma unroll
      for(int r=0;r<4;r++) atomicAdd(&outF[(size_t)(row0+r)*N + col], acc[m][n][r]);
    }
  }
}

// ---------- host ----------
extern "C" void kernel_launch(void* const* d_in, const int* in_sizes, int n_in,
                              void* d_out, int out_size, void* d_ws, size_t ws_size,
                              hipStream_t stream){
  const float* word  = (const float*)d_in[0];
  const int*   ids   = (const int*)d_in[1];
  const int*   cids  = (const int*)d_in[2];
  const void*  mask  = d_in[3];
  const int*   co_ei = (const int*)d_in[4];
  const float* co_ew = (const float*)d_in[5];
  const int*   re_ei = (const int*)d_in[6];
  const float* re_ew = (const float*)d_in[7];
  const float* png   = (const float*)d_in[8];
  const float* co_W  = (const float*)d_in[9];
  const float* co_b  = (const float*)d_in[10];
  const float* re_W  = (const float*)d_in[11];
  const float* re_b  = (const float*)d_in[12];
  const float* pn_W  = (const float*)d_in[13];
  const float* pn_b  = (const float*)d_in[14];
  const float* zw    = (const float*)d_in[15];
  const float* zb    = (const float*)d_in[16];
  const float* zwp   = (const float*)d_in[17];
  const float* zbp   = (const float*)d_in[18];
  float* out = (float*)d_out;

  // opt-in to 128 KiB dynamic LDS (idempotent, host-side, capture-safe)
  hipFuncSetAttribute((const void*)gemm8p_bf16<0>, hipFuncAttributeMaxDynamicSharedMemorySize, G8_LDS);
  hipFuncSetAttribute((const void*)gemm8p_bf16<2>, hipFuncAttributeMaxDynamicSharedMemorySize, G8_LDS);
  hipFuncSetAttribute((const void*)gemm8p_zc,      hipFuncAttributeMaxDynamicSharedMemorySize, G8_LDS);

  char* wsb = (char*)d_ws;
  size_t off = 0;
  auto alloc = [&](size_t bytes)->void*{ void* p = wsb + off; off += (bytes + 255) & ~(size_t)255; return p; };
  u16* WORDB = (u16*)alloc((size_t)M_PAD*HIDC*2);
  u16* BUFB  = (u16*)alloc((size_t)M_PAD*HIDC*2);
  u16* BUFX  = (u16*)alloc((size_t)M_PAD*HIDC*2);
  u16* ZWALL = (u16*)alloc((size_t)2*ZNC*HIDC*2);
  u16* WT2   = (u16*)alloc((size_t)2*3*HIDC*HIDC*2);
  u16* PNWB  = (u16*)alloc((size_t)HIDC*HIDC*2);
  u16* PNB   = (u16*)alloc((size_t)128*M_PAD*2);
  u16* TOKALL= (u16*)alloc((size_t)3*TOKM*HIDC*2);
  float2* TOKF = (float2*)alloc((size_t)TOKM*HIDC*4);
  float* GT   = (float*)alloc((size_t)HIDC*128*4);
  float* DEG2 = (float*)alloc((size_t)2*N_NODESC*4);
  int*   CNT2 = (int*)alloc((size_t)2*N_NODESC*4);
  float* DINVA = (float*)alloc((size_t)2*N_NODESC*4);
  float* DINVB = (float*)alloc((size_t)2*N_NODESC*4);
  int*   RP2  = (int*)alloc((size_t)2*NN1*4);
  int*   CUR2 = (int*)alloc((size_t)2*N_NODESC*4);
  int*   PART2= (int*)alloc((size_t)2*NBLK*4);
  float2* EMETA=(float2*)alloc((size_t)2*NEC*8);
  u32*   NEED = (u32*)alloc((size_t)N_NODESC*4);
  float* INVM = (float*)alloc((size_t)TOKM*4);
  (void)ws_size; (void)in_sizes; (void)n_in; (void)out_size;

  const int GD_TOK = (TOKM*384 + 255)/256;
  const int GD_E   = (NEC + 255)/256;
  const int SPMM_GD  = (N_NODESC + 3)/4;
  const int PN_NCHUNKS = M_PAD/PN_KCHUNK;               // 60
  const int G_PN  = (HIDC/128)*PN_NCHUNKS;              // 360
  const int G8_GCN = (M_PAD/256)*(HIDC/256);            // 360
  const int G8_CBT = (HIDC/256)*(M_PAD/256);            // 360
  const int G8_ZC  = (TOKM/256)*(ZNC/256);              // 288

  // ---- prep ----
  hipMemsetAsync(NEED, 0, (size_t)N_NODESC*4, stream);
  hipMemsetAsync(DEG2, 0, (size_t)2*N_NODESC*4, stream);
  hipMemsetAsync(CNT2, 0, (size_t)2*N_NODESC*4, stream);
  k_invmask<<<1,256,0,stream>>>(mask, INVM);
  k_needed<<<(TOKM+255)/256,256,0,stream>>>(ids, NEED);
  k_conv<<<(HIDC*HIDC/2 + 255)/256,256,0,stream>>>(pn_W, PNWB, HIDC*HIDC/2);
  k_conv<<<(ZNC*HIDC/2 + 255)/256,256,0,stream>>>(zw, ZWALL, ZNC*HIDC/2);
  k_conv<<<(ZNC*HIDC/2 + 255)/256,256,0,stream>>>(zwp, ZWALL + (size_t)ZNC*HIDC, ZNC*HIDC/2);
  k_conv_pad<<<(M_PAD*384 + 255)/256,256,0,stream>>>(word, WORDB, N_NODESC, M_PAD);
  k_transposeW2<<<dim3((3*HIDC*384 + 255)/256, 2),256,0,stream>>>(co_W, re_W, WT2);

  // ---- batched CSR build ----
  k_degcnt2<<<dim3(GD_E,2),256,0,stream>>>(co_ei, re_ei, co_ew, re_ew, DEG2, CNT2);
  k_dinv2<<<dim3((N_NODESC+255)/256,2),256,0,stream>>>(DEG2, DINVA, DINVB);
  k_scan1<<<dim3(NBLK,2),256,0,stream>>>(CNT2, PART2);
  k_scan2<<<2,128,0,stream>>>(PART2, RP2);
  k_scan3<<<dim3(NBLK,2),256,0,stream>>>(CNT2, PART2, RP2, CUR2);
  k_scatter2<<<dim3(GD_E,2),256,0,stream>>>(co_ei, re_ei, co_ew, re_ew, DINVA, CUR2, EMETA);

  // ---- pn path: cbT = pnW·word^T (+row bias), GT = cbT·pn^T (split-K), gather ----
  gemm8p_bf16<2><<<G8_CBT,512,G8_LDS,stream>>>(PNWB, WORDB, HIDC, M_PAD, HIDC, BUFX, pn_b);
  k_pnb<<<(128*(M_PAD/2) + 255)/256,256,0,stream>>>(png, PNB);
  hipMemsetAsync(GT, 0, (size_t)HIDC*128*4, stream);
  gemm_splitk<<<G_PN,256,0,stream>>>(BUFX, PNB, HIDC, 128, M_PAD, GT, PN_KCHUNK);
  k_gather_pn<<<GD_TOK,256,0,stream>>>(GT, cids, TOKALL + (size_t)2*TOKM*HIDC);

  // ---- GCN stacks ----
  auto run_graph = [&](int g, const float* bf, u16* tokb){
    const int* rp = RP2 + (size_t)g*NN1;
    const float2* em = EMETA + (size_t)g*NEC;
    const float* di2 = DINVB + (size_t)g*N_NODESC;
    const u16* X = WORDB;
    for(int i=0;i<3;i++){
      gemm8p_bf16<0><<<G8_GCN,512,G8_LDS,stream>>>(X, WT2 + ((size_t)g*3 + i)*HIDC*HIDC,
                                                   M_PAD, HIDC, HIDC, BUFB, nullptr);
      if(i==2)
        k_spmm<<<SPMM_GD,256,0,stream>>>(BUFB, rp, em, di2, bf + i*HIDC, BUFX, NEED);
      else
        k_spmm_slab<<<SP_GRID,256,0,stream>>>(BUFB, rp, em, di2, bf + i*HIDC, BUFX);
      k_gather<<<GD_TOK,256,0,stream>>>(BUFX, ids, TOKF, tokb, i);
      X = BUFX;
    }
  };
  run_graph(0, co_b, TOKALL);
  run_graph(1, re_b, TOKALL + (size_t)TOKM*HIDC);

  // ---- zero-convs -> outputs ----
  dim3 zgrid(G8_ZC, 1, 3);
  gemm8p_zc<<<zgrid,512,G8_LDS,stream>>>(TOKALL, ZWALL, zb, zbp, INVM, out);
  k_zerocol<<<(3*LLAY*4*HIDC + 255)/256,256,0,stream>>>(out);
}

// Round 3
// 1223.776 us; speedup vs baseline: 1.2513x; 1.2513x over previous
//
#include <hip/hip_runtime.h>
#include <stdint.h>

typedef unsigned int u32;
typedef unsigned short u16;
typedef __attribute__((ext_vector_type(8))) short short8;
typedef __attribute__((ext_vector_type(4))) float f32x4;

#define N_NODESC 30522
#define HIDC 768
#define NEC 488352
#define TOKM 2048
#define LLAY 12
#define NCLS 101
#define M_PAD 30720     // 120*256
#define ZNC (LLAY*HIDC) // 9216
#define OUT_SET (LLAY*4*513*HIDC)
#define PN_KCHUNK 512
#define NBLK 120
#define NN1 (N_NODESC+1)
#define G8_LDS 131072

// ---------- helpers ----------
__device__ __forceinline__ float bl(u32 u){ return __uint_as_float(u<<16); }
__device__ __forceinline__ float bh(u32 u){ return __uint_as_float(u & 0xffff0000u); }
__device__ __forceinline__ u32 f2b1(float f){ u32 x=__float_as_uint(f); return (x + 0x7fffu + ((x>>16)&1u))>>16; }
__device__ __forceinline__ u32 pack2(float a, float b){ return f2b1(a) | (f2b1(b)<<16); }

__device__ __forceinline__ void mfma16(f32x4& d, short8 a, short8 b){
  asm volatile("v_mfma_f32_16x16x32_bf16 %0, %1, %2, %0" : "+v"(d) : "v"(a), "v"(b));
}
__device__ __forceinline__ void async16(const void* g, void* l){
  __builtin_amdgcn_global_load_lds((const __attribute__((address_space(1))) u32*)g,
                                   (__attribute__((address_space(3))) u32*)l, 16, 0, 0);
}

// ---------- mask normalize ----------
__global__ void k_invmask(const void* __restrict__ mask, float* __restrict__ invm){
  __shared__ int s_byte, s_flt;
  int t = threadIdx.x;
  const unsigned char* mb = (const unsigned char*)mask;
  const u32* mw = (const u32*)mask;
  int lb=0, lf=0;
  for(int i=t;i<2048;i+=256) if((i&3)!=0 && mb[i]!=0) lb=1;
  for(int i=t;i<512;i+=256) if(mw[i]==0x3F800000u) lf=1;
  if(t==0){ s_byte=0; s_flt=0; }
  __syncthreads();
  if(lb) s_byte=1;
  if(lf) s_flt=1;
  __syncthreads();
  int mode = s_flt ? 2 : (s_byte ? 1 : 0);
  for(int p=t;p<2048;p+=256){
    int mv = (mode==1) ? (int)mb[p] : (int)(mw[p]!=0u);
    invm[p] = mv ? 0.f : 1.f;
  }
}

__global__ void k_needed(const int* __restrict__ ids, u32* __restrict__ needed){
  int p = blockIdx.x*256 + threadIdx.x;
  if(p < TOKM){ int id = ids[p]; if(id < N_NODESC) needed[id] = 1u; }
}

// frontier expansion: NEED1[g] = NEED  union  { src(e) : dst(e) in NEED }, per graph
__global__ void k_need1_init(const u32* __restrict__ needed, u32* __restrict__ need1){
  int v = blockIdx.x*256 + threadIdx.x;
  if(v < N_NODESC){ u32 x = needed[v]; need1[v] = x; need1[N_NODESC + v] = x; }
}
__global__ void k_need_expand(const int* __restrict__ coei, const int* __restrict__ reei,
                              const u32* __restrict__ needed, u32* __restrict__ need1){
  int g = blockIdx.y;
  const int* ei = g ? reei : coei;
  int e = blockIdx.x*256 + threadIdx.x;
  if(e < NEC){
    int d = ei[NEC+e];
    if(needed[d]) need1[(size_t)g*N_NODESC + ei[e]] = 1u;
  }
}

// ---------- converts ----------
__global__ void k_conv(const float* __restrict__ src, u16* __restrict__ dst, int ndw){
  int i = blockIdx.x*256 + threadIdx.x;
  if(i < ndw) ((u32*)dst)[i] = pack2(src[2*i], src[2*i+1]);
}
__global__ void k_conv_pad(const float* __restrict__ src, u16* __restrict__ dst, int srcRows, int padRows){
  int i = blockIdx.x*256 + threadIdx.x;
  if(i >= padRows*384) return;
  int row = i/384; int c2 = (i - row*384)*2;
  float lo=0.f, hi=0.f;
  if(row < srcRows){ const float* s = src + (size_t)row*HIDC + c2; lo=s[0]; hi=s[1]; }
  ((u32*)dst)[i] = pack2(lo, hi);
}
__global__ void k_pnb(const float* __restrict__ png, u16* __restrict__ pnb){
  int i = blockIdx.x*256 + threadIdx.x;
  if(i >= 128*(M_PAD/2)) return;
  int row = i/(M_PAD/2); int k2 = (i - row*(M_PAD/2))*2;
  float lo=0.f, hi=0.f;
  if(row < NCLS){
    const float* s = png + (size_t)row*N_NODESC;
    if(k2 < N_NODESC) lo = s[k2];
    if(k2+1 < N_NODESC) hi = s[k2+1];
  }
  ((u32*)pnb)[i] = pack2(lo, hi);
}
__global__ void k_transposeW2(const float* __restrict__ coW, const float* __restrict__ reW,
                              u16* __restrict__ Wt2){
  int g = blockIdx.y;
  int i = blockIdx.x*256 + threadIdx.x;
  if(i >= 3*HIDC*384) return;
  const float* W = g ? reW : coW;
  int mat = i/(HIDC*384); int rem = i - mat*HIDC*384;
  int n = rem/384; int kd = rem - n*384;
  const float* Wm = W + (size_t)mat*HIDC*HIDC;
  float lo = Wm[(size_t)(2*kd)*HIDC + n];
  float hi = Wm[(size_t)(2*kd+1)*HIDC + n];
  ((u32*)Wt2)[(size_t)g*3*HIDC*384 + (size_t)mat*HIDC*384 + (size_t)n*384 + kd] = pack2(lo, hi);
}

// ---------- batched graph prep ----------
__global__ void k_degcnt2(const int* __restrict__ coei, const int* __restrict__ reei,
                          const float* __restrict__ coew, const float* __restrict__ reew,
                          float* __restrict__ deg2, int* __restrict__ cnt2){
  int g = blockIdx.y;
  const int* ei = g ? reei : coei;
  const float* ew = g ? reew : coew;
  int e = blockIdx.x*256 + threadIdx.x;
  if(e < NEC){ int d = ei[NEC+e]; atomicAdd(&deg2[(size_t)g*N_NODESC + d], ew[e]); atomicAdd(&cnt2[(size_t)g*N_NODESC + d], 1); }
}
__global__ void k_dinv2(const float* __restrict__ deg2, float* __restrict__ dinvA, float* __restrict__ dinvB){
  int g = blockIdx.y;
  int v = blockIdx.x*256 + threadIdx.x;
  if(v < N_NODESC){
    float d = deg2[(size_t)g*N_NODESC + v] + 1.f;
    dinvA[(size_t)g*N_NODESC + v] = rsqrtf(d);
    dinvB[(size_t)g*N_NODESC + v] = 1.f/d;
  }
}
__global__ void k_scan1(const int* __restrict__ cnt2, int* __restrict__ part2){
  __shared__ int wt[4];
  int g = blockIdx.y, b = blockIdx.x, t = threadIdx.x;
  int lane = t & 63, w = t >> 6;
  int i = b*256 + t;
  int v = (i < N_NODESC) ? cnt2[(size_t)g*N_NODESC + i] : 0;
  int x = v;
  #pragma unroll
  for(int off=1; off<64; off<<=1){ int y = __shfl_up(x, off); if(lane>=off) x += y; }
  if(lane==63) wt[w] = x;
  __syncthreads();
  if(t==0) part2[g*NBLK + b] = wt[0]+wt[1]+wt[2]+wt[3];
}
__global__ void k_scan2(int* __restrict__ part2, int* __restrict__ rp2){
  __shared__ int w0tot;
  int g = blockIdx.x, t = threadIdx.x;   // 128 threads
  int lane = t & 63, w = t >> 6;
  int v = (t < NBLK) ? part2[g*NBLK + t] : 0;
  int x = v;
  #pragma unroll
  for(int off=1; off<64; off<<=1){ int y = __shfl_up(x, off); if(lane>=off) x += y; }
  if(w==0 && lane==63) w0tot = x;
  __syncthreads();
  int incl = x + (w ? w0tot : 0);
  int excl = incl - v;
  if(t < NBLK) part2[g*NBLK + t] = excl;
  if(t == 127) rp2[(size_t)g*NN1 + N_NODESC] = incl;
}
__global__ void k_scan3(const int* __restrict__ cnt2, const int* __restrict__ part2,
                        int* __restrict__ rp2, int* __restrict__ cur2){
  __shared__ int wt[4];
  int g = blockIdx.y, b = blockIdx.x, t = threadIdx.x;
  int lane = t & 63, w = t >> 6;
  int i = b*256 + t;
  int v = (i < N_NODESC) ? cnt2[(size_t)g*N_NODESC + i] : 0;
  int x = v;
  #pragma unroll
  for(int off=1; off<64; off<<=1){ int y = __shfl_up(x, off); if(lane>=off) x += y; }
  if(lane==63) wt[w] = x;
  __syncthreads();
  int wpre = 0;
  #pragma unroll
  for(int j=0;j<4;j++) if(j<w) wpre += wt[j];
  int excl = x - v + wpre + part2[g*NBLK + b];
  if(i < N_NODESC){ rp2[(size_t)g*NN1 + i] = excl; cur2[(size_t)g*N_NODESC + i] = excl; }
}
__global__ void k_scatter2(const int* __restrict__ coei, const int* __restrict__ reei,
                           const float* __restrict__ coew, const float* __restrict__ reew,
                           const float* __restrict__ dinvA, int* __restrict__ cur2,
                           float2* __restrict__ emeta){
  int g = blockIdx.y;
  const int* ei = g ? reei : coei;
  const float* ew = g ? reew : coew;
  int e = blockIdx.x*256 + threadIdx.x;
  if(e < NEC){
    int s = ei[e], d = ei[NEC+e];
    int pos = atomicAdd(&cur2[(size_t)g*N_NODESC + d], 1);
    float nrm = dinvA[(size_t)g*N_NODESC + s]*ew[e]*dinvA[(size_t)g*N_NODESC + d];
    emeta[(size_t)g*NEC + pos] = make_float2(__int_as_float(s), nrm);
  }
}

// ---------- SpMM ----------
__global__ __launch_bounds__(256)
void k_spmm(const u16* __restrict__ hW, const int* __restrict__ rp,
            const float2* __restrict__ emeta, const float* __restrict__ dinv2,
            const float* __restrict__ bias, u16* __restrict__ hout,
            const u32* __restrict__ needed){
  int v = blockIdx.x*4 + (threadIdx.x>>6);
  if(v >= N_NODESC) return;
  if(needed && !needed[v]) return;
  int lane = threadIdx.x & 63;
  const u32* H = (const u32*)hW;
  float acc[12];
  #pragma unroll
  for(int q=0;q<12;q++) acc[q]=0.f;
  int e0 = rp[v], e1 = rp[v+1];
  int e = e0;
  for(; e+4<=e1; e+=4){
    float2 m0=emeta[e], m1=emeta[e+1], m2=emeta[e+2], m3=emeta[e+3];
    const u32* r0 = H + (size_t)__float_as_int(m0.x)*384 + lane;
    const u32* r1 = H + (size_t)__float_as_int(m1.x)*384 + lane;
    const u32* r2 = H + (size_t)__float_as_int(m2.x)*384 + lane;
    const u32* r3 = H + (size_t)__float_as_int(m3.x)*384 + lane;
    u32 u0[6],u1[6],u2[6],u3[6];
    #pragma unroll
    for(int q=0;q<6;q++){ u0[q]=r0[q*64]; u1[q]=r1[q*64]; u2[q]=r2[q*64]; u3[q]=r3[q*64]; }
    #pragma unroll
    for(int q=0;q<6;q++){
      acc[2*q]   += m0.y*bl(u0[q]) + m1.y*bl(u1[q]) + m2.y*bl(u2[q]) + m3.y*bl(u3[q]);
      acc[2*q+1] += m0.y*bh(u0[q]) + m1.y*bh(u1[q]) + m2.y*bh(u2[q]) + m3.y*bh(u3[q]);
    }
  }
  for(; e<e1; ++e){
    float2 mm = emeta[e];
    const u32* r = H + (size_t)__float_as_int(mm.x)*384 + lane;
    #pragma unroll
    for(int q=0;q<6;q++){ u32 u = r[q*64]; acc[2*q] += mm.y*bl(u); acc[2*q+1] += mm.y*bh(u); }
  }
  { float wgt = dinv2[v];
    const u32* r = H + (size_t)v*384 + lane;
    #pragma unroll
    for(int q=0;q<6;q++){ u32 u = r[q*64]; acc[2*q] += wgt*bl(u); acc[2*q+1] += wgt*bh(u); }
  }
  const float2* B2 = (const float2*)bias;
  u32* O = (u32*)hout + (size_t)v*384 + lane;
  #pragma unroll
  for(int q=0;q<6;q++){
    float2 bb = B2[lane + 64*q];
    float x0 = fmaxf(acc[2*q]+bb.x, 0.f);
    float x1 = fmaxf(acc[2*q+1]+bb.y, 0.f);
    O[q*64] = pack2(x0, x1);
  }
}

// ---------- token gather ----------
__global__ void k_gather(const u16* __restrict__ h, const int* __restrict__ ids,
                         float2* __restrict__ tokf, u16* __restrict__ tokb, int phase){
  int d = blockIdx.x*256 + threadIdx.x;
  if(d >= TOKM*384) return;
  int p = d/384, q = d - p*384;
  int id = ids[p];
  float x0=0.f, x1=0.f;
  if(id < N_NODESC){ u32 u = ((const u32*)h)[(size_t)id*384 + q]; x0 = bl(u)*(1.f/3.f); x1 = bh(u)*(1.f/3.f); }
  float2 cur;
  if(phase==0){ cur.x=x0; cur.y=x1; }
  else { cur = tokf[d]; cur.x += x0; cur.y += x1; }
  if(phase==2) ((u32*)tokb)[d] = pack2(cur.x, cur.y);
  else tokf[d] = cur;
}

__global__ void k_gather_pn(const float* __restrict__ GT, const int* __restrict__ cids, u16* __restrict__ tokb){
  int d = blockIdx.x*256 + threadIdx.x;
  if(d >= TOKM*384) return;
  int p = d/384, q = d - p*384;
  int cid = cids[p];
  float lo = GT[(size_t)(2*q)*128 + cid];
  float hi = GT[(size_t)(2*q+1)*128 + cid];
  ((u32*)tokb)[d] = pack2(lo, hi);
}

__global__ void k_zerocol(float* __restrict__ out){
  int i = blockIdx.x*256 + threadIdx.x;
  if(i >= 3*LLAY*4*HIDC) return;
  int set = i/(LLAY*4*HIDC); int rem = i - set*(LLAY*4*HIDC);
  int l = rem/(4*HIDC); int rem2 = rem - l*(4*HIDC);
  int b = rem2/HIDC; int o = rem2 - b*HIDC;
  out[(size_t)set*OUT_SET + (size_t)(l*4+b)*513*HIDC + o] = 0.f;
}

// ================= 8-phase 256x256 GEMM core =================
// LDS map (bytes): A buf b: b*65536 + half*16384 ; B buf b: b*65536+32768 + half*16384
// swizzle: byte ^= ((row&7)<<4)  -> staged via pre-swizzled global source (involution)
#define G8_AOFF(b) ((b)*65536)
#define G8_BOFF(b) ((b)*65536 + 32768)

__device__ __forceinline__ void g8_stage(const u16* __restrict__ src, int ldk, int g0, int kt,
                                         char* half_base, int tid){
  const int lane = tid & 63;
  const int csw = ((lane&7) ^ (lane>>3)) << 3;   // pre-swizzled source col (elements)
  const u16* s0 = src + (size_t)(g0 + (tid>>3))*ldk + (kt + csw);
  const u16* s1 = src + (size_t)(g0 + 64 + (tid>>3))*ldk + (kt + csw);
  async16(s0, half_base + (size_t)tid*16);
  async16(s1, half_base + 8192 + (size_t)tid*16);
}

__device__ __forceinline__ void g8_core(const u16* __restrict__ A, const u16* __restrict__ Bt,
                                        int K, int m0, int n0,
                                        f32x4 (&acc)[8][4], char* LDS, int tid){
  const int lane = tid & 63;
  const int wid = tid >> 6;
  const int wr = wid >> 2, wc = wid & 3;
  const int NK = K >> 6;   // K-tiles (BK=64); requires NK>=3, even

  // prologue: B(0)h0,h1 A(0)h0,h1 B(1)h0,h1 ; vmcnt(4) ; barrier
  g8_stage(Bt, K, n0,      0, LDS + G8_BOFF(0),         tid);
  g8_stage(Bt, K, n0+128,  0, LDS + G8_BOFF(0) + 16384, tid);
  g8_stage(A,  K, m0,      0, LDS + G8_AOFF(0),         tid);
  g8_stage(A,  K, m0+128,  0, LDS + G8_AOFF(0) + 16384, tid);
  g8_stage(Bt, K, n0,     64, LDS + G8_BOFF(1),         tid);
  g8_stage(Bt, K, n0+128, 64, LDS + G8_BOFF(1) + 16384, tid);
  asm volatile("s_waitcnt vmcnt(4)" ::: "memory");
  __builtin_amdgcn_sched_barrier(0);
  __builtin_amdgcn_s_barrier();
  __builtin_amdgcn_sched_barrier(0);

  short8 bf8[8];
  for(int T=0; T<NK; ++T){
    const int buf = T & 1;
    const char* Ab = LDS + G8_AOFF(buf) + wr*16384;
    const char* Bb = LDS + G8_BOFF(buf) + (wc>>1)*16384;
    #pragma unroll
    for(int q=0; q<4; ++q){
      // ---- ds-reads for this phase ----
      if(q==0){
        #pragma unroll
        for(int n=0;n<4;n++){
          #pragma unroll
          for(int kk=0;kk<2;kk++){
            int row = ((wc&1)<<6) + (n<<4) + (lane&15);
            int cb = ((kk<<6) + ((lane>>4)<<4)) ^ ((lane&7)<<4);
            bf8[n*2+kk] = *(const short8*)(Bb + row*128 + cb);
          }
        }
      }
      short8 af[2][2];
      #pragma unroll
      for(int j=0;j<2;j++){
        #pragma unroll
        for(int kk=0;kk<2;kk++){
          int row = ((2*q+j)<<4) + (lane&15);
          int cb = ((kk<<6) + ((lane>>4)<<4)) ^ ((lane&7)<<4);
          af[j][kk] = *(const short8*)(Ab + row*128 + cb);
        }
      }
      // ---- stage schedule: q0:A(T+1)h0 q1:A(T+1)h1 q2:B(T+2)h0 q3:B(T+2)h1 ----
      if(q==0 && T+1<NK) g8_stage(A,  K, m0,      (T+1)<<6, LDS + G8_AOFF((T+1)&1),         tid);
      if(q==1 && T+1<NK) g8_stage(A,  K, m0+128,  (T+1)<<6, LDS + G8_AOFF((T+1)&1) + 16384, tid);
      if(q==2 && T+2<NK) g8_stage(Bt, K, n0,      (T+2)<<6, LDS + G8_BOFF(buf),             tid);
      if(q==3 && T+2<NK) g8_stage(Bt, K, n0+128,  (T+2)<<6, LDS + G8_BOFF(buf) + 16384,     tid);
      if(q==3){
        if(T <= NK-3)      asm volatile("s_waitcnt vmcnt(4)" ::: "memory");
        else if(T == NK-2) asm volatile("s_waitcnt vmcnt(0)" ::: "memory");
      }
      __builtin_amdgcn_sched_barrier(0);
      __builtin_amdgcn_s_barrier();
      __builtin_amdgcn_sched_barrier(0);
      __builtin_amdgcn_s_setprio(1);
      #pragma unroll
      for(int j=0;j<2;j++){
        #pragma unroll
        for(int n=0;n<4;n++){
          #pragma unroll
          for(int kk=0;kk<2;kk++) mfma16(acc[2*q+j][n], af[j][kk], bf8[n*2+kk]);
        }
      }
      __builtin_amdgcn_s_setprio(0);
      __builtin_amdgcn_sched_barrier(0);
      __builtin_amdgcn_s_barrier();
      __builtin_amdgcn_sched_barrier(0);
    }
  }
}

__device__ __forceinline__ void g8_split(int ntM, int ntN, int& bm, int& bn){
  int nwg = ntM*ntN;                       // must be %8==0 (360, 288)
  int bid = (int)blockIdx.x;
  int wg = (bid & 7)*(nwg>>3) + (bid>>3);  // XCD-chunked, bijective
  if(ntN <= ntM){ bm = wg/ntN; bn = wg - bm*ntN; }
  else          { bn = wg/ntM; bm = wg - bn*ntM; }
}

// MODE 0: bf16 out [M,N] ; MODE 2: bf16 out + per-row bias
template<int MODE>
__global__ __launch_bounds__(512,2)
void gemm8p_bf16(const u16* __restrict__ A, const u16* __restrict__ Bt,
                 int M, int N, int K,
                 u16* __restrict__ outB, const float* __restrict__ bias){
  extern __shared__ char LDS[];
  const int tid = threadIdx.x;
  const int lane = tid & 63;
  const int wid = tid >> 6;
  const int wr = wid >> 2, wc = wid & 3;
  int bm, bn;
  g8_split(M>>8, N>>8, bm, bn);
  const int m0 = bm << 8, n0 = bn << 8;

  f32x4 acc[8][4];
  f32x4 zv = {0.f,0.f,0.f,0.f};
  #pragma unroll
  for(int m=0;m<8;m++){
    #pragma unroll
    for(int n=0;n<4;n++) acc[m][n] = zv;
  }
  g8_core(A, Bt, K, m0, n0, acc, LDS, tid);

  const int rbase = (lane>>4)<<2;
  const int cbase = lane & 15;
  #pragma unroll
  for(int m=0;m<8;m++){
    int row0 = m0 + (wr<<7) + (m<<4) + rbase;
    #pragma unroll
    for(int n=0;n<4;n++){
      int col = n0 + (wc<<6) + (n<<4) + cbase;
      #pragma unroll
      for(int r=0;r<4;r++){
        float v = acc[m][n][r];
        if(MODE==2) v += bias[row0+r];
        outB[(size_t)(row0+r)*N + col] = (u16)f2b1(v);
      }
    }
  }
}

// zero-conv epilogue version (3 sets via blockIdx.z)
// Epilogue v2: LDS-staged coalesced fp32 stores.
__global__ __launch_bounds__(512,2)
void gemm8p_zc(const u16* __restrict__ TOKALL, const u16* __restrict__ ZWALL,
               const float* __restrict__ zb, const float* __restrict__ zbp,
               const float* __restrict__ invm, float* __restrict__ out){
  extern __shared__ char LDS[];
  const int set = blockIdx.z;
  const u16* A  = TOKALL + (size_t)set*TOKM*HIDC;
  const u16* Bt = ZWALL + (set==2 ? (size_t)ZNC*HIDC : 0);
  const float* bias = (set==2) ? zbp : zb;
  const bool use_mask = (set != 2);
  float* o = out + (size_t)set*OUT_SET;

  const int tid = threadIdx.x;
  const int lane = tid & 63;
  const int wid = tid >> 6;
  const int wr = wid >> 2, wc = wid & 3;
  int bm, bn;
  g8_split(TOKM>>8, ZNC>>8, bm, bn);     // 8 x 36
  const int m0 = bm << 8, n0 = bn << 8;

  f32x4 acc[8][4];
  f32x4 zv = {0.f,0.f,0.f,0.f};
  #pragma unroll
  for(int m=0;m<8;m++){
    #pragma unroll
    for(int n=0;n<4;n++) acc[m][n] = zv;
  }
  g8_core(A, Bt, HIDC, m0, n0, acc, LDS, tid);

  // block-constant output decomposition of the 256-col span
  const int l = n0 / HIDC;
  const int oc0 = n0 - l*HIDC;
  const int lo = lane & 15, hi = lane >> 4;

  #pragma unroll
  for(int pass=0; pass<2; ++pass){
    __syncthreads();            // all mainloop (or prev-pass) LDS reads done
    if(wr == pass){
      #pragma unroll
      for(int m=0;m<8;m++){
        #pragma unroll
        for(int n=0;n<4;n++){
          int col = (wc<<6) + (n<<4) + lo;      // 0..255
          float badd = bias[n0 + col];
          #pragma unroll
          for(int r=0;r<4;r++){
            int lr = (m<<4) + (hi<<2) + r;      // 0..127
            *(float*)(LDS + (size_t)lr*1024 + ((col<<2) ^ ((lr&7)<<4))) = acc[m][n][r] + badd;
          }
        }
      }
    }
    __syncthreads();
    // 128 rows x 1024B ; wave wid stores rows wid, wid+8, ...
    #pragma unroll
    for(int i=0;i<16;i++){
      int lr = (i<<3) + wid;
      int rr = m0 + (pass<<7) + lr;             // global token row
      int b = rr >> 9, s = rr & 511;
      f32x4 v = *(const f32x4*)(LDS + (size_t)lr*1024 + ((lane<<4) ^ ((lr&7)<<4)));
      if(use_mask){ float w = invm[rr]; v = v * w; }
      *(f32x4*)(o + (size_t)((l*4+b)*513 + (s+1))*HIDC + oc0 + (lane<<2)) = v;
    }
  }
}

// ---------- split-K GEMM (m97-style): atomics into GT ----------
__global__ __launch_bounds__(256,2)
void gemm_splitk(const u16* __restrict__ A, const u16* __restrict__ Bt,
                 int M, int N, int K, float* __restrict__ outF, int kchunk){
  __shared__ u16 As[128*64];
  __shared__ u16 Bs[128*64];
  const int t = threadIdx.x;
  const int lane = t & 63;
  const int w = t >> 6;
  const int wr = w >> 1, wc = w & 1;
  int nchunks = (K + kchunk - 1)/kchunk;
  int bm = (int)blockIdx.x / nchunks;
  int ch = (int)blockIdx.x - bm*nchunks;
  int k0 = ch*kchunk, k1 = k0 + kchunk; if(k1 > K) k1 = K;
  const int m0 = bm << 7, n0 = 0;

  f32x4 zv = {0.f,0.f,0.f,0.f};
  f32x4 acc[4][4];
  #pragma unroll
  for(int m=0;m<4;m++){
    #pragma unroll
    for(int n=0;n<4;n++) acc[m][n] = zv;
  }
  const int srow = t >> 3;
  const int scol = (t & 7) << 3;
  const u16* Ag = A + (size_t)(m0 + srow)*K + scol;
  const u16* Bg = Bt + (size_t)(n0 + srow)*K + scol;
  u16* Al = &As[t*8];
  u16* Bl = &Bs[t*8];

  for(int kt=k0; kt<k1; kt+=64){
    __syncthreads();
    #pragma unroll
    for(int i=0;i<4;i++){
      async16(Ag + (size_t)(i*32)*K + kt, Al + i*2048);
      async16(Bg + (size_t)(i*32)*K + kt, Bl + i*2048);
    }
    __syncthreads();
    #pragma unroll
    for(int kk=0; kk<64; kk+=32){
      const int ko = kk + ((lane>>4)<<3);
      short8 af[4], bfv[4];
      #pragma unroll
      for(int m=0;m<4;m++) af[m] = *(const short8*)&As[((wr<<6)+(m<<4)+(lane&15))*64 + ko];
      #pragma unroll
      for(int n=0;n<4;n++) bfv[n] = *(const short8*)&Bs[((wc<<6)+(n<<4)+(lane&15))*64 + ko];
      #pragma unroll
      for(int m=0;m<4;m++){
        #pragma unroll
        for(int n=0;n<4;n++) mfma16(acc[m][n], af[m], bfv[n]);
      }
    }
  }
  const int rbase = (lane>>4)<<2;
  const int cbase = lane & 15;
  #pragma unroll
  for(int m=0;m<4;m++){
    int row0 = m0 + (wr<<6) + (m<<4) + rbase;
    #pragma unroll
    for(int n=0;n<4;n++){
      int col = n0 + (wc<<6) + (n<<4) + cbase;
      #pragma unroll
      for(int r=0;r<4;r++) atomicAdd(&outF[(size_t)(row0+r)*N + col], acc[m][n][r]);
    }
  }
}

// ---------- host ----------
extern "C" void kernel_launch(void* const* d_in, const int* in_sizes, int n_in,
                              void* d_out, int out_size, void* d_ws, size_t ws_size,
                              hipStream_t stream){
  const float* word  = (const float*)d_in[0];
  const int*   ids   = (const int*)d_in[1];
  const int*   cids  = (const int*)d_in[2];
  const void*  mask  = d_in[3];
  const int*   co_ei = (const int*)d_in[4];
  const float* co_ew = (const float*)d_in[5];
  const int*   re_ei = (const int*)d_in[6];
  const float* re_ew = (const float*)d_in[7];
  const float* png   = (const float*)d_in[8];
  const float* co_W  = (const float*)d_in[9];
  const float* co_b  = (const float*)d_in[10];
  const float* re_W  = (const float*)d_in[11];
  const float* re_b  = (const float*)d_in[12];
  const float* pn_W  = (const float*)d_in[13];
  const float* pn_b  = (const float*)d_in[14];
  const float* zw    = (const float*)d_in[15];
  const float* zb    = (const float*)d_in[16];
  const float* zwp   = (const float*)d_in[17];
  const float* zbp   = (const float*)d_in[18];
  float* out = (float*)d_out;

  // opt-in to 128 KiB dynamic LDS (idempotent, host-side, capture-safe)
  hipFuncSetAttribute((const void*)gemm8p_bf16<0>, hipFuncAttributeMaxDynamicSharedMemorySize, G8_LDS);
  hipFuncSetAttribute((const void*)gemm8p_bf16<2>, hipFuncAttributeMaxDynamicSharedMemorySize, G8_LDS);
  hipFuncSetAttribute((const void*)gemm8p_zc,      hipFuncAttributeMaxDynamicSharedMemorySize, G8_LDS);

  char* wsb = (char*)d_ws;
  size_t off = 0;
  auto alloc = [&](size_t bytes)->void*{ void* p = wsb + off; off += (bytes + 255) & ~(size_t)255; return p; };
  u16* WORDB = (u16*)alloc((size_t)M_PAD*HIDC*2);
  u16* BUFB  = (u16*)alloc((size_t)M_PAD*HIDC*2);
  u16* BUFX  = (u16*)alloc((size_t)M_PAD*HIDC*2);
  u16* ZWALL = (u16*)alloc((size_t)2*ZNC*HIDC*2);
  u16* WT2   = (u16*)alloc((size_t)2*3*HIDC*HIDC*2);
  u16* PNWB  = (u16*)alloc((size_t)HIDC*HIDC*2);
  u16* PNB   = (u16*)alloc((size_t)128*M_PAD*2);
  u16* TOKALL= (u16*)alloc((size_t)3*TOKM*HIDC*2);
  float2* TOKF = (float2*)alloc((size_t)TOKM*HIDC*4);
  float* GT   = (float*)alloc((size_t)HIDC*128*4);
  float* DEG2 = (float*)alloc((size_t)2*N_NODESC*4);
  int*   CNT2 = (int*)alloc((size_t)2*N_NODESC*4);
  float* DINVA = (float*)alloc((size_t)2*N_NODESC*4);
  float* DINVB = (float*)alloc((size_t)2*N_NODESC*4);
  int*   RP2  = (int*)alloc((size_t)2*NN1*4);
  int*   CUR2 = (int*)alloc((size_t)2*N_NODESC*4);
  int*   PART2= (int*)alloc((size_t)2*NBLK*4);
  float2* EMETA=(float2*)alloc((size_t)2*NEC*8);
  u32*   NEED = (u32*)alloc((size_t)N_NODESC*4);
  u32*   NEED1= (u32*)alloc((size_t)2*N_NODESC*4);
  float* INVM = (float*)alloc((size_t)TOKM*4);
  (void)ws_size; (void)in_sizes; (void)n_in; (void)out_size;

  const int GD_TOK = (TOKM*384 + 255)/256;
  const int GD_E   = (NEC + 255)/256;
  const int GD_N   = (N_NODESC + 255)/256;
  const int SPMM_GD  = (N_NODESC + 3)/4;
  const int PN_NCHUNKS = M_PAD/PN_KCHUNK;               // 60
  const int G_PN  = (HIDC/128)*PN_NCHUNKS;              // 360
  const int G8_GCN = (M_PAD/256)*(HIDC/256);            // 360
  const int G8_CBT = (HIDC/256)*(M_PAD/256);            // 360
  const int G8_ZC  = (TOKM/256)*(ZNC/256);              // 288

  // ---- prep ----
  hipMemsetAsync(NEED, 0, (size_t)N_NODESC*4, stream);
  hipMemsetAsync(DEG2, 0, (size_t)2*N_NODESC*4, stream);
  hipMemsetAsync(CNT2, 0, (size_t)2*N_NODESC*4, stream);
  k_invmask<<<1,256,0,stream>>>(mask, INVM);
  k_needed<<<(TOKM+255)/256,256,0,stream>>>(ids, NEED);
  k_need1_init<<<GD_N,256,0,stream>>>(NEED, NEED1);
  k_need_expand<<<dim3(GD_E,2),256,0,stream>>>(co_ei, re_ei, NEED, NEED1);
  k_conv<<<(HIDC*HIDC/2 + 255)/256,256,0,stream>>>(pn_W, PNWB, HIDC*HIDC/2);
  k_conv<<<(ZNC*HIDC/2 + 255)/256,256,0,stream>>>(zw, ZWALL, ZNC*HIDC/2);
  k_conv<<<(ZNC*HIDC/2 + 255)/256,256,0,stream>>>(zwp, ZWALL + (size_t)ZNC*HIDC, ZNC*HIDC/2);
  k_conv_pad<<<(M_PAD*384 + 255)/256,256,0,stream>>>(word, WORDB, N_NODESC, M_PAD);
  k_transposeW2<<<dim3((3*HIDC*384 + 255)/256, 2),256,0,stream>>>(co_W, re_W, WT2);

  // ---- batched CSR build ----
  k_degcnt2<<<dim3(GD_E,2),256,0,stream>>>(co_ei, re_ei, co_ew, re_ew, DEG2, CNT2);
  k_dinv2<<<dim3(GD_N,2),256,0,stream>>>(DEG2, DINVA, DINVB);
  k_scan1<<<dim3(NBLK,2),256,0,stream>>>(CNT2, PART2);
  k_scan2<<<2,128,0,stream>>>(PART2, RP2);
  k_scan3<<<dim3(NBLK,2),256,0,stream>>>(CNT2, PART2, RP2, CUR2);
  k_scatter2<<<dim3(GD_E,2),256,0,stream>>>(co_ei, re_ei, co_ew, re_ew, DINVA, CUR2, EMETA);

  // ---- pn path: cbT = pnW·word^T (+row bias), GT = cbT·pn^T (split-K), gather ----
  gemm8p_bf16<2><<<G8_CBT,512,G8_LDS,stream>>>(PNWB, WORDB, HIDC, M_PAD, HIDC, BUFX, pn_b);
  k_pnb<<<(128*(M_PAD/2) + 255)/256,256,0,stream>>>(png, PNB);
  hipMemsetAsync(GT, 0, (size_t)HIDC*128*4, stream);
  gemm_splitk<<<G_PN,256,0,stream>>>(BUFX, PNB, HIDC, 128, M_PAD, GT, PN_KCHUNK);
  k_gather_pn<<<GD_TOK,256,0,stream>>>(GT, cids, TOKALL + (size_t)2*TOKM*HIDC);

  // ---- GCN stacks ----
  // layer filters: L0 = none (output feeds L1 spmm reads over ~all rows);
  // L1 = NEED1 (rows read by L2's NEED-filtered spmm: NEED u sources-into-NEED);
  // L2 = NEED (rows read by token gather).  All consumed values bit-identical.
  auto run_graph = [&](int g, const float* bf, u16* tokb){
    const int* rp = RP2 + (size_t)g*NN1;
    const float2* em = EMETA + (size_t)g*NEC;
    const float* di2 = DINVB + (size_t)g*N_NODESC;
    const u16* X = WORDB;
    for(int i=0;i<3;i++){
      gemm8p_bf16<0><<<G8_GCN,512,G8_LDS,stream>>>(X, WT2 + ((size_t)g*3 + i)*HIDC*HIDC,
                                                   M_PAD, HIDC, HIDC, BUFB, nullptr);
      const u32* flt = (i==2) ? NEED : (i==1 ? NEED1 + (size_t)g*N_NODESC : nullptr);
      k_spmm<<<SPMM_GD,256,0,stream>>>(BUFB, rp, em, di2, bf + i*HIDC, BUFX, flt);
      k_gather<<<GD_TOK,256,0,stream>>>(BUFX, ids, TOKF, tokb, i);
      X = BUFX;
    }
  };
  run_graph(0, co_b, TOKALL);
  run_graph(1, re_b, TOKALL + (size_t)TOKM*HIDC);

  // ---- zero-convs -> outputs ----
  dim3 zgrid(G8_ZC, 1, 3);
  gemm8p_zc<<<zgrid,512,G8_LDS,stream>>>(TOKALL, ZWALL, zb, zbp, INVM, out);
  k_zerocol<<<(3*LLAY*4*HIDC + 255)/256,256,0,stream>>>(out);
}

// Round 4
// 1168.349 us; speedup vs baseline: 1.3107x; 1.0474x over previous
//
#include <hip/hip_runtime.h>
#include <stdint.h>

typedef unsigned int u32;
typedef unsigned short u16;
typedef __attribute__((ext_vector_type(8))) short short8;
typedef __attribute__((ext_vector_type(4))) float f32x4;

#define N_NODESC 30522
#define HIDC 768
#define NEC 488352
#define TOKM 2048
#define LLAY 12
#define NCLS 101
#define M_PAD 30720     // 120*256
#define ZNC (LLAY*HIDC) // 9216
#define OUT_SET (LLAY*4*513*HIDC)
#define PN_KCHUNK 512
#define NBLK 120
#define NN1 (N_NODESC+1)
#define G4_LDS 65536

// ---------- helpers ----------
__device__ __forceinline__ float bl(u32 u){ return __uint_as_float(u<<16); }
__device__ __forceinline__ float bh(u32 u){ return __uint_as_float(u & 0xffff0000u); }
__device__ __forceinline__ u32 f2b1(float f){ u32 x=__float_as_uint(f); return (x + 0x7fffu + ((x>>16)&1u))>>16; }
__device__ __forceinline__ u32 pack2(float a, float b){ return f2b1(a) | (f2b1(b)<<16); }

__device__ __forceinline__ void mfma16(f32x4& d, short8 a, short8 b){
  asm volatile("v_mfma_f32_16x16x32_bf16 %0, %1, %2, %0" : "+v"(d) : "v"(a), "v"(b));
}
__device__ __forceinline__ void async16(const void* g, void* l){
  __builtin_amdgcn_global_load_lds((const __attribute__((address_space(1))) u32*)g,
                                   (__attribute__((address_space(3))) u32*)l, 16, 0, 0);
}

// ---------- mask normalize ----------
__global__ void k_invmask(const void* __restrict__ mask, float* __restrict__ invm){
  __shared__ int s_byte, s_flt;
  int t = threadIdx.x;
  const unsigned char* mb = (const unsigned char*)mask;
  const u32* mw = (const u32*)mask;
  int lb=0, lf=0;
  for(int i=t;i<2048;i+=256) if((i&3)!=0 && mb[i]!=0) lb=1;
  for(int i=t;i<512;i+=256) if(mw[i]==0x3F800000u) lf=1;
  if(t==0){ s_byte=0; s_flt=0; }
  __syncthreads();
  if(lb) s_byte=1;
  if(lf) s_flt=1;
  __syncthreads();
  int mode = s_flt ? 2 : (s_byte ? 1 : 0);
  for(int p=t;p<2048;p+=256){
    int mv = (mode==1) ? (int)mb[p] : (int)(mw[p]!=0u);
    invm[p] = mv ? 0.f : 1.f;
  }
}

__global__ void k_needed(const int* __restrict__ ids, u32* __restrict__ needed){
  int p = blockIdx.x*256 + threadIdx.x;
  if(p < TOKM){ int id = ids[p]; if(id < N_NODESC) needed[id] = 1u; }
}

// frontier expansion: NEED1[g] = NEED  union  { src(e) : dst(e) in NEED }, per graph
__global__ void k_need1_init(const u32* __restrict__ needed, u32* __restrict__ need1){
  int v = blockIdx.x*256 + threadIdx.x;
  if(v < N_NODESC){ u32 x = needed[v]; need1[v] = x; need1[N_NODESC + v] = x; }
}
__global__ void k_need_expand(const int* __restrict__ coei, const int* __restrict__ reei,
                              const u32* __restrict__ needed, u32* __restrict__ need1){
  int g = blockIdx.y;
  const int* ei = g ? reei : coei;
  int e = blockIdx.x*256 + threadIdx.x;
  if(e < NEC){
    int d = ei[NEC+e];
    if(needed[d]) need1[(size_t)g*N_NODESC + ei[e]] = 1u;
  }
}

// ---------- converts ----------
__global__ void k_conv(const float* __restrict__ src, u16* __restrict__ dst, int ndw){
  int i = blockIdx.x*256 + threadIdx.x;
  if(i < ndw) ((u32*)dst)[i] = pack2(src[2*i], src[2*i+1]);
}
__global__ void k_conv_pad(const float* __restrict__ src, u16* __restrict__ dst, int srcRows, int padRows){
  int i = blockIdx.x*256 + threadIdx.x;
  if(i >= padRows*384) return;
  int row = i/384; int c2 = (i - row*384)*2;
  float lo=0.f, hi=0.f;
  if(row < srcRows){ const float* s = src + (size_t)row*HIDC + c2; lo=s[0]; hi=s[1]; }
  ((u32*)dst)[i] = pack2(lo, hi);
}
__global__ void k_pnb(const float* __restrict__ png, u16* __restrict__ pnb){
  int i = blockIdx.x*256 + threadIdx.x;
  if(i >= 128*(M_PAD/2)) return;
  int row = i/(M_PAD/2); int k2 = (i - row*(M_PAD/2))*2;
  float lo=0.f, hi=0.f;
  if(row < NCLS){
    const float* s = png + (size_t)row*N_NODESC;
    if(k2 < N_NODESC) lo = s[k2];
    if(k2+1 < N_NODESC) hi = s[k2+1];
  }
  ((u32*)pnb)[i] = pack2(lo, hi);
}
__global__ void k_transposeW2(const float* __restrict__ coW, const float* __restrict__ reW,
                              u16* __restrict__ Wt2){
  int g = blockIdx.y;
  int i = blockIdx.x*256 + threadIdx.x;
  if(i >= 3*HIDC*384) return;
  const float* W = g ? reW : coW;
  int mat = i/(HIDC*384); int rem = i - mat*HIDC*384;
  int n = rem/384; int kd = rem - n*384;
  const float* Wm = W + (size_t)mat*HIDC*HIDC;
  float lo = Wm[(size_t)(2*kd)*HIDC + n];
  float hi = Wm[(size_t)(2*kd+1)*HIDC + n];
  ((u32*)Wt2)[(size_t)g*3*HIDC*384 + (size_t)mat*HIDC*384 + (size_t)n*384 + kd] = pack2(lo, hi);
}

// ---------- batched graph prep ----------
__global__ void k_degcnt2(const int* __restrict__ coei, const int* __restrict__ reei,
                          const float* __restrict__ coew, const float* __restrict__ reew,
                          float* __restrict__ deg2, int* __restrict__ cnt2){
  int g = blockIdx.y;
  const int* ei = g ? reei : coei;
  const float* ew = g ? reew : coew;
  int e = blockIdx.x*256 + threadIdx.x;
  if(e < NEC){ int d = ei[NEC+e]; atomicAdd(&deg2[(size_t)g*N_NODESC + d], ew[e]); atomicAdd(&cnt2[(size_t)g*N_NODESC + d], 1); }
}
__global__ void k_dinv2(const float* __restrict__ deg2, float* __restrict__ dinvA, float* __restrict__ dinvB){
  int g = blockIdx.y;
  int v = blockIdx.x*256 + threadIdx.x;
  if(v < N_NODESC){
    float d = deg2[(size_t)g*N_NODESC + v] + 1.f;
    dinvA[(size_t)g*N_NODESC + v] = rsqrtf(d);
    dinvB[(size_t)g*N_NODESC + v] = 1.f/d;
  }
}
__global__ void k_scan1(const int* __restrict__ cnt2, int* __restrict__ part2){
  __shared__ int wt[4];
  int g = blockIdx.y, b = blockIdx.x, t = threadIdx.x;
  int lane = t & 63, w = t >> 6;
  int i = b*256 + t;
  int v = (i < N_NODESC) ? cnt2[(size_t)g*N_NODESC + i] : 0;
  int x = v;
  #pragma unroll
  for(int off=1; off<64; off<<=1){ int y = __shfl_up(x, off); if(lane>=off) x += y; }
  if(lane==63) wt[w] = x;
  __syncthreads();
  if(t==0) part2[g*NBLK + b] = wt[0]+wt[1]+wt[2]+wt[3];
}
__global__ void k_scan2(int* __restrict__ part2, int* __restrict__ rp2){
  __shared__ int w0tot;
  int g = blockIdx.x, t = threadIdx.x;   // 128 threads
  int lane = t & 63, w = t >> 6;
  int v = (t < NBLK) ? part2[g*NBLK + t] : 0;
  int x = v;
  #pragma unroll
  for(int off=1; off<64; off<<=1){ int y = __shfl_up(x, off); if(lane>=off) x += y; }
  if(w==0 && lane==63) w0tot = x;
  __syncthreads();
  int incl = x + (w ? w0tot : 0);
  int excl = incl - v;
  if(t < NBLK) part2[g*NBLK + t] = excl;
  if(t == 127) rp2[(size_t)g*NN1 + N_NODESC] = incl;
}
__global__ void k_scan3(const int* __restrict__ cnt2, const int* __restrict__ part2,
                        int* __restrict__ rp2, int* __restrict__ cur2){
  __shared__ int wt[4];
  int g = blockIdx.y, b = blockIdx.x, t = threadIdx.x;
  int lane = t & 63, w = t >> 6;
  int i = b*256 + t;
  int v = (i < N_NODESC) ? cnt2[(size_t)g*N_NODESC + i] : 0;
  int x = v;
  #pragma unroll
  for(int off=1; off<64; off<<=1){ int y = __shfl_up(x, off); if(lane>=off) x += y; }
  if(lane==63) wt[w] = x;
  __syncthreads();
  int wpre = 0;
  #pragma unroll
  for(int j=0;j<4;j++) if(j<w) wpre += wt[j];
  int excl = x - v + wpre + part2[g*NBLK + b];
  if(i < N_NODESC){ rp2[(size_t)g*NN1 + i] = excl; cur2[(size_t)g*N_NODESC + i] = excl; }
}
__global__ void k_scatter2(const int* __restrict__ coei, const int* __restrict__ reei,
                           const float* __restrict__ coew, const float* __restrict__ reew,
                           const float* __restrict__ dinvA, int* __restrict__ cur2,
                           float2* __restrict__ emeta){
  int g = blockIdx.y;
  const int* ei = g ? reei : coei;
  const float* ew = g ? reew : coew;
  int e = blockIdx.x*256 + threadIdx.x;
  if(e < NEC){
    int s = ei[e], d = ei[NEC+e];
    int pos = atomicAdd(&cur2[(size_t)g*N_NODESC + d], 1);
    float nrm = dinvA[(size_t)g*N_NODESC + s]*ew[e]*dinvA[(size_t)g*N_NODESC + d];
    emeta[(size_t)g*NEC + pos] = make_float2(__int_as_float(s), nrm);
  }
}

// ---------- SpMM ----------
__global__ __launch_bounds__(256)
void k_spmm(const u16* __restrict__ hW, const int* __restrict__ rp,
            const float2* __restrict__ emeta, const float* __restrict__ dinv2,
            const float* __restrict__ bias, u16* __restrict__ hout,
            const u32* __restrict__ needed){
  int v = blockIdx.x*4 + (threadIdx.x>>6);
  if(v >= N_NODESC) return;
  if(needed && !needed[v]) return;
  int lane = threadIdx.x & 63;
  const u32* H = (const u32*)hW;
  float acc[12];
  #pragma unroll
  for(int q=0;q<12;q++) acc[q]=0.f;
  int e0 = rp[v], e1 = rp[v+1];
  int e = e0;
  for(; e+4<=e1; e+=4){
    float2 m0=emeta[e], m1=emeta[e+1], m2=emeta[e+2], m3=emeta[e+3];
    const u32* r0 = H + (size_t)__float_as_int(m0.x)*384 + lane;
    const u32* r1 = H + (size_t)__float_as_int(m1.x)*384 + lane;
    const u32* r2 = H + (size_t)__float_as_int(m2.x)*384 + lane;
    const u32* r3 = H + (size_t)__float_as_int(m3.x)*384 + lane;
    u32 u0[6],u1[6],u2[6],u3[6];
    #pragma unroll
    for(int q=0;q<6;q++){ u0[q]=r0[q*64]; u1[q]=r1[q*64]; u2[q]=r2[q*64]; u3[q]=r3[q*64]; }
    #pragma unroll
    for(int q=0;q<6;q++){
      acc[2*q]   += m0.y*bl(u0[q]) + m1.y*bl(u1[q]) + m2.y*bl(u2[q]) + m3.y*bl(u3[q]);
      acc[2*q+1] += m0.y*bh(u0[q]) + m1.y*bh(u1[q]) + m2.y*bh(u2[q]) + m3.y*bh(u3[q]);
    }
  }
  for(; e<e1; ++e){
    float2 mm = emeta[e];
    const u32* r = H + (size_t)__float_as_int(mm.x)*384 + lane;
    #pragma unroll
    for(int q=0;q<6;q++){ u32 u = r[q*64]; acc[2*q] += mm.y*bl(u); acc[2*q+1] += mm.y*bh(u); }
  }
  { float wgt = dinv2[v];
    const u32* r = H + (size_t)v*384 + lane;
    #pragma unroll
    for(int q=0;q<6;q++){ u32 u = r[q*64]; acc[2*q] += wgt*bl(u); acc[2*q+1] += wgt*bh(u); }
  }
  const float2* B2 = (const float2*)bias;
  u32* O = (u32*)hout + (size_t)v*384 + lane;
  #pragma unroll
  for(int q=0;q<6;q++){
    float2 bb = B2[lane + 64*q];
    float x0 = fmaxf(acc[2*q]+bb.x, 0.f);
    float x1 = fmaxf(acc[2*q+1]+bb.y, 0.f);
    O[q*64] = pack2(x0, x1);
  }
}

// ---------- token gather ----------
__global__ void k_gather(const u16* __restrict__ h, const int* __restrict__ ids,
                         float2* __restrict__ tokf, u16* __restrict__ tokb, int phase){
  int d = blockIdx.x*256 + threadIdx.x;
  if(d >= TOKM*384) return;
  int p = d/384, q = d - p*384;
  int id = ids[p];
  float x0=0.f, x1=0.f;
  if(id < N_NODESC){ u32 u = ((const u32*)h)[(size_t)id*384 + q]; x0 = bl(u)*(1.f/3.f); x1 = bh(u)*(1.f/3.f); }
  float2 cur;
  if(phase==0){ cur.x=x0; cur.y=x1; }
  else { cur = tokf[d]; cur.x += x0; cur.y += x1; }
  if(phase==2) ((u32*)tokb)[d] = pack2(cur.x, cur.y);
  else tokf[d] = cur;
}

__global__ void k_gather_pn(const float* __restrict__ GT, const int* __restrict__ cids, u16* __restrict__ tokb){
  int d = blockIdx.x*256 + threadIdx.x;
  if(d >= TOKM*384) return;
  int p = d/384, q = d - p*384;
  int cid = cids[p];
  float lo = GT[(size_t)(2*q)*128 + cid];
  float hi = GT[(size_t)(2*q+1)*128 + cid];
  ((u32*)tokb)[d] = pack2(lo, hi);
}

__global__ void k_zerocol(float* __restrict__ out){
  int i = blockIdx.x*256 + threadIdx.x;
  if(i >= 3*LLAY*4*HIDC) return;
  int set = i/(LLAY*4*HIDC); int rem = i - set*(LLAY*4*HIDC);
  int l = rem/(4*HIDC); int rem2 = rem - l*(4*HIDC);
  int b = rem2/HIDC; int o = rem2 - b*HIDC;
  out[(size_t)set*OUT_SET + (size_t)(l*4+b)*513*HIDC + o] = 0.f;
}

// ================= 128x128 2-phase GEMM core (2 blocks/CU) =================
// LDS: buf b: A at b*32768, B at b*32768+16384 (each 128 rows x 64 cols bf16 = 16KB)
// swizzle: byte ^= ((row&7)<<4), staged via pre-swizzled global source (involution).
// Schedule per K-tile T (BK=64):  [vmcnt(8); barrier] -> ds_read ALL 16 frags to regs
// -> lgkmcnt(0) -> MFMA half(m01) -> barrier (buffers now free) -> stage T+2 into
// buf[T&1] (8 async16) -> MFMA half(m23).  2-tile prefetch lead; counted vmcnt.
#define G4_ABUF(b) ((b)*32768)
#define G4_BBUF(b) ((b)*32768 + 16384)

__device__ __forceinline__ void g4_stage(const u16* __restrict__ src, int ldk, int g0, int kt,
                                         char* base, int tid){
  const int lane = tid & 63;
  const int csw = ((lane&7) ^ (lane>>3)) << 3;   // pre-swizzled source col (elements)
  const int r = tid >> 3;                        // 0..31
  #pragma unroll
  for(int h=0; h<4; ++h)
    async16(src + (size_t)(g0 + h*32 + r)*ldk + (kt + csw), base + h*4096 + (size_t)tid*16);
}

__device__ __forceinline__ void g4_core(const u16* __restrict__ A, const u16* __restrict__ Bt,
                                        int K, int m0, int n0,
                                        f32x4 (&acc)[4][4], char* LDS, int tid){
  const int lane = tid & 63;
  const int wid = tid >> 6;
  const int wr = wid >> 1, wc = wid & 1;
  const int NK = K >> 6;   // requires NK>=2

  // prologue: T0 -> buf0, T1 -> buf1 (8 issues each)
  g4_stage(A,  K, m0,  0, LDS + G4_ABUF(0), tid);
  g4_stage(Bt, K, n0,  0, LDS + G4_BBUF(0), tid);
  g4_stage(A,  K, m0, 64, LDS + G4_ABUF(1), tid);
  g4_stage(Bt, K, n0, 64, LDS + G4_BBUF(1), tid);

  short8 af[4][2], bf[4][2];
  for(int T=0; T<NK; ++T){
    const int buf = T & 1;
    const char* Ab = LDS + G4_ABUF(buf) + wr*8192;
    const char* Bb = LDS + G4_BBUF(buf) + wc*8192;
    if(T+1 < NK) asm volatile("s_waitcnt vmcnt(8)" ::: "memory");
    else         asm volatile("s_waitcnt vmcnt(0)" ::: "memory");
    __builtin_amdgcn_sched_barrier(0);
    __builtin_amdgcn_s_barrier();
    __builtin_amdgcn_sched_barrier(0);
    #pragma unroll
    for(int m=0;m<4;m++){
      #pragma unroll
      for(int kk=0;kk<2;kk++){
        int row = (m<<4) + (lane&15);
        int cb = ((kk<<6) + ((lane>>4)<<4)) ^ ((lane&7)<<4);
        af[m][kk] = *(const short8*)(Ab + row*128 + cb);
        bf[m][kk] = *(const short8*)(Bb + row*128 + cb);
      }
    }
    asm volatile("s_waitcnt lgkmcnt(0)" ::: "memory");
    __builtin_amdgcn_sched_barrier(0);
    __builtin_amdgcn_s_setprio(1);
    #pragma unroll
    for(int m=0;m<2;m++){
      #pragma unroll
      for(int n=0;n<4;n++){
        #pragma unroll
        for(int kk=0;kk<2;kk++) mfma16(acc[m][n], af[m][kk], bf[n][kk]);
      }
    }
    __builtin_amdgcn_s_setprio(0);
    __builtin_amdgcn_sched_barrier(0);
    __builtin_amdgcn_s_barrier();     // all waves' ds_reads done -> buf free
    __builtin_amdgcn_sched_barrier(0);
    if(T+2 < NK){
      g4_stage(A,  K, m0, (T+2)<<6, LDS + G4_ABUF(buf), tid);
      g4_stage(Bt, K, n0, (T+2)<<6, LDS + G4_BBUF(buf), tid);
    }
    __builtin_amdgcn_s_setprio(1);
    #pragma unroll
    for(int m=2;m<4;m++){
      #pragma unroll
      for(int n=0;n<4;n++){
        #pragma unroll
        for(int kk=0;kk<2;kk++) mfma16(acc[m][n], af[m][kk], bf[n][kk]);
      }
    }
    __builtin_amdgcn_s_setprio(0);
    __builtin_amdgcn_sched_barrier(0);
  }
}

__device__ __forceinline__ void g_split(int ntM, int ntN, int& bm, int& bn){
  int nwg = ntM*ntN;                       // must be %8==0
  int bid = (int)blockIdx.x;
  int wg = (bid & 7)*(nwg>>3) + (bid>>3);  // XCD-chunked, bijective
  if(ntN <= ntM){ bm = wg/ntN; bn = wg - bm*ntN; }
  else          { bn = wg/ntM; bm = wg - bn*ntM; }
}

// MODE 0: bf16 out [M,N] ; MODE 2: bf16 out + per-row bias
template<int MODE>
__global__ __launch_bounds__(256,2)
void gemm4p_bf16(const u16* __restrict__ A, const u16* __restrict__ Bt,
                 int M, int N, int K,
                 u16* __restrict__ outB, const float* __restrict__ bias){
  extern __shared__ char LDS[];
  const int tid = threadIdx.x;
  const int lane = tid & 63;
  const int wid = tid >> 6;
  const int wr = wid >> 1, wc = wid & 1;
  int bm, bn;
  g_split(M>>7, N>>7, bm, bn);
  const int m0 = bm << 7, n0 = bn << 7;

  f32x4 acc[4][4];
  f32x4 zv = {0.f,0.f,0.f,0.f};
  #pragma unroll
  for(int m=0;m<4;m++){
    #pragma unroll
    for(int n=0;n<4;n++) acc[m][n] = zv;
  }
  g4_core(A, Bt, K, m0, n0, acc, LDS, tid);

  const int rbase = (lane>>4)<<2;
  const int cbase = lane & 15;
  #pragma unroll
  for(int m=0;m<4;m++){
    int row0 = m0 + (wr<<6) + (m<<4) + rbase;
    #pragma unroll
    for(int n=0;n<4;n++){
      int col = n0 + (wc<<6) + (n<<4) + cbase;
      #pragma unroll
      for(int r=0;r<4;r++){
        float v = acc[m][n][r];
        if(MODE==2) v += bias[row0+r];
        outB[(size_t)(row0+r)*N + col] = (u16)f2b1(v);
      }
    }
  }
}

// zero-conv epilogue version (3 sets via blockIdx.z); LDS-staged coalesced fp32 stores.
// Tile fp32 = 128 rows x 512B = 64KB -> single pass through the (dead) mainloop LDS.
__global__ __launch_bounds__(256,2)
void gemm4p_zc(const u16* __restrict__ TOKALL, const u16* __restrict__ ZWALL,
               const float* __restrict__ zb, const float* __restrict__ zbp,
               const float* __restrict__ invm, float* __restrict__ out){
  extern __shared__ char LDS[];
  const int set = blockIdx.z;
  const u16* A  = TOKALL + (size_t)set*TOKM*HIDC;
  const u16* Bt = ZWALL + (set==2 ? (size_t)ZNC*HIDC : 0);
  const float* bias = (set==2) ? zbp : zb;
  const bool use_mask = (set != 2);
  float* o = out + (size_t)set*OUT_SET;

  const int tid = threadIdx.x;
  const int lane = tid & 63;
  const int wid = tid >> 6;
  const int wr = wid >> 1, wc = wid & 1;
  int bm, bn;
  g_split(TOKM>>7, ZNC>>7, bm, bn);     // 16 x 72
  const int m0 = bm << 7, n0 = bn << 7;

  f32x4 acc[4][4];
  f32x4 zv = {0.f,0.f,0.f,0.f};
  #pragma unroll
  for(int m=0;m<4;m++){
    #pragma unroll
    for(int n=0;n<4;n++) acc[m][n] = zv;
  }
  g4_core(A, Bt, HIDC, m0, n0, acc, LDS, tid);

  const int l = n0 / HIDC;          // 128-col span never straddles a layer (768=6*128)
  const int oc0 = n0 - l*HIDC;
  const int lo = lane & 15, hi = lane >> 4;

  __syncthreads();                  // mainloop fully done; LDS reusable
  #pragma unroll
  for(int m=0;m<4;m++){
    #pragma unroll
    for(int n=0;n<4;n++){
      int c = (wc<<6) + (n<<4) + lo;            // 0..127
      float badd = bias[n0 + c];
      #pragma unroll
      for(int r=0;r<4;r++){
        int lr = (wr<<6) + (m<<4) + (hi<<2) + r; // 0..127
        *(float*)(LDS + (size_t)lr*512 + (((c<<2) ^ ((lr&7)<<4)))) = acc[m][n][r] + badd;
      }
    }
  }
  __syncthreads();
  // 128 rows x 512B; wave wid stores rows wid, wid+4, ... as float2/lane (full lines)
  #pragma unroll
  for(int i=0;i<32;i++){
    int lr = (i<<2) + wid;
    int rr = m0 + lr;                           // global token row
    int b = rr >> 9, s = rr & 511;
    float2 v = *(const float2*)(LDS + (size_t)lr*512 + ((lane<<3) ^ ((lr&7)<<4)));
    if(use_mask){ float w = invm[rr]; v.x *= w; v.y *= w; }
    *(float2*)(o + (size_t)((l*4+b)*513 + (s+1))*HIDC + oc0 + (lane<<1)) = v;
  }
}

// ---------- split-K GEMM (m97-style): atomics into GT ----------
__global__ __launch_bounds__(256,2)
void gemm_splitk(const u16* __restrict__ A, const u16* __restrict__ Bt,
                 int M, int N, int K, float* __restrict__ outF, int kchunk){
  __shared__ u16 As[128*64];
  __shared__ u16 Bs[128*64];
  const int t = threadIdx.x;
  const int lane = t & 63;
  const int w = t >> 6;
  const int wr = w >> 1, wc = w & 1;
  int nchunks = (K + kchunk - 1)/kchunk;
  int bm = (int)blockIdx.x / nchunks;
  int ch = (int)blockIdx.x - bm*nchunks;
  int k0 = ch*kchunk, k1 = k0 + kchunk; if(k1 > K) k1 = K;
  const int m0 = bm << 7, n0 = 0;

  f32x4 zv = {0.f,0.f,0.f,0.f};
  f32x4 acc[4][4];
  #pragma unroll
  for(int m=0;m<4;m++){
    #pragma unroll
    for(int n=0;n<4;n++) acc[m][n] = zv;
  }
  const int srow = t >> 3;
  const int scol = (t & 7) << 3;
  const u16* Ag = A + (size_t)(m0 + srow)*K + scol;
  const u16* Bg = Bt + (size_t)(n0 + srow)*K + scol;
  u16* Al = &As[t*8];
  u16* Bl = &Bs[t*8];

  for(int kt=k0; kt<k1; kt+=64){
    __syncthreads();
    #pragma unroll
    for(int i=0;i<4;i++){
      async16(Ag + (size_t)(i*32)*K + kt, Al + i*2048);
      async16(Bg + (size_t)(i*32)*K + kt, Bl + i*2048);
    }
    __syncthreads();
    #pragma unroll
    for(int kk=0; kk<64; kk+=32){
      const int ko = kk + ((lane>>4)<<3);
      short8 af[4], bfv[4];
      #pragma unroll
      for(int m=0;m<4;m++) af[m] = *(const short8*)&As[((wr<<6)+(m<<4)+(lane&15))*64 + ko];
      #pragma unroll
      for(int n=0;n<4;n++) bfv[n] = *(const short8*)&Bs[((wc<<6)+(n<<4)+(lane&15))*64 + ko];
      #pragma unroll
      for(int m=0;m<4;m++){
        #pragma unroll
        for(int n=0;n<4;n++) mfma16(acc[m][n], af[m], bfv[n]);
      }
    }
  }
  const int rbase = (lane>>4)<<2;
  const int cbase = lane & 15;
  #pragma unroll
  for(int m=0;m<4;m++){
    int row0 = m0 + (wr<<6) + (m<<4) + rbase;
    #pragma unroll
    for(int n=0;n<4;n++){
      int col = n0 + (wc<<6) + (n<<4) + cbase;
      #pragma unroll
      for(int r=0;r<4;r++) atomicAdd(&outF[(size_t)(row0+r)*N + col], acc[m][n][r]);
    }
  }
}

// ---------- host ----------
extern "C" void kernel_launch(void* const* d_in, const int* in_sizes, int n_in,
                              void* d_out, int out_size, void* d_ws, size_t ws_size,
                              hipStream_t stream){
  const float* word  = (const float*)d_in[0];
  const int*   ids   = (const int*)d_in[1];
  const int*   cids  = (const int*)d_in[2];
  const void*  mask  = d_in[3];
  const int*   co_ei = (const int*)d_in[4];
  const float* co_ew = (const float*)d_in[5];
  const int*   re_ei = (const int*)d_in[6];
  const float* re_ew = (const float*)d_in[7];
  const float* png   = (const float*)d_in[8];
  const float* co_W  = (const float*)d_in[9];
  const float* co_b  = (const float*)d_in[10];
  const float* re_W  = (const float*)d_in[11];
  const float* re_b  = (const float*)d_in[12];
  const float* pn_W  = (const float*)d_in[13];
  const float* pn_b  = (const float*)d_in[14];
  const float* zw    = (const float*)d_in[15];
  const float* zb    = (const float*)d_in[16];
  const float* zwp   = (const float*)d_in[17];
  const float* zbp   = (const float*)d_in[18];
  float* out = (float*)d_out;

  hipFuncSetAttribute((const void*)gemm4p_bf16<0>, hipFuncAttributeMaxDynamicSharedMemorySize, G4_LDS);
  hipFuncSetAttribute((const void*)gemm4p_bf16<2>, hipFuncAttributeMaxDynamicSharedMemorySize, G4_LDS);
  hipFuncSetAttribute((const void*)gemm4p_zc,      hipFuncAttributeMaxDynamicSharedMemorySize, G4_LDS);

  char* wsb = (char*)d_ws;
  size_t off = 0;
  auto alloc = [&](size_t bytes)->void*{ void* p = wsb + off; off += (bytes + 255) & ~(size_t)255; return p; };
  u16* WORDB = (u16*)alloc((size_t)M_PAD*HIDC*2);
  u16* BUFB  = (u16*)alloc((size_t)M_PAD*HIDC*2);
  u16* BUFX  = (u16*)alloc((size_t)M_PAD*HIDC*2);
  u16* ZWALL = (u16*)alloc((size_t)2*ZNC*HIDC*2);
  u16* WT2   = (u16*)alloc((size_t)2*3*HIDC*HIDC*2);
  u16* PNWB  = (u16*)alloc((size_t)HIDC*HIDC*2);
  u16* PNB   = (u16*)alloc((size_t)128*M_PAD*2);
  u16* TOKALL= (u16*)alloc((size_t)3*TOKM*HIDC*2);
  float2* TOKF = (float2*)alloc((size_t)TOKM*HIDC*4);
  float* GT   = (float*)alloc((size_t)HIDC*128*4);
  float* DEG2 = (float*)alloc((size_t)2*N_NODESC*4);
  int*   CNT2 = (int*)alloc((size_t)2*N_NODESC*4);
  float* DINVA = (float*)alloc((size_t)2*N_NODESC*4);
  float* DINVB = (float*)alloc((size_t)2*N_NODESC*4);
  int*   RP2  = (int*)alloc((size_t)2*NN1*4);
  int*   CUR2 = (int*)alloc((size_t)2*N_NODESC*4);
  int*   PART2= (int*)alloc((size_t)2*NBLK*4);
  float2* EMETA=(float2*)alloc((size_t)2*NEC*8);
  u32*   NEED = (u32*)alloc((size_t)N_NODESC*4);
  u32*   NEED1= (u32*)alloc((size_t)2*N_NODESC*4);
  float* INVM = (float*)alloc((size_t)TOKM*4);
  (void)ws_size; (void)in_sizes; (void)n_in; (void)out_size;

  const int GD_TOK = (TOKM*384 + 255)/256;
  const int GD_E   = (NEC + 255)/256;
  const int GD_N   = (N_NODESC + 255)/256;
  const int SPMM_GD  = (N_NODESC + 3)/4;
  const int PN_NCHUNKS = M_PAD/PN_KCHUNK;               // 60
  const int G_PN  = (HIDC/128)*PN_NCHUNKS;              // 360
  const int G4_GCN = (M_PAD/128)*(HIDC/128);            // 1440
  const int G4_CBT = (HIDC/128)*(M_PAD/128);            // 1440
  const int G4_ZC  = (TOKM/128)*(ZNC/128);              // 1152

  // ---- prep ----
  hipMemsetAsync(NEED, 0, (size_t)N_NODESC*4, stream);
  hipMemsetAsync(DEG2, 0, (size_t)2*N_NODESC*4, stream);
  hipMemsetAsync(CNT2, 0, (size_t)2*N_NODESC*4, stream);
  k_invmask<<<1,256,0,stream>>>(mask, INVM);
  k_needed<<<(TOKM+255)/256,256,0,stream>>>(ids, NEED);
  k_need1_init<<<GD_N,256,0,stream>>>(NEED, NEED1);
  k_need_expand<<<dim3(GD_E,2),256,0,stream>>>(co_ei, re_ei, NEED, NEED1);
  k_conv<<<(HIDC*HIDC/2 + 255)/256,256,0,stream>>>(pn_W, PNWB, HIDC*HIDC/2);
  k_conv<<<(ZNC*HIDC/2 + 255)/256,256,0,stream>>>(zw, ZWALL, ZNC*HIDC/2);
  k_conv<<<(ZNC*HIDC/2 + 255)/256,256,0,stream>>>(zwp, ZWALL + (size_t)ZNC*HIDC, ZNC*HIDC/2);
  k_conv_pad<<<(M_PAD*384 + 255)/256,256,0,stream>>>(word, WORDB, N_NODESC, M_PAD);
  k_transposeW2<<<dim3((3*HIDC*384 + 255)/256, 2),256,0,stream>>>(co_W, re_W, WT2);

  // ---- batched CSR build ----
  k_degcnt2<<<dim3(GD_E,2),256,0,stream>>>(co_ei, re_ei, co_ew, re_ew, DEG2, CNT2);
  k_dinv2<<<dim3(GD_N,2),256,0,stream>>>(DEG2, DINVA, DINVB);
  k_scan1<<<dim3(NBLK,2),256,0,stream>>>(CNT2, PART2);
  k_scan2<<<2,128,0,stream>>>(PART2, RP2);
  k_scan3<<<dim3(NBLK,2),256,0,stream>>>(CNT2, PART2, RP2, CUR2);
  k_scatter2<<<dim3(GD_E,2),256,0,stream>>>(co_ei, re_ei, co_ew, re_ew, DINVA, CUR2, EMETA);

  // ---- pn path: cbT = pnW·word^T (+row bias), GT = cbT·pn^T (split-K), gather ----
  gemm4p_bf16<2><<<G4_CBT,256,G4_LDS,stream>>>(PNWB, WORDB, HIDC, M_PAD, HIDC, BUFX, pn_b);
  k_pnb<<<(128*(M_PAD/2) + 255)/256,256,0,stream>>>(png, PNB);
  hipMemsetAsync(GT, 0, (size_t)HIDC*128*4, stream);
  gemm_splitk<<<G_PN,256,0,stream>>>(BUFX, PNB, HIDC, 128, M_PAD, GT, PN_KCHUNK);
  k_gather_pn<<<GD_TOK,256,0,stream>>>(GT, cids, TOKALL + (size_t)2*TOKM*HIDC);

  // ---- GCN stacks ----
  // layer filters: L0 = none; L1 = NEED1; L2 = NEED. All consumed values bit-identical.
  auto run_graph = [&](int g, const float* bf, u16* tokb){
    const int* rp = RP2 + (size_t)g*NN1;
    const float2* em = EMETA + (size_t)g*NEC;
    const float* di2 = DINVB + (size_t)g*N_NODESC;
    const u16* X = WORDB;
    for(int i=0;i<3;i++){
      gemm4p_bf16<0><<<G4_GCN,256,G4_LDS,stream>>>(X, WT2 + ((size_t)g*3 + i)*HIDC*HIDC,
                                                   M_PAD, HIDC, HIDC, BUFB, nullptr);
      const u32* flt = (i==2) ? NEED : (i==1 ? NEED1 + (size_t)g*N_NODESC : nullptr);
      k_spmm<<<SPMM_GD,256,0,stream>>>(BUFB, rp, em, di2, bf + i*HIDC, BUFX, flt);
      k_gather<<<GD_TOK,256,0,stream>>>(BUFX, ids, TOKF, tokb, i);
      X = BUFX;
    }
  };
  run_graph(0, co_b, TOKALL);
  run_graph(1, re_b, TOKALL + (size_t)TOKM*HIDC);

  // ---- zero-convs -> outputs ----
  dim3 zgrid(G4_ZC, 1, 3);
  gemm4p_zc<<<zgrid,256,G4_LDS,stream>>>(TOKALL, ZWALL, zb, zbp, INVM, out);
  k_zerocol<<<(3*LLAY*4*HIDC + 255)/256,256,0,stream>>>(out);
}

// Round 5
// 1139.708 us; speedup vs baseline: 1.3436x; 1.0251x over previous
//
#include <hip/hip_runtime.h>
#include <stdint.h>

typedef unsigned int u32;
typedef unsigned short u16;
typedef __attribute__((ext_vector_type(8))) short short8;
typedef __attribute__((ext_vector_type(4))) float f32x4;

#define N_NODESC 30522
#define HIDC 768
#define NEC 488352
#define TOKM 2048
#define LLAY 12
#define NCLS 101
#define M_PAD 30720     // 120*256
#define ZNC (LLAY*HIDC) // 9216
#define OUT_SET (LLAY*4*513*HIDC)
#define PN_KCHUNK 512
#define NBLK 120
#define NN1 (N_NODESC+1)
#define G4_LDS 65536
#define G8_LDS 131072

// ---------- helpers ----------
__device__ __forceinline__ float bl(u32 u){ return __uint_as_float(u<<16); }
__device__ __forceinline__ float bh(u32 u){ return __uint_as_float(u & 0xffff0000u); }
__device__ __forceinline__ u32 f2b1(float f){ u32 x=__float_as_uint(f); return (x + 0x7fffu + ((x>>16)&1u))>>16; }
__device__ __forceinline__ u32 pack2(float a, float b){ return f2b1(a) | (f2b1(b)<<16); }

__device__ __forceinline__ void mfma16(f32x4& d, short8 a, short8 b){
  asm volatile("v_mfma_f32_16x16x32_bf16 %0, %1, %2, %0" : "+v"(d) : "v"(a), "v"(b));
}
__device__ __forceinline__ void async16(const void* g, void* l){
  __builtin_amdgcn_global_load_lds((const __attribute__((address_space(1))) u32*)g,
                                   (__attribute__((address_space(3))) u32*)l, 16, 0, 0);
}

// ---------- mask normalize ----------
__global__ void k_invmask(const void* __restrict__ mask, float* __restrict__ invm){
  __shared__ int s_byte, s_flt;
  int t = threadIdx.x;
  const unsigned char* mb = (const unsigned char*)mask;
  const u32* mw = (const u32*)mask;
  int lb=0, lf=0;
  for(int i=t;i<2048;i+=256) if((i&3)!=0 && mb[i]!=0) lb=1;
  for(int i=t;i<512;i+=256) if(mw[i]==0x3F800000u) lf=1;
  if(t==0){ s_byte=0; s_flt=0; }
  __syncthreads();
  if(lb) s_byte=1;
  if(lf) s_flt=1;
  __syncthreads();
  int mode = s_flt ? 2 : (s_byte ? 1 : 0);
  for(int p=t;p<2048;p+=256){
    int mv = (mode==1) ? (int)mb[p] : (int)(mw[p]!=0u);
    invm[p] = mv ? 0.f : 1.f;
  }
}

__global__ void k_needed(const int* __restrict__ ids, u32* __restrict__ needed){
  int p = blockIdx.x*256 + threadIdx.x;
  if(p < TOKM){ int id = ids[p]; if(id < N_NODESC) needed[id] = 1u; }
}

// frontier expansion: NEED1[g] = NEED  union  { src(e) : dst(e) in NEED }, per graph
__global__ void k_need1_init(const u32* __restrict__ needed, u32* __restrict__ need1){
  int v = blockIdx.x*256 + threadIdx.x;
  if(v < N_NODESC){ u32 x = needed[v]; need1[v] = x; need1[N_NODESC + v] = x; }
}
__global__ void k_need_expand(const int* __restrict__ coei, const int* __restrict__ reei,
                              const u32* __restrict__ needed, u32* __restrict__ need1){
  int g = blockIdx.y;
  const int* ei = g ? reei : coei;
  int e = blockIdx.x*256 + threadIdx.x;
  if(e < NEC){
    int d = ei[NEC+e];
    if(needed[d]) need1[(size_t)g*N_NODESC + ei[e]] = 1u;
  }
}

// ---------- converts ----------
__global__ void k_conv(const float* __restrict__ src, u16* __restrict__ dst, int ndw){
  int i = blockIdx.x*256 + threadIdx.x;
  if(i < ndw) ((u32*)dst)[i] = pack2(src[2*i], src[2*i+1]);
}
__global__ void k_conv_pad(const float* __restrict__ src, u16* __restrict__ dst, int srcRows, int padRows){
  int i = blockIdx.x*256 + threadIdx.x;
  if(i >= padRows*384) return;
  int row = i/384; int c2 = (i - row*384)*2;
  float lo=0.f, hi=0.f;
  if(row < srcRows){ const float* s = src + (size_t)row*HIDC + c2; lo=s[0]; hi=s[1]; }
  ((u32*)dst)[i] = pack2(lo, hi);
}
__global__ void k_pnb(const float* __restrict__ png, u16* __restrict__ pnb){
  int i = blockIdx.x*256 + threadIdx.x;
  if(i >= 128*(M_PAD/2)) return;
  int row = i/(M_PAD/2); int k2 = (i - row*(M_PAD/2))*2;
  float lo=0.f, hi=0.f;
  if(row < NCLS){
    const float* s = png + (size_t)row*N_NODESC;
    if(k2 < N_NODESC) lo = s[k2];
    if(k2+1 < N_NODESC) hi = s[k2+1];
  }
  ((u32*)pnb)[i] = pack2(lo, hi);
}
__global__ void k_transposeW2(const float* __restrict__ coW, const float* __restrict__ reW,
                              u16* __restrict__ Wt2){
  int g = blockIdx.y;
  int i = blockIdx.x*256 + threadIdx.x;
  if(i >= 3*HIDC*384) return;
  const float* W = g ? reW : coW;
  int mat = i/(HIDC*384); int rem = i - mat*HIDC*384;
  int n = rem/384; int kd = rem - n*384;
  const float* Wm = W + (size_t)mat*HIDC*HIDC;
  float lo = Wm[(size_t)(2*kd)*HIDC + n];
  float hi = Wm[(size_t)(2*kd+1)*HIDC + n];
  ((u32*)Wt2)[(size_t)g*3*HIDC*384 + (size_t)mat*HIDC*384 + (size_t)n*384 + kd] = pack2(lo, hi);
}

// ---------- batched graph prep ----------
__global__ void k_degcnt2(const int* __restrict__ coei, const int* __restrict__ reei,
                          const float* __restrict__ coew, const float* __restrict__ reew,
                          float* __restrict__ deg2, int* __restrict__ cnt2){
  int g = blockIdx.y;
  const int* ei = g ? reei : coei;
  const float* ew = g ? reew : coew;
  int e = blockIdx.x*256 + threadIdx.x;
  if(e < NEC){ int d = ei[NEC+e]; atomicAdd(&deg2[(size_t)g*N_NODESC + d], ew[e]); atomicAdd(&cnt2[(size_t)g*N_NODESC + d], 1); }
}
__global__ void k_dinv2(const float* __restrict__ deg2, float* __restrict__ dinvA, float* __restrict__ dinvB){
  int g = blockIdx.y;
  int v = blockIdx.x*256 + threadIdx.x;
  if(v < N_NODESC){
    float d = deg2[(size_t)g*N_NODESC + v] + 1.f;
    dinvA[(size_t)g*N_NODESC + v] = rsqrtf(d);
    dinvB[(size_t)g*N_NODESC + v] = 1.f/d;
  }
}
__global__ void k_scan1(const int* __restrict__ cnt2, int* __restrict__ part2){
  __shared__ int wt[4];
  int g = blockIdx.y, b = blockIdx.x, t = threadIdx.x;
  int lane = t & 63, w = t >> 6;
  int i = b*256 + t;
  int v = (i < N_NODESC) ? cnt2[(size_t)g*N_NODESC + i] : 0;
  int x = v;
  #pragma unroll
  for(int off=1; off<64; off<<=1){ int y = __shfl_up(x, off); if(lane>=off) x += y; }
  if(lane==63) wt[w] = x;
  __syncthreads();
  if(t==0) part2[g*NBLK + b] = wt[0]+wt[1]+wt[2]+wt[3];
}
__global__ void k_scan2(int* __restrict__ part2, int* __restrict__ rp2){
  __shared__ int w0tot;
  int g = blockIdx.x, t = threadIdx.x;   // 128 threads
  int lane = t & 63, w = t >> 6;
  int v = (t < NBLK) ? part2[g*NBLK + t] : 0;
  int x = v;
  #pragma unroll
  for(int off=1; off<64; off<<=1){ int y = __shfl_up(x, off); if(lane>=off) x += y; }
  if(w==0 && lane==63) w0tot = x;
  __syncthreads();
  int incl = x + (w ? w0tot : 0);
  int excl = incl - v;
  if(t < NBLK) part2[g*NBLK + t] = excl;
  if(t == 127) rp2[(size_t)g*NN1 + N_NODESC] = incl;
}
__global__ void k_scan3(const int* __restrict__ cnt2, const int* __restrict__ part2,
                        int* __restrict__ rp2, int* __restrict__ cur2){
  __shared__ int wt[4];
  int g = blockIdx.y, b = blockIdx.x, t = threadIdx.x;
  int lane = t & 63, w = t >> 6;
  int i = b*256 + t;
  int v = (i < N_NODESC) ? cnt2[(size_t)g*N_NODESC + i] : 0;
  int x = v;
  #pragma unroll
  for(int off=1; off<64; off<<=1){ int y = __shfl_up(x, off); if(lane>=off) x += y; }
  if(lane==63) wt[w] = x;
  __syncthreads();
  int wpre = 0;
  #pragma unroll
  for(int j=0;j<4;j++) if(j<w) wpre += wt[j];
  int excl = x - v + wpre + part2[g*NBLK + b];
  if(i < N_NODESC){ rp2[(size_t)g*NN1 + i] = excl; cur2[(size_t)g*N_NODESC + i] = excl; }
}
__global__ void k_scatter2(const int* __restrict__ coei, const int* __restrict__ reei,
                           const float* __restrict__ coew, const float* __restrict__ reew,
                           const float* __restrict__ dinvA, int* __restrict__ cur2,
                           float2* __restrict__ emeta){
  int g = blockIdx.y;
  const int* ei = g ? reei : coei;
  const float* ew = g ? reew : coew;
  int e = blockIdx.x*256 + threadIdx.x;
  if(e < NEC){
    int s = ei[e], d = ei[NEC+e];
    int pos = atomicAdd(&cur2[(size_t)g*N_NODESC + d], 1);
    float nrm = dinvA[(size_t)g*N_NODESC + s]*ew[e]*dinvA[(size_t)g*N_NODESC + d];
    emeta[(size_t)g*NEC + pos] = make_float2(__int_as_float(s), nrm);
  }
}

// ---------- SpMM ----------
__global__ __launch_bounds__(256)
void k_spmm(const u16* __restrict__ hW, const int* __restrict__ rp,
            const float2* __restrict__ emeta, const float* __restrict__ dinv2,
            const float* __restrict__ bias, u16* __restrict__ hout,
            const u32* __restrict__ needed){
  int v = blockIdx.x*4 + (threadIdx.x>>6);
  if(v >= N_NODESC) return;
  if(needed && !needed[v]) return;
  int lane = threadIdx.x & 63;
  const u32* H = (const u32*)hW;
  float acc[12];
  #pragma unroll
  for(int q=0;q<12;q++) acc[q]=0.f;
  int e0 = rp[v], e1 = rp[v+1];
  int e = e0;
  for(; e+4<=e1; e+=4){
    float2 m0=emeta[e], m1=emeta[e+1], m2=emeta[e+2], m3=emeta[e+3];
    const u32* r0 = H + (size_t)__float_as_int(m0.x)*384 + lane;
    const u32* r1 = H + (size_t)__float_as_int(m1.x)*384 + lane;
    const u32* r2 = H + (size_t)__float_as_int(m2.x)*384 + lane;
    const u32* r3 = H + (size_t)__float_as_int(m3.x)*384 + lane;
    u32 u0[6],u1[6],u2[6],u3[6];
    #pragma unroll
    for(int q=0;q<6;q++){ u0[q]=r0[q*64]; u1[q]=r1[q*64]; u2[q]=r2[q*64]; u3[q]=r3[q*64]; }
    #pragma unroll
    for(int q=0;q<6;q++){
      acc[2*q]   += m0.y*bl(u0[q]) + m1.y*bl(u1[q]) + m2.y*bl(u2[q]) + m3.y*bl(u3[q]);
      acc[2*q+1] += m0.y*bh(u0[q]) + m1.y*bh(u1[q]) + m2.y*bh(u2[q]) + m3.y*bh(u3[q]);
    }
  }
  for(; e<e1; ++e){
    float2 mm = emeta[e];
    const u32* r = H + (size_t)__float_as_int(mm.x)*384 + lane;
    #pragma unroll
    for(int q=0;q<6;q++){ u32 u = r[q*64]; acc[2*q] += mm.y*bl(u); acc[2*q+1] += mm.y*bh(u); }
  }
  { float wgt = dinv2[v];
    const u32* r = H + (size_t)v*384 + lane;
    #pragma unroll
    for(int q=0;q<6;q++){ u32 u = r[q*64]; acc[2*q] += wgt*bl(u); acc[2*q+1] += wgt*bh(u); }
  }
  const float2* B2 = (const float2*)bias;
  u32* O = (u32*)hout + (size_t)v*384 + lane;
  #pragma unroll
  for(int q=0;q<6;q++){
    float2 bb = B2[lane + 64*q];
    float x0 = fmaxf(acc[2*q]+bb.x, 0.f);
    float x1 = fmaxf(acc[2*q+1]+bb.y, 0.f);
    O[q*64] = pack2(x0, x1);
  }
}

// ---------- token gather ----------
__global__ void k_gather(const u16* __restrict__ h, const int* __restrict__ ids,
                         float2* __restrict__ tokf, u16* __restrict__ tokb, int phase){
  int d = blockIdx.x*256 + threadIdx.x;
  if(d >= TOKM*384) return;
  int p = d/384, q = d - p*384;
  int id = ids[p];
  float x0=0.f, x1=0.f;
  if(id < N_NODESC){ u32 u = ((const u32*)h)[(size_t)id*384 + q]; x0 = bl(u)*(1.f/3.f); x1 = bh(u)*(1.f/3.f); }
  float2 cur;
  if(phase==0){ cur.x=x0; cur.y=x1; }
  else { cur = tokf[d]; cur.x += x0; cur.y += x1; }
  if(phase==2) ((u32*)tokb)[d] = pack2(cur.x, cur.y);
  else tokf[d] = cur;
}

__global__ void k_gather_pn(const float* __restrict__ GT, const int* __restrict__ cids, u16* __restrict__ tokb){
  int d = blockIdx.x*256 + threadIdx.x;
  if(d >= TOKM*384) return;
  int p = d/384, q = d - p*384;
  int cid = cids[p];
  float lo = GT[(size_t)(2*q)*128 + cid];
  float hi = GT[(size_t)(2*q+1)*128 + cid];
  ((u32*)tokb)[d] = pack2(lo, hi);
}

__global__ void k_zerocol(float* __restrict__ out){
  int i = blockIdx.x*256 + threadIdx.x;
  if(i >= 3*LLAY*4*HIDC) return;
  int set = i/(LLAY*4*HIDC); int rem = i - set*(LLAY*4*HIDC);
  int l = rem/(4*HIDC); int rem2 = rem - l*(4*HIDC);
  int b = rem2/HIDC; int o = rem2 - b*HIDC;
  out[(size_t)set*OUT_SET + (size_t)(l*4+b)*513*HIDC + o] = 0.f;
}

// ---------- XCD-chunked bijective block split (shared) ----------
__device__ __forceinline__ void g_split(int ntM, int ntN, int& bm, int& bn){
  int nwg = ntM*ntN;                       // must be %8==0
  int bid = (int)blockIdx.x;
  int wg = (bid & 7)*(nwg>>3) + (bid>>3);  // XCD-chunked, bijective
  if(ntN <= ntM){ bm = wg/ntN; bn = wg - bm*ntN; }
  else          { bn = wg/ntM; bm = wg - bn*ntM; }
}

// ================= 256x256 8-phase GEMM core (1 block/CU) — used for zc =================
#define G8_AOFF(b) ((b)*65536)
#define G8_BOFF(b) ((b)*65536 + 32768)

__device__ __forceinline__ void g8_stage(const u16* __restrict__ src, int ldk, int g0, int kt,
                                         char* half_base, int tid){
  const int lane = tid & 63;
  const int csw = ((lane&7) ^ (lane>>3)) << 3;   // pre-swizzled source col (elements)
  const u16* s0 = src + (size_t)(g0 + (tid>>3))*ldk + (kt + csw);
  const u16* s1 = src + (size_t)(g0 + 64 + (tid>>3))*ldk + (kt + csw);
  async16(s0, half_base + (size_t)tid*16);
  async16(s1, half_base + 8192 + (size_t)tid*16);
}

__device__ __forceinline__ void g8_core(const u16* __restrict__ A, const u16* __restrict__ Bt,
                                        int K, int m0, int n0,
                                        f32x4 (&acc)[8][4], char* LDS, int tid){
  const int lane = tid & 63;
  const int wid = tid >> 6;
  const int wr = wid >> 2, wc = wid & 3;
  const int NK = K >> 6;   // K-tiles (BK=64); requires NK>=3, even

  g8_stage(Bt, K, n0,      0, LDS + G8_BOFF(0),         tid);
  g8_stage(Bt, K, n0+128,  0, LDS + G8_BOFF(0) + 16384, tid);
  g8_stage(A,  K, m0,      0, LDS + G8_AOFF(0),         tid);
  g8_stage(A,  K, m0+128,  0, LDS + G8_AOFF(0) + 16384, tid);
  g8_stage(Bt, K, n0,     64, LDS + G8_BOFF(1),         tid);
  g8_stage(Bt, K, n0+128, 64, LDS + G8_BOFF(1) + 16384, tid);
  asm volatile("s_waitcnt vmcnt(4)" ::: "memory");
  __builtin_amdgcn_sched_barrier(0);
  __builtin_amdgcn_s_barrier();
  __builtin_amdgcn_sched_barrier(0);

  short8 bf8[8];
  for(int T=0; T<NK; ++T){
    const int buf = T & 1;
    const char* Ab = LDS + G8_AOFF(buf) + wr*16384;
    const char* Bb = LDS + G8_BOFF(buf) + (wc>>1)*16384;
    #pragma unroll
    for(int q=0; q<4; ++q){
      if(q==0){
        #pragma unroll
        for(int n=0;n<4;n++){
          #pragma unroll
          for(int kk=0;kk<2;kk++){
            int row = ((wc&1)<<6) + (n<<4) + (lane&15);
            int cb = ((kk<<6) + ((lane>>4)<<4)) ^ ((lane&7)<<4);
            bf8[n*2+kk] = *(const short8*)(Bb + row*128 + cb);
          }
        }
      }
      short8 af[2][2];
      #pragma unroll
      for(int j=0;j<2;j++){
        #pragma unroll
        for(int kk=0;kk<2;kk++){
          int row = ((2*q+j)<<4) + (lane&15);
          int cb = ((kk<<6) + ((lane>>4)<<4)) ^ ((lane&7)<<4);
          af[j][kk] = *(const short8*)(Ab + row*128 + cb);
        }
      }
      if(q==0 && T+1<NK) g8_stage(A,  K, m0,      (T+1)<<6, LDS + G8_AOFF((T+1)&1),         tid);
      if(q==1 && T+1<NK) g8_stage(A,  K, m0+128,  (T+1)<<6, LDS + G8_AOFF((T+1)&1) + 16384, tid);
      if(q==2 && T+2<NK) g8_stage(Bt, K, n0,      (T+2)<<6, LDS + G8_BOFF(buf),             tid);
      if(q==3 && T+2<NK) g8_stage(Bt, K, n0+128,  (T+2)<<6, LDS + G8_BOFF(buf) + 16384,     tid);
      if(q==3){
        if(T <= NK-3)      asm volatile("s_waitcnt vmcnt(4)" ::: "memory");
        else if(T == NK-2) asm volatile("s_waitcnt vmcnt(0)" ::: "memory");
      }
      __builtin_amdgcn_sched_barrier(0);
      __builtin_amdgcn_s_barrier();
      __builtin_amdgcn_sched_barrier(0);
      __builtin_amdgcn_s_setprio(1);
      #pragma unroll
      for(int j=0;j<2;j++){
        #pragma unroll
        for(int n=0;n<4;n++){
          #pragma unroll
          for(int kk=0;kk<2;kk++) mfma16(acc[2*q+j][n], af[j][kk], bf8[n*2+kk]);
        }
      }
      __builtin_amdgcn_s_setprio(0);
      __builtin_amdgcn_sched_barrier(0);
      __builtin_amdgcn_s_barrier();
      __builtin_amdgcn_sched_barrier(0);
    }
  }
}

// zero-conv GEMM (3 sets via blockIdx.z), g8 core + LDS-staged coalesced fp32 stores
__global__ __launch_bounds__(512,2)
void gemm8p_zc(const u16* __restrict__ TOKALL, const u16* __restrict__ ZWALL,
               const float* __restrict__ zb, const float* __restrict__ zbp,
               const float* __restrict__ invm, float* __restrict__ out){
  extern __shared__ char LDS[];
  const int set = blockIdx.z;
  const u16* A  = TOKALL + (size_t)set*TOKM*HIDC;
  const u16* Bt = ZWALL + (set==2 ? (size_t)ZNC*HIDC : 0);
  const float* bias = (set==2) ? zbp : zb;
  const bool use_mask = (set != 2);
  float* o = out + (size_t)set*OUT_SET;

  const int tid = threadIdx.x;
  const int lane = tid & 63;
  const int wid = tid >> 6;
  const int wr = wid >> 2, wc = wid & 3;
  int bm, bn;
  g_split(TOKM>>8, ZNC>>8, bm, bn);     // 8 x 36
  const int m0 = bm << 8, n0 = bn << 8;

  f32x4 acc[8][4];
  f32x4 zv = {0.f,0.f,0.f,0.f};
  #pragma unroll
  for(int m=0;m<8;m++){
    #pragma unroll
    for(int n=0;n<4;n++) acc[m][n] = zv;
  }
  g8_core(A, Bt, HIDC, m0, n0, acc, LDS, tid);

  const int l = n0 / HIDC;
  const int oc0 = n0 - l*HIDC;
  const int lo = lane & 15, hi = lane >> 4;

  #pragma unroll
  for(int pass=0; pass<2; ++pass){
    __syncthreads();
    if(wr == pass){
      #pragma unroll
      for(int m=0;m<8;m++){
        #pragma unroll
        for(int n=0;n<4;n++){
          int col = (wc<<6) + (n<<4) + lo;      // 0..255
          float badd = bias[n0 + col];
          #pragma unroll
          for(int r=0;r<4;r++){
            int lr = (m<<4) + (hi<<2) + r;      // 0..127
            *(float*)(LDS + (size_t)lr*1024 + ((col<<2) ^ ((lr&7)<<4))) = acc[m][n][r] + badd;
          }
        }
      }
    }
    __syncthreads();
    #pragma unroll
    for(int i=0;i<16;i++){
      int lr = (i<<3) + wid;
      int rr = m0 + (pass<<7) + lr;             // global token row
      int b = rr >> 9, s = rr & 511;
      f32x4 v = *(const f32x4*)(LDS + (size_t)lr*1024 + ((lane<<4) ^ ((lr&7)<<4)));
      if(use_mask){ float w = invm[rr]; v = v * w; }
      *(f32x4*)(o + (size_t)((l*4+b)*513 + (s+1))*HIDC + oc0 + (lane<<2)) = v;
    }
  }
}

// ================= 128x128 2-phase GEMM core (2 blocks/CU) — used for GCN/CBT =================
#define G4_ABUF(b) ((b)*32768)
#define G4_BBUF(b) ((b)*32768 + 16384)

__device__ __forceinline__ void g4_stage(const u16* __restrict__ src, int ldk, int g0, int kt,
                                         char* base, int tid){
  const int lane = tid & 63;
  const int csw = ((lane&7) ^ (lane>>3)) << 3;   // pre-swizzled source col (elements)
  const int r = tid >> 3;                        // 0..31
  #pragma unroll
  for(int h=0; h<4; ++h)
    async16(src + (size_t)(g0 + h*32 + r)*ldk + (kt + csw), base + h*4096 + (size_t)tid*16);
}

__device__ __forceinline__ void g4_core(const u16* __restrict__ A, const u16* __restrict__ Bt,
                                        int K, int m0, int n0,
                                        f32x4 (&acc)[4][4], char* LDS, int tid){
  const int lane = tid & 63;
  const int wid = tid >> 6;
  const int wr = wid >> 1, wc = wid & 1;
  const int NK = K >> 6;   // requires NK>=2

  g4_stage(A,  K, m0,  0, LDS + G4_ABUF(0), tid);
  g4_stage(Bt, K, n0,  0, LDS + G4_BBUF(0), tid);
  g4_stage(A,  K, m0, 64, LDS + G4_ABUF(1), tid);
  g4_stage(Bt, K, n0, 64, LDS + G4_BBUF(1), tid);

  short8 af[4][2], bf[4][2];
  for(int T=0; T<NK; ++T){
    const int buf = T & 1;
    const char* Ab = LDS + G4_ABUF(buf) + wr*8192;
    const char* Bb = LDS + G4_BBUF(buf) + wc*8192;
    if(T+1 < NK) asm volatile("s_waitcnt vmcnt(8)" ::: "memory");
    else         asm volatile("s_waitcnt vmcnt(0)" ::: "memory");
    __builtin_amdgcn_sched_barrier(0);
    __builtin_amdgcn_s_barrier();
    __builtin_amdgcn_sched_barrier(0);
    #pragma unroll
    for(int m=0;m<4;m++){
      #pragma unroll
      for(int kk=0;kk<2;kk++){
        int row = (m<<4) + (lane&15);
        int cb = ((kk<<6) + ((lane>>4)<<4)) ^ ((lane&7)<<4);
        af[m][kk] = *(const short8*)(Ab + row*128 + cb);
        bf[m][kk] = *(const short8*)(Bb + row*128 + cb);
      }
    }
    asm volatile("s_waitcnt lgkmcnt(0)" ::: "memory");
    __builtin_amdgcn_sched_barrier(0);
    __builtin_amdgcn_s_setprio(1);
    #pragma unroll
    for(int m=0;m<2;m++){
      #pragma unroll
      for(int n=0;n<4;n++){
        #pragma unroll
        for(int kk=0;kk<2;kk++) mfma16(acc[m][n], af[m][kk], bf[n][kk]);
      }
    }
    __builtin_amdgcn_s_setprio(0);
    __builtin_amdgcn_sched_barrier(0);
    __builtin_amdgcn_s_barrier();     // all waves' ds_reads done -> buf free
    __builtin_amdgcn_sched_barrier(0);
    if(T+2 < NK){
      g4_stage(A,  K, m0, (T+2)<<6, LDS + G4_ABUF(buf), tid);
      g4_stage(Bt, K, n0, (T+2)<<6, LDS + G4_BBUF(buf), tid);
    }
    __builtin_amdgcn_s_setprio(1);
    #pragma unroll
    for(int m=2;m<4;m++){
      #pragma unroll
      for(int n=0;n<4;n++){
        #pragma unroll
        for(int kk=0;kk<2;kk++) mfma16(acc[m][n], af[m][kk], bf[n][kk]);
      }
    }
    __builtin_amdgcn_s_setprio(0);
    __builtin_amdgcn_sched_barrier(0);
  }
}

// MODE 0: bf16 out [M,N] ; MODE 2: bf16 out + per-row bias
template<int MODE>
__global__ __launch_bounds__(256,2)
void gemm4p_bf16(const u16* __restrict__ A, const u16* __restrict__ Bt,
                 int M, int N, int K,
                 u16* __restrict__ outB, const float* __restrict__ bias){
  extern __shared__ char LDS[];
  const int tid = threadIdx.x;
  const int lane = tid & 63;
  const int wid = tid >> 6;
  const int wr = wid >> 1, wc = wid & 1;
  int bm, bn;
  g_split(M>>7, N>>7, bm, bn);
  const int m0 = bm << 7, n0 = bn << 7;

  f32x4 acc[4][4];
  f32x4 zv = {0.f,0.f,0.f,0.f};
  #pragma unroll
  for(int m=0;m<4;m++){
    #pragma unroll
    for(int n=0;n<4;n++) acc[m][n] = zv;
  }
  g4_core(A, Bt, K, m0, n0, acc, LDS, tid);

  const int rbase = (lane>>4)<<2;
  const int cbase = lane & 15;
  #pragma unroll
  for(int m=0;m<4;m++){
    int row0 = m0 + (wr<<6) + (m<<4) + rbase;
    #pragma unroll
    for(int n=0;n<4;n++){
      int col = n0 + (wc<<6) + (n<<4) + cbase;
      #pragma unroll
      for(int r=0;r<4;r++){
        float v = acc[m][n][r];
        if(MODE==2) v += bias[row0+r];
        outB[(size_t)(row0+r)*N + col] = (u16)f2b1(v);
      }
    }
  }
}

// ---------- split-K GEMM (m97-style): atomics into GT ----------
__global__ __launch_bounds__(256,2)
void gemm_splitk(const u16* __restrict__ A, const u16* __restrict__ Bt,
                 int M, int N, int K, float* __restrict__ outF, int kchunk){
  __shared__ u16 As[128*64];
  __shared__ u16 Bs[128*64];
  const int t = threadIdx.x;
  const int lane = t & 63;
  const int w = t >> 6;
  const int wr = w >> 1, wc = w & 1;
  int nchunks = (K + kchunk - 1)/kchunk;
  int bm = (int)blockIdx.x / nchunks;
  int ch = (int)blockIdx.x - bm*nchunks;
  int k0 = ch*kchunk, k1 = k0 + kchunk; if(k1 > K) k1 = K;
  const int m0 = bm << 7, n0 = 0;

  f32x4 zv = {0.f,0.f,0.f,0.f};
  f32x4 acc[4][4];
  #pragma unroll
  for(int m=0;m<4;m++){
    #pragma unroll
    for(int n=0;n<4;n++) acc[m][n] = zv;
  }
  const int srow = t >> 3;
  const int scol = (t & 7) << 3;
  const u16* Ag = A + (size_t)(m0 + srow)*K + scol;
  const u16* Bg = Bt + (size_t)(n0 + srow)*K + scol;
  u16* Al = &As[t*8];
  u16* Bl = &Bs[t*8];

  for(int kt=k0; kt<k1; kt+=64){
    __syncthreads();
    #pragma unroll
    for(int i=0;i<4;i++){
      async16(Ag + (size_t)(i*32)*K + kt, Al + i*2048);
      async16(Bg + (size_t)(i*32)*K + kt, Bl + i*2048);
    }
    __syncthreads();
    #pragma unroll
    for(int kk=0; kk<64; kk+=32){
      const int ko = kk + ((lane>>4)<<3);
      short8 af[4], bfv[4];
      #pragma unroll
      for(int m=0;m<4;m++) af[m] = *(const short8*)&As[((wr<<6)+(m<<4)+(lane&15))*64 + ko];
      #pragma unroll
      for(int n=0;n<4;n++) bfv[n] = *(const short8*)&Bs[((wc<<6)+(n<<4)+(lane&15))*64 + ko];
      #pragma unroll
      for(int m=0;m<4;m++){
        #pragma unroll
        for(int n=0;n<4;n++) mfma16(acc[m][n], af[m], bfv[n]);
      }
    }
  }
  const int rbase = (lane>>4)<<2;
  const int cbase = lane & 15;
  #pragma unroll
  for(int m=0;m<4;m++){
    int row0 = m0 + (wr<<6) + (m<<4) + rbase;
    #pragma unroll
    for(int n=0;n<4;n++){
      int col = n0 + (wc<<6) + (n<<4) + cbase;
      #pragma unroll
      for(int r=0;r<4;r++) atomicAdd(&outF[(size_t)(row0+r)*N + col], acc[m][n][r]);
    }
  }
}

// ---------- host ----------
extern "C" void kernel_launch(void* const* d_in, const int* in_sizes, int n_in,
                              void* d_out, int out_size, void* d_ws, size_t ws_size,
                              hipStream_t stream){
  const float* word  = (const float*)d_in[0];
  const int*   ids   = (const int*)d_in[1];
  const int*   cids  = (const int*)d_in[2];
  const void*  mask  = d_in[3];
  const int*   co_ei = (const int*)d_in[4];
  const float* co_ew = (const float*)d_in[5];
  const int*   re_ei = (const int*)d_in[6];
  const float* re_ew = (const float*)d_in[7];
  const float* png   = (const float*)d_in[8];
  const float* co_W  = (const float*)d_in[9];
  const float* co_b  = (const float*)d_in[10];
  const float* re_W  = (const float*)d_in[11];
  const float* re_b  = (const float*)d_in[12];
  const float* pn_W  = (const float*)d_in[13];
  const float* pn_b  = (const float*)d_in[14];
  const float* zw    = (const float*)d_in[15];
  const float* zb    = (const float*)d_in[16];
  const float* zwp   = (const float*)d_in[17];
  const float* zbp   = (const float*)d_in[18];
  float* out = (float*)d_out;

  hipFuncSetAttribute((const void*)gemm4p_bf16<0>, hipFuncAttributeMaxDynamicSharedMemorySize, G4_LDS);
  hipFuncSetAttribute((const void*)gemm4p_bf16<2>, hipFuncAttributeMaxDynamicSharedMemorySize, G4_LDS);
  hipFuncSetAttribute((const void*)gemm8p_zc,      hipFuncAttributeMaxDynamicSharedMemorySize, G8_LDS);

  char* wsb = (char*)d_ws;
  size_t off = 0;
  auto alloc = [&](size_t bytes)->void*{ void* p = wsb + off; off += (bytes + 255) & ~(size_t)255; return p; };
  u16* WORDB = (u16*)alloc((size_t)M_PAD*HIDC*2);
  u16* BUFB  = (u16*)alloc((size_t)M_PAD*HIDC*2);
  u16* BUFX  = (u16*)alloc((size_t)M_PAD*HIDC*2);
  u16* ZWALL = (u16*)alloc((size_t)2*ZNC*HIDC*2);
  u16* WT2   = (u16*)alloc((size_t)2*3*HIDC*HIDC*2);
  u16* PNWB  = (u16*)alloc((size_t)HIDC*HIDC*2);
  u16* PNB   = (u16*)alloc((size_t)128*M_PAD*2);
  u16* TOKALL= (u16*)alloc((size_t)3*TOKM*HIDC*2);
  float2* TOKF = (float2*)alloc((size_t)TOKM*HIDC*4);
  float* GT   = (float*)alloc((size_t)HIDC*128*4);
  float* DEG2 = (float*)alloc((size_t)2*N_NODESC*4);
  int*   CNT2 = (int*)alloc((size_t)2*N_NODESC*4);
  float* DINVA = (float*)alloc((size_t)2*N_NODESC*4);
  float* DINVB = (float*)alloc((size_t)2*N_NODESC*4);
  int*   RP2  = (int*)alloc((size_t)2*NN1*4);
  int*   CUR2 = (int*)alloc((size_t)2*N_NODESC*4);
  int*   PART2= (int*)alloc((size_t)2*NBLK*4);
  float2* EMETA=(float2*)alloc((size_t)2*NEC*8);
  u32*   NEED = (u32*)alloc((size_t)N_NODESC*4);
  u32*   NEED1= (u32*)alloc((size_t)2*N_NODESC*4);
  float* INVM = (float*)alloc((size_t)TOKM*4);
  (void)ws_size; (void)in_sizes; (void)n_in; (void)out_size;

  const int GD_TOK = (TOKM*384 + 255)/256;
  const int GD_E   = (NEC + 255)/256;
  const int GD_N   = (N_NODESC + 255)/256;
  const int SPMM_GD  = (N_NODESC + 3)/4;
  const int PN_NCHUNKS = M_PAD/PN_KCHUNK;               // 60
  const int G_PN  = (HIDC/128)*PN_NCHUNKS;              // 360
  const int G4_GCN = (M_PAD/128)*(HIDC/128);            // 1440
  const int G4_CBT = (HIDC/128)*(M_PAD/128);            // 1440
  const int G8_ZC  = (TOKM/256)*(ZNC/256);              // 288

  // ---- prep ----
  hipMemsetAsync(NEED, 0, (size_t)N_NODESC*4, stream);
  hipMemsetAsync(DEG2, 0, (size_t)2*N_NODESC*4, stream);
  hipMemsetAsync(CNT2, 0, (size_t)2*N_NODESC*4, stream);
  k_invmask<<<1,256,0,stream>>>(mask, INVM);
  k_needed<<<(TOKM+255)/256,256,0,stream>>>(ids, NEED);
  k_need1_init<<<GD_N,256,0,stream>>>(NEED, NEED1);
  k_need_expand<<<dim3(GD_E,2),256,0,stream>>>(co_ei, re_ei, NEED, NEED1);
  k_conv<<<(HIDC*HIDC/2 + 255)/256,256,0,stream>>>(pn_W, PNWB, HIDC*HIDC/2);
  k_conv<<<(ZNC*HIDC/2 + 255)/256,256,0,stream>>>(zw, ZWALL, ZNC*HIDC/2);
  k_conv<<<(ZNC*HIDC/2 + 255)/256,256,0,stream>>>(zwp, ZWALL + (size_t)ZNC*HIDC, ZNC*HIDC/2);
  k_conv_pad<<<(M_PAD*384 + 255)/256,256,0,stream>>>(word, WORDB, N_NODESC, M_PAD);
  k_transposeW2<<<dim3((3*HIDC*384 + 255)/256, 2),256,0,stream>>>(co_W, re_W, WT2);

  // ---- batched CSR build ----
  k_degcnt2<<<dim3(GD_E,2),256,0,stream>>>(co_ei, re_ei, co_ew, re_ew, DEG2, CNT2);
  k_dinv2<<<dim3(GD_N,2),256,0,stream>>>(DEG2, DINVA, DINVB);
  k_scan1<<<dim3(NBLK,2),256,0,stream>>>(CNT2, PART2);
  k_scan2<<<2,128,0,stream>>>(PART2, RP2);
  k_scan3<<<dim3(NBLK,2),256,0,stream>>>(CNT2, PART2, RP2, CUR2);
  k_scatter2<<<dim3(GD_E,2),256,0,stream>>>(co_ei, re_ei, co_ew, re_ew, DINVA, CUR2, EMETA);

  // ---- pn path: cbT = pnW·word^T (+row bias), GT = cbT·pn^T (split-K), gather ----
  gemm4p_bf16<2><<<G4_CBT,256,G4_LDS,stream>>>(PNWB, WORDB, HIDC, M_PAD, HIDC, BUFX, pn_b);
  k_pnb<<<(128*(M_PAD/2) + 255)/256,256,0,stream>>>(png, PNB);
  hipMemsetAsync(GT, 0, (size_t)HIDC*128*4, stream);
  gemm_splitk<<<G_PN,256,0,stream>>>(BUFX, PNB, HIDC, 128, M_PAD, GT, PN_KCHUNK);
  k_gather_pn<<<GD_TOK,256,0,stream>>>(GT, cids, TOKALL + (size_t)2*TOKM*HIDC);

  // ---- GCN stacks ----
  // layer filters: L0 = none; L1 = NEED1; L2 = NEED. All consumed values bit-identical.
  auto run_graph = [&](int g, const float* bf, u16* tokb){
    const int* rp = RP2 + (size_t)g*NN1;
    const float2* em = EMETA + (size_t)g*NEC;
    const float* di2 = DINVB + (size_t)g*N_NODESC;
    const u16* X = WORDB;
    for(int i=0;i<3;i++){
      gemm4p_bf16<0><<<G4_GCN,256,G4_LDS,stream>>>(X, WT2 + ((size_t)g*3 + i)*HIDC*HIDC,
                                                   M_PAD, HIDC, HIDC, BUFB, nullptr);
      const u32* flt = (i==2) ? NEED : (i==1 ? NEED1 + (size_t)g*N_NODESC : nullptr);
      k_spmm<<<SPMM_GD,256,0,stream>>>(BUFB, rp, em, di2, bf + i*HIDC, BUFX, flt);
      k_gather<<<GD_TOK,256,0,stream>>>(BUFX, ids, TOKF, tokb, i);
      X = BUFX;
    }
  };
  run_graph(0, co_b, TOKALL);
  run_graph(1, re_b, TOKALL + (size_t)TOKM*HIDC);

  // ---- zero-convs -> outputs ----
  dim3 zgrid(G8_ZC, 1, 3);
  gemm8p_zc<<<zgrid,512,G8_LDS,stream>>>(TOKALL, ZWALL, zb, zbp, INVM, out);
  k_zerocol<<<(3*LLAY*4*HIDC + 255)/256,256,0,stream>>>(out);
}

// Round 6
// 1129.147 us; speedup vs baseline: 1.3562x; 1.0094x over previous
//
#include <hip/hip_runtime.h>
#include <stdint.h>

typedef unsigned int u32;
typedef unsigned short u16;
typedef __attribute__((ext_vector_type(8))) short short8;
typedef __attribute__((ext_vector_type(4))) float f32x4;

#define N_NODESC 30522
#define HIDC 768
#define NEC 488352
#define TOKM 2048
#define LLAY 12
#define NCLS 101
#define M_PAD 30720     // 120*256
#define ZNC (LLAY*HIDC) // 9216
#define OUT_SET (LLAY*4*513*HIDC)
#define PN_KCHUNK 512
#define NBLK 120
#define NN1 (N_NODESC+1)
#define G4_LDS 65536
#define G8_LDS 131072

// ---------- helpers ----------
__device__ __forceinline__ float bl(u32 u){ return __uint_as_float(u<<16); }
__device__ __forceinline__ float bh(u32 u){ return __uint_as_float(u & 0xffff0000u); }
__device__ __forceinline__ u32 f2b1(float f){ u32 x=__float_as_uint(f); return (x + 0x7fffu + ((x>>16)&1u))>>16; }
__device__ __forceinline__ u32 pack2(float a, float b){ return f2b1(a) | (f2b1(b)<<16); }

__device__ __forceinline__ void mfma16(f32x4& d, short8 a, short8 b){
  asm volatile("v_mfma_f32_16x16x32_bf16 %0, %1, %2, %0" : "+v"(d) : "v"(a), "v"(b));
}
__device__ __forceinline__ void async16(const void* g, void* l){
  __builtin_amdgcn_global_load_lds((const __attribute__((address_space(1))) u32*)g,
                                   (__attribute__((address_space(3))) u32*)l, 16, 0, 0);
}

// ---------- mask normalize ----------
__global__ void k_invmask(const void* __restrict__ mask, float* __restrict__ invm){
  __shared__ int s_byte, s_flt;
  int t = threadIdx.x;
  const unsigned char* mb = (const unsigned char*)mask;
  const u32* mw = (const u32*)mask;
  int lb=0, lf=0;
  for(int i=t;i<2048;i+=256) if((i&3)!=0 && mb[i]!=0) lb=1;
  for(int i=t;i<512;i+=256) if(mw[i]==0x3F800000u) lf=1;
  if(t==0){ s_byte=0; s_flt=0; }
  __syncthreads();
  if(lb) s_byte=1;
  if(lf) s_flt=1;
  __syncthreads();
  int mode = s_flt ? 2 : (s_byte ? 1 : 0);
  for(int p=t;p<2048;p+=256){
    int mv = (mode==1) ? (int)mb[p] : (int)(mw[p]!=0u);
    invm[p] = mv ? 0.f : 1.f;
  }
}

// token->node marking + node->token inverted chain (TMAP pre-memset to -1)
__global__ void k_needed(const int* __restrict__ ids, u32* __restrict__ needed,
                         int* __restrict__ tmap, int* __restrict__ nxt){
  int p = blockIdx.x*256 + threadIdx.x;
  if(p < TOKM){
    int id = ids[p];
    if(id < N_NODESC){
      needed[id] = 1u;
      int old = atomicExch(&tmap[id], p);
      nxt[p] = old;
    }
  }
}

// frontier expansion: NEED1[g] = NEED  union  { src(e) : dst(e) in NEED }, per graph
__global__ void k_need1_init(const u32* __restrict__ needed, u32* __restrict__ need1){
  int v = blockIdx.x*256 + threadIdx.x;
  if(v < N_NODESC){ u32 x = needed[v]; need1[v] = x; need1[N_NODESC + v] = x; }
}
__global__ void k_need_expand(const int* __restrict__ coei, const int* __restrict__ reei,
                              const u32* __restrict__ needed, u32* __restrict__ need1){
  int g = blockIdx.y;
  const int* ei = g ? reei : coei;
  int e = blockIdx.x*256 + threadIdx.x;
  if(e < NEC){
    int d = ei[NEC+e];
    if(needed[d]) need1[(size_t)g*N_NODESC + ei[e]] = 1u;
  }
}

// ---------- converts ----------
__global__ void k_conv(const float* __restrict__ src, u16* __restrict__ dst, int ndw){
  int i = blockIdx.x*256 + threadIdx.x;
  if(i < ndw) ((u32*)dst)[i] = pack2(src[2*i], src[2*i+1]);
}
// two-source variant (zw and zwp into adjacent halves of ZWALL)
__global__ void k_conv2(const float* __restrict__ a, const float* __restrict__ b,
                        u16* __restrict__ dst, int ndwHalf){
  int i = blockIdx.x*256 + threadIdx.x;
  if(i >= 2*ndwHalf) return;
  const float* s = (i < ndwHalf) ? a : b;
  int j = (i < ndwHalf) ? i : i - ndwHalf;
  ((u32*)dst)[i] = pack2(s[2*j], s[2*j+1]);
}
__global__ void k_conv_pad(const float* __restrict__ src, u16* __restrict__ dst, int srcRows, int padRows){
  int i = blockIdx.x*256 + threadIdx.x;
  if(i >= padRows*384) return;
  int row = i/384; int c2 = (i - row*384)*2;
  float lo=0.f, hi=0.f;
  if(row < srcRows){ const float* s = src + (size_t)row*HIDC + c2; lo=s[0]; hi=s[1]; }
  ((u32*)dst)[i] = pack2(lo, hi);
}
__global__ void k_pnb(const float* __restrict__ png, u16* __restrict__ pnb){
  int i = blockIdx.x*256 + threadIdx.x;
  if(i >= 128*(M_PAD/2)) return;
  int row = i/(M_PAD/2); int k2 = (i - row*(M_PAD/2))*2;
  float lo=0.f, hi=0.f;
  if(row < NCLS){
    const float* s = png + (size_t)row*N_NODESC;
    if(k2 < N_NODESC) lo = s[k2];
    if(k2+1 < N_NODESC) hi = s[k2+1];
  }
  ((u32*)pnb)[i] = pack2(lo, hi);
}
__global__ void k_transposeW2(const float* __restrict__ coW, const float* __restrict__ reW,
                              u16* __restrict__ Wt2){
  int g = blockIdx.y;
  int i = blockIdx.x*256 + threadIdx.x;
  if(i >= 3*HIDC*384) return;
  const float* W = g ? reW : coW;
  int mat = i/(HIDC*384); int rem = i - mat*HIDC*384;
  int n = rem/384; int kd = rem - n*384;
  const float* Wm = W + (size_t)mat*HIDC*HIDC;
  float lo = Wm[(size_t)(2*kd)*HIDC + n];
  float hi = Wm[(size_t)(2*kd+1)*HIDC + n];
  ((u32*)Wt2)[(size_t)g*3*HIDC*384 + (size_t)mat*HIDC*384 + (size_t)n*384 + kd] = pack2(lo, hi);
}

// ---------- batched graph prep ----------
__global__ void k_degcnt2(const int* __restrict__ coei, const int* __restrict__ reei,
                          const float* __restrict__ coew, const float* __restrict__ reew,
                          float* __restrict__ deg2, int* __restrict__ cnt2){
  int g = blockIdx.y;
  const int* ei = g ? reei : coei;
  const float* ew = g ? reew : coew;
  int e = blockIdx.x*256 + threadIdx.x;
  if(e < NEC){ int d = ei[NEC+e]; atomicAdd(&deg2[(size_t)g*N_NODESC + d], ew[e]); atomicAdd(&cnt2[(size_t)g*N_NODESC + d], 1); }
}
__global__ void k_dinv2(const float* __restrict__ deg2, float* __restrict__ dinvA, float* __restrict__ dinvB){
  int g = blockIdx.y;
  int v = blockIdx.x*256 + threadIdx.x;
  if(v < N_NODESC){
    float d = deg2[(size_t)g*N_NODESC + v] + 1.f;
    dinvA[(size_t)g*N_NODESC + v] = rsqrtf(d);
    dinvB[(size_t)g*N_NODESC + v] = 1.f/d;
  }
}
__global__ void k_scan1(const int* __restrict__ cnt2, int* __restrict__ part2){
  __shared__ int wt[4];
  int g = blockIdx.y, b = blockIdx.x, t = threadIdx.x;
  int lane = t & 63, w = t >> 6;
  int i = b*256 + t;
  int v = (i < N_NODESC) ? cnt2[(size_t)g*N_NODESC + i] : 0;
  int x = v;
  #pragma unroll
  for(int off=1; off<64; off<<=1){ int y = __shfl_up(x, off); if(lane>=off) x += y; }
  if(lane==63) wt[w] = x;
  __syncthreads();
  if(t==0) part2[g*NBLK + b] = wt[0]+wt[1]+wt[2]+wt[3];
}
__global__ void k_scan2(int* __restrict__ part2, int* __restrict__ rp2){
  __shared__ int w0tot;
  int g = blockIdx.x, t = threadIdx.x;   // 128 threads
  int lane = t & 63, w = t >> 6;
  int v = (t < NBLK) ? part2[g*NBLK + t] : 0;
  int x = v;
  #pragma unroll
  for(int off=1; off<64; off<<=1){ int y = __shfl_up(x, off); if(lane>=off) x += y; }
  if(w==0 && lane==63) w0tot = x;
  __syncthreads();
  int incl = x + (w ? w0tot : 0);
  int excl = incl - v;
  if(t < NBLK) part2[g*NBLK + t] = excl;
  if(t == 127) rp2[(size_t)g*NN1 + N_NODESC] = incl;
}
__global__ void k_scan3(const int* __restrict__ cnt2, const int* __restrict__ part2,
                        int* __restrict__ rp2, int* __restrict__ cur2){
  __shared__ int wt[4];
  int g = blockIdx.y, b = blockIdx.x, t = threadIdx.x;
  int lane = t & 63, w = t >> 6;
  int i = b*256 + t;
  int v = (i < N_NODESC) ? cnt2[(size_t)g*N_NODESC + i] : 0;
  int x = v;
  #pragma unroll
  for(int off=1; off<64; off<<=1){ int y = __shfl_up(x, off); if(lane>=off) x += y; }
  if(lane==63) wt[w] = x;
  __syncthreads();
  int wpre = 0;
  #pragma unroll
  for(int j=0;j<4;j++) if(j<w) wpre += wt[j];
  int excl = x - v + wpre + part2[g*NBLK + b];
  if(i < N_NODESC){ rp2[(size_t)g*NN1 + i] = excl; cur2[(size_t)g*N_NODESC + i] = excl; }
}
__global__ void k_scatter2(const int* __restrict__ coei, const int* __restrict__ reei,
                           const float* __restrict__ coew, const float* __restrict__ reew,
                           const float* __restrict__ dinvA, int* __restrict__ cur2,
                           float2* __restrict__ emeta){
  int g = blockIdx.y;
  const int* ei = g ? reei : coei;
  const float* ew = g ? reew : coew;
  int e = blockIdx.x*256 + threadIdx.x;
  if(e < NEC){
    int s = ei[e], d = ei[NEC+e];
    int pos = atomicAdd(&cur2[(size_t)g*N_NODESC + d], 1);
    float nrm = dinvA[(size_t)g*N_NODESC + s]*ew[e]*dinvA[(size_t)g*N_NODESC + d];
    emeta[(size_t)g*NEC + pos] = make_float2(__int_as_float(s), nrm);
  }
}

// ---------- SpMM with fused token scatter ----------
// phase 0: hout write + TOKF[p] = bf16(x)/3      (set; every token node is computed)
// phase 1: hout write + TOKF[p] += bf16(x)/3
// phase 2: NO hout write; TOKALL[p] = pack2(TOKF[p] + bf16(x)/3)
// Token values use the bf16-rounded row (pack2 then decode) -> bit-identical to the
// old k_gather which read the packed BUFX.  tmap/nxt = node->token chain.
__global__ __launch_bounds__(256)
void k_spmm(const u16* __restrict__ hW, const int* __restrict__ rp,
            const float2* __restrict__ emeta, const float* __restrict__ dinv2,
            const float* __restrict__ bias, u16* __restrict__ hout,
            const u32* __restrict__ needed,
            const int* __restrict__ tmap, const int* __restrict__ nxt,
            float2* __restrict__ tokf, u16* __restrict__ tokb, int phase){
  int v = blockIdx.x*4 + (threadIdx.x>>6);
  if(v >= N_NODESC) return;
  if(needed && !needed[v]) return;
  int lane = threadIdx.x & 63;
  const u32* H = (const u32*)hW;
  float acc[12];
  #pragma unroll
  for(int q=0;q<12;q++) acc[q]=0.f;
  int e0 = rp[v], e1 = rp[v+1];
  int e = e0;
  for(; e+4<=e1; e+=4){
    float2 m0=emeta[e], m1=emeta[e+1], m2=emeta[e+2], m3=emeta[e+3];
    const u32* r0 = H + (size_t)__float_as_int(m0.x)*384 + lane;
    const u32* r1 = H + (size_t)__float_as_int(m1.x)*384 + lane;
    const u32* r2 = H + (size_t)__float_as_int(m2.x)*384 + lane;
    const u32* r3 = H + (size_t)__float_as_int(m3.x)*384 + lane;
    u32 u0[6],u1[6],u2[6],u3[6];
    #pragma unroll
    for(int q=0;q<6;q++){ u0[q]=r0[q*64]; u1[q]=r1[q*64]; u2[q]=r2[q*64]; u3[q]=r3[q*64]; }
    #pragma unroll
    for(int q=0;q<6;q++){
      acc[2*q]   += m0.y*bl(u0[q]) + m1.y*bl(u1[q]) + m2.y*bl(u2[q]) + m3.y*bl(u3[q]);
      acc[2*q+1] += m0.y*bh(u0[q]) + m1.y*bh(u1[q]) + m2.y*bh(u2[q]) + m3.y*bh(u3[q]);
    }
  }
  for(; e<e1; ++e){
    float2 mm = emeta[e];
    const u32* r = H + (size_t)__float_as_int(mm.x)*384 + lane;
    #pragma unroll
    for(int q=0;q<6;q++){ u32 u = r[q*64]; acc[2*q] += mm.y*bl(u); acc[2*q+1] += mm.y*bh(u); }
  }
  { float wgt = dinv2[v];
    const u32* r = H + (size_t)v*384 + lane;
    #pragma unroll
    for(int q=0;q<6;q++){ u32 u = r[q*64]; acc[2*q] += wgt*bl(u); acc[2*q+1] += wgt*bh(u); }
  }
  const float2* B2 = (const float2*)bias;
  u32 wv[6];
  #pragma unroll
  for(int q=0;q<6;q++){
    float2 bb = B2[lane + 64*q];
    float x0 = fmaxf(acc[2*q]+bb.x, 0.f);
    float x1 = fmaxf(acc[2*q+1]+bb.y, 0.f);
    wv[q] = pack2(x0, x1);
  }
  if(phase != 2){
    u32* O = (u32*)hout + (size_t)v*384 + lane;
    #pragma unroll
    for(int q=0;q<6;q++) O[q*64] = wv[q];
  }
  int p = tmap[v];                       // wave-uniform; almost always -1
  while(p >= 0){
    float2* TF = tokf + (size_t)p*384 + lane;
    if(phase == 0){
      #pragma unroll
      for(int q=0;q<6;q++)
        TF[q*64] = make_float2(bl(wv[q])*(1.f/3.f), bh(wv[q])*(1.f/3.f));
    } else if(phase == 1){
      #pragma unroll
      for(int q=0;q<6;q++){
        float2 c = TF[q*64];
        c.x += bl(wv[q])*(1.f/3.f); c.y += bh(wv[q])*(1.f/3.f);
        TF[q*64] = c;
      }
    } else {
      u32* TB = (u32*)tokb + (size_t)p*384 + lane;
      #pragma unroll
      for(int q=0;q<6;q++){
        float2 c = TF[q*64];
        c.x += bl(wv[q])*(1.f/3.f); c.y += bh(wv[q])*(1.f/3.f);
        TB[q*64] = pack2(c.x, c.y);
      }
    }
    p = nxt[p];
  }
}

__global__ void k_gather_pn(const float* __restrict__ GT, const int* __restrict__ cids, u16* __restrict__ tokb){
  int d = blockIdx.x*256 + threadIdx.x;
  if(d >= TOKM*384) return;
  int p = d/384, q = d - p*384;
  int cid = cids[p];
  float lo = GT[(size_t)(2*q)*128 + cid];
  float hi = GT[(size_t)(2*q+1)*128 + cid];
  ((u32*)tokb)[d] = pack2(lo, hi);
}

__global__ void k_zerocol(float* __restrict__ out){
  int i = blockIdx.x*256 + threadIdx.x;
  if(i >= 3*LLAY*4*HIDC) return;
  int set = i/(LLAY*4*HIDC); int rem = i - set*(LLAY*4*HIDC);
  int l = rem/(4*HIDC); int rem2 = rem - l*(4*HIDC);
  int b = rem2/HIDC; int o = rem2 - b*HIDC;
  out[(size_t)set*OUT_SET + (size_t)(l*4+b)*513*HIDC + o] = 0.f;
}

// ---------- XCD-chunked bijective block split (shared) ----------
__device__ __forceinline__ void g_split(int ntM, int ntN, int& bm, int& bn){
  int nwg = ntM*ntN;                       // must be %8==0
  int bid = (int)blockIdx.x;
  int wg = (bid & 7)*(nwg>>3) + (bid>>3);  // XCD-chunked, bijective
  if(ntN <= ntM){ bm = wg/ntN; bn = wg - bm*ntN; }
  else          { bn = wg/ntM; bm = wg - bn*ntM; }
}

// ================= 256x256 8-phase GEMM core (1 block/CU) — used for zc =================
#define G8_AOFF(b) ((b)*65536)
#define G8_BOFF(b) ((b)*65536 + 32768)

__device__ __forceinline__ void g8_stage(const u16* __restrict__ src, int ldk, int g0, int kt,
                                         char* half_base, int tid){
  const int lane = tid & 63;
  const int csw = ((lane&7) ^ (lane>>3)) << 3;   // pre-swizzled source col (elements)
  const u16* s0 = src + (size_t)(g0 + (tid>>3))*ldk + (kt + csw);
  const u16* s1 = src + (size_t)(g0 + 64 + (tid>>3))*ldk + (kt + csw);
  async16(s0, half_base + (size_t)tid*16);
  async16(s1, half_base + 8192 + (size_t)tid*16);
}

__device__ __forceinline__ void g8_core(const u16* __restrict__ A, const u16* __restrict__ Bt,
                                        int K, int m0, int n0,
                                        f32x4 (&acc)[8][4], char* LDS, int tid){
  const int lane = tid & 63;
  const int wid = tid >> 6;
  const int wr = wid >> 2, wc = wid & 3;
  const int NK = K >> 6;   // K-tiles (BK=64); requires NK>=3, even

  g8_stage(Bt, K, n0,      0, LDS + G8_BOFF(0),         tid);
  g8_stage(Bt, K, n0+128,  0, LDS + G8_BOFF(0) + 16384, tid);
  g8_stage(A,  K, m0,      0, LDS + G8_AOFF(0),         tid);
  g8_stage(A,  K, m0+128,  0, LDS + G8_AOFF(0) + 16384, tid);
  g8_stage(Bt, K, n0,     64, LDS + G8_BOFF(1),         tid);
  g8_stage(Bt, K, n0+128, 64, LDS + G8_BOFF(1) + 16384, tid);
  asm volatile("s_waitcnt vmcnt(4)" ::: "memory");
  __builtin_amdgcn_sched_barrier(0);
  __builtin_amdgcn_s_barrier();
  __builtin_amdgcn_sched_barrier(0);

  short8 bf8[8];
  for(int T=0; T<NK; ++T){
    const int buf = T & 1;
    const char* Ab = LDS + G8_AOFF(buf) + wr*16384;
    const char* Bb = LDS + G8_BOFF(buf) + (wc>>1)*16384;
    #pragma unroll
    for(int q=0; q<4; ++q){
      if(q==0){
        #pragma unroll
        for(int n=0;n<4;n++){
          #pragma unroll
          for(int kk=0;kk<2;kk++){
            int row = ((wc&1)<<6) + (n<<4) + (lane&15);
            int cb = ((kk<<6) + ((lane>>4)<<4)) ^ ((lane&7)<<4);
            bf8[n*2+kk] = *(const short8*)(Bb + row*128 + cb);
          }
        }
      }
      short8 af[2][2];
      #pragma unroll
      for(int j=0;j<2;j++){
        #pragma unroll
        for(int kk=0;kk<2;kk++){
          int row = ((2*q+j)<<4) + (lane&15);
          int cb = ((kk<<6) + ((lane>>4)<<4)) ^ ((lane&7)<<4);
          af[j][kk] = *(const short8*)(Ab + row*128 + cb);
        }
      }
      if(q==0 && T+1<NK) g8_stage(A,  K, m0,      (T+1)<<6, LDS + G8_AOFF((T+1)&1),         tid);
      if(q==1 && T+1<NK) g8_stage(A,  K, m0+128,  (T+1)<<6, LDS + G8_AOFF((T+1)&1) + 16384, tid);
      if(q==2 && T+2<NK) g8_stage(Bt, K, n0,      (T+2)<<6, LDS + G8_BOFF(buf),             tid);
      if(q==3 && T+2<NK) g8_stage(Bt, K, n0+128,  (T+2)<<6, LDS + G8_BOFF(buf) + 16384,     tid);
      if(q==3){
        if(T <= NK-3)      asm volatile("s_waitcnt vmcnt(4)" ::: "memory");
        else if(T == NK-2) asm volatile("s_waitcnt vmcnt(0)" ::: "memory");
      }
      __builtin_amdgcn_sched_barrier(0);
      __builtin_amdgcn_s_barrier();
      __builtin_amdgcn_sched_barrier(0);
      __builtin_amdgcn_s_setprio(1);
      #pragma unroll
      for(int j=0;j<2;j++){
        #pragma unroll
        for(int n=0;n<4;n++){
          #pragma unroll
          for(int kk=0;kk<2;kk++) mfma16(acc[2*q+j][n], af[j][kk], bf8[n*2+kk]);
        }
      }
      __builtin_amdgcn_s_setprio(0);
      __builtin_amdgcn_sched_barrier(0);
      __builtin_amdgcn_s_barrier();
      __builtin_amdgcn_sched_barrier(0);
    }
  }
}

// zero-conv GEMM (3 sets via blockIdx.z), g8 core + LDS-staged coalesced fp32 stores
__global__ __launch_bounds__(512,2)
void gemm8p_zc(const u16* __restrict__ TOKALL, const u16* __restrict__ ZWALL,
               const float* __restrict__ zb, const float* __restrict__ zbp,
               const float* __restrict__ invm, float* __restrict__ out){
  extern __shared__ char LDS[];
  const int set = blockIdx.z;
  const u16* A  = TOKALL + (size_t)set*TOKM*HIDC;
  const u16* Bt = ZWALL + (set==2 ? (size_t)ZNC*HIDC : 0);
  const float* bias = (set==2) ? zbp : zb;
  const bool use_mask = (set != 2);
  float* o = out + (size_t)set*OUT_SET;

  const int tid = threadIdx.x;
  const int lane = tid & 63;
  const int wid = tid >> 6;
  const int wr = wid >> 2, wc = wid & 3;
  int bm, bn;
  g_split(TOKM>>8, ZNC>>8, bm, bn);     // 8 x 36
  const int m0 = bm << 8, n0 = bn << 8;

  f32x4 acc[8][4];
  f32x4 zv = {0.f,0.f,0.f,0.f};
  #pragma unroll
  for(int m=0;m<8;m++){
    #pragma unroll
    for(int n=0;n<4;n++) acc[m][n] = zv;
  }
  g8_core(A, Bt, HIDC, m0, n0, acc, LDS, tid);

  const int l = n0 / HIDC;
  const int oc0 = n0 - l*HIDC;
  const int lo = lane & 15, hi = lane >> 4;

  #pragma unroll
  for(int pass=0; pass<2; ++pass){
    __syncthreads();
    if(wr == pass){
      #pragma unroll
      for(int m=0;m<8;m++){
        #pragma unroll
        for(int n=0;n<4;n++){
          int col = (wc<<6) + (n<<4) + lo;      // 0..255
          float badd = bias[n0 + col];
          #pragma unroll
          for(int r=0;r<4;r++){
            int lr = (m<<4) + (hi<<2) + r;      // 0..127
            *(float*)(LDS + (size_t)lr*1024 + ((col<<2) ^ ((lr&7)<<4))) = acc[m][n][r] + badd;
          }
        }
      }
    }
    __syncthreads();
    #pragma unroll
    for(int i=0;i<16;i++){
      int lr = (i<<3) + wid;
      int rr = m0 + (pass<<7) + lr;             // global token row
      int b = rr >> 9, s = rr & 511;
      f32x4 v = *(const f32x4*)(LDS + (size_t)lr*1024 + ((lane<<4) ^ ((lr&7)<<4)));
      if(use_mask){ float w = invm[rr]; v = v * w; }
      *(f32x4*)(o + (size_t)((l*4+b)*513 + (s+1))*HIDC + oc0 + (lane<<2)) = v;
    }
  }
}

// ================= 128x128 2-phase GEMM core (2 blocks/CU) — used for GCN/CBT =================
#define G4_ABUF(b) ((b)*32768)
#define G4_BBUF(b) ((b)*32768 + 16384)

__device__ __forceinline__ void g4_stage(const u16* __restrict__ src, int ldk, int g0, int kt,
                                         char* base, int tid){
  const int lane = tid & 63;
  const int csw = ((lane&7) ^ (lane>>3)) << 3;   // pre-swizzled source col (elements)
  const int r = tid >> 3;                        // 0..31
  #pragma unroll
  for(int h=0; h<4; ++h)
    async16(src + (size_t)(g0 + h*32 + r)*ldk + (kt + csw), base + h*4096 + (size_t)tid*16);
}

__device__ __forceinline__ void g4_core(const u16* __restrict__ A, const u16* __restrict__ Bt,
                                        int K, int m0, int n0,
                                        f32x4 (&acc)[4][4], char* LDS, int tid){
  const int lane = tid & 63;
  const int wid = tid >> 6;
  const int wr = wid >> 1, wc = wid & 1;
  const int NK = K >> 6;   // requires NK>=2

  g4_stage(A,  K, m0,  0, LDS + G4_ABUF(0), tid);
  g4_stage(Bt, K, n0,  0, LDS + G4_BBUF(0), tid);
  g4_stage(A,  K, m0, 64, LDS + G4_ABUF(1), tid);
  g4_stage(Bt, K, n0, 64, LDS + G4_BBUF(1), tid);

  short8 af[4][2], bf[4][2];
  for(int T=0; T<NK; ++T){
    const int buf = T & 1;
    const char* Ab = LDS + G4_ABUF(buf) + wr*8192;
    const char* Bb = LDS + G4_BBUF(buf) + wc*8192;
    if(T+1 < NK) asm volatile("s_waitcnt vmcnt(8)" ::: "memory");
    else         asm volatile("s_waitcnt vmcnt(0)" ::: "memory");
    __builtin_amdgcn_sched_barrier(0);
    __builtin_amdgcn_s_barrier();
    __builtin_amdgcn_sched_barrier(0);
    #pragma unroll
    for(int m=0;m<4;m++){
      #pragma unroll
      for(int kk=0;kk<2;kk++){
        int row = (m<<4) + (lane&15);
        int cb = ((kk<<6) + ((lane>>4)<<4)) ^ ((lane&7)<<4);
        af[m][kk] = *(const short8*)(Ab + row*128 + cb);
        bf[m][kk] = *(const short8*)(Bb + row*128 + cb);
      }
    }
    asm volatile("s_waitcnt lgkmcnt(0)" ::: "memory");
    __builtin_amdgcn_sched_barrier(0);
    __builtin_amdgcn_s_setprio(1);
    #pragma unroll
    for(int m=0;m<2;m++){
      #pragma unroll
      for(int n=0;n<4;n++){
        #pragma unroll
        for(int kk=0;kk<2;kk++) mfma16(acc[m][n], af[m][kk], bf[n][kk]);
      }
    }
    __builtin_amdgcn_s_setprio(0);
    __builtin_amdgcn_sched_barrier(0);
    __builtin_amdgcn_s_barrier();     // all waves' ds_reads done -> buf free
    __builtin_amdgcn_sched_barrier(0);
    if(T+2 < NK){
      g4_stage(A,  K, m0, (T+2)<<6, LDS + G4_ABUF(buf), tid);
      g4_stage(Bt, K, n0, (T+2)<<6, LDS + G4_BBUF(buf), tid);
    }
    __builtin_amdgcn_s_setprio(1);
    #pragma unroll
    for(int m=2;m<4;m++){
      #pragma unroll
      for(int n=0;n<4;n++){
        #pragma unroll
        for(int kk=0;kk<2;kk++) mfma16(acc[m][n], af[m][kk], bf[n][kk]);
      }
    }
    __builtin_amdgcn_s_setprio(0);
    __builtin_amdgcn_sched_barrier(0);
  }
}

// MODE 0: bf16 out [M,N] ; MODE 2: bf16 out + per-row bias
template<int MODE>
__global__ __launch_bounds__(256,2)
void gemm4p_bf16(const u16* __restrict__ A, const u16* __restrict__ Bt,
                 int M, int N, int K,
                 u16* __restrict__ outB, const float* __restrict__ bias){
  extern __shared__ char LDS[];
  const int tid = threadIdx.x;
  const int lane = tid & 63;
  const int wid = tid >> 6;
  const int wr = wid >> 1, wc = wid & 1;
  int bm, bn;
  g_split(M>>7, N>>7, bm, bn);
  const int m0 = bm << 7, n0 = bn << 7;

  f32x4 acc[4][4];
  f32x4 zv = {0.f,0.f,0.f,0.f};
  #pragma unroll
  for(int m=0;m<4;m++){
    #pragma unroll
    for(int n=0;n<4;n++) acc[m][n] = zv;
  }
  g4_core(A, Bt, K, m0, n0, acc, LDS, tid);

  const int rbase = (lane>>4)<<2;
  const int cbase = lane & 15;
  #pragma unroll
  for(int m=0;m<4;m++){
    int row0 = m0 + (wr<<6) + (m<<4) + rbase;
    #pragma unroll
    for(int n=0;n<4;n++){
      int col = n0 + (wc<<6) + (n<<4) + cbase;
      #pragma unroll
      for(int r=0;r<4;r++){
        float v = acc[m][n][r];
        if(MODE==2) v += bias[row0+r];
        outB[(size_t)(row0+r)*N + col] = (u16)f2b1(v);
      }
    }
  }
}

// ---------- split-K GEMM (m97-style): atomics into GT ----------
__global__ __launch_bounds__(256,2)
void gemm_splitk(const u16* __restrict__ A, const u16* __restrict__ Bt,
                 int M, int N, int K, float* __restrict__ outF, int kchunk){
  __shared__ u16 As[128*64];
  __shared__ u16 Bs[128*64];
  const int t = threadIdx.x;
  const int lane = t & 63;
  const int w = t >> 6;
  const int wr = w >> 1, wc = w & 1;
  int nchunks = (K + kchunk - 1)/kchunk;
  int bm = (int)blockIdx.x / nchunks;
  int ch = (int)blockIdx.x - bm*nchunks;
  int k0 = ch*kchunk, k1 = k0 + kchunk; if(k1 > K) k1 = K;
  const int m0 = bm << 7, n0 = 0;

  f32x4 zv = {0.f,0.f,0.f,0.f};
  f32x4 acc[4][4];
  #pragma unroll
  for(int m=0;m<4;m++){
    #pragma unroll
    for(int n=0;n<4;n++) acc[m][n] = zv;
  }
  const int srow = t >> 3;
  const int scol = (t & 7) << 3;
  const u16* Ag = A + (size_t)(m0 + srow)*K + scol;
  const u16* Bg = Bt + (size_t)(n0 + srow)*K + scol;
  u16* Al = &As[t*8];
  u16* Bl = &Bs[t*8];

  for(int kt=k0; kt<k1; kt+=64){
    __syncthreads();
    #pragma unroll
    for(int i=0;i<4;i++){
      async16(Ag + (size_t)(i*32)*K + kt, Al + i*2048);
      async16(Bg + (size_t)(i*32)*K + kt, Bl + i*2048);
    }
    __syncthreads();
    #pragma unroll
    for(int kk=0; kk<64; kk+=32){
      const int ko = kk + ((lane>>4)<<3);
      short8 af[4], bfv[4];
      #pragma unroll
      for(int m=0;m<4;m++) af[m] = *(const short8*)&As[((wr<<6)+(m<<4)+(lane&15))*64 + ko];
      #pragma unroll
      for(int n=0;n<4;n++) bfv[n] = *(const short8*)&Bs[((wc<<6)+(n<<4)+(lane&15))*64 + ko];
      #pragma unroll
      for(int m=0;m<4;m++){
        #pragma unroll
        for(int n=0;n<4;n++) mfma16(acc[m][n], af[m], bfv[n]);
      }
    }
  }
  const int rbase = (lane>>4)<<2;
  const int cbase = lane & 15;
  #pragma unroll
  for(int m=0;m<4;m++){
    int row0 = m0 + (wr<<6) + (m<<4) + rbase;
    #pragma unroll
    for(int n=0;n<4;n++){
      int col = n0 + (wc<<6) + (n<<4) + cbase;
      #pragma unroll
      for(int r=0;r<4;r++) atomicAdd(&outF[(size_t)(row0+r)*N + col], acc[m][n][r]);
    }
  }
}

// ---------- host ----------
extern "C" void kernel_launch(void* const* d_in, const int* in_sizes, int n_in,
                              void* d_out, int out_size, void* d_ws, size_t ws_size,
                              hipStream_t stream){
  const float* word  = (const float*)d_in[0];
  const int*   ids   = (const int*)d_in[1];
  const int*   cids  = (const int*)d_in[2];
  const void*  mask  = d_in[3];
  const int*   co_ei = (const int*)d_in[4];
  const float* co_ew = (const float*)d_in[5];
  const int*   re_ei = (const int*)d_in[6];
  const float* re_ew = (const float*)d_in[7];
  const float* png   = (const float*)d_in[8];
  const float* co_W  = (const float*)d_in[9];
  const float* co_b  = (const float*)d_in[10];
  const float* re_W  = (const float*)d_in[11];
  const float* re_b  = (const float*)d_in[12];
  const float* pn_W  = (const float*)d_in[13];
  const float* pn_b  = (const float*)d_in[14];
  const float* zw    = (const float*)d_in[15];
  const float* zb    = (const float*)d_in[16];
  const float* zwp   = (const float*)d_in[17];
  const float* zbp   = (const float*)d_in[18];
  float* out = (float*)d_out;

  hipFuncSetAttribute((const void*)gemm4p_bf16<0>, hipFuncAttributeMaxDynamicSharedMemorySize, G4_LDS);
  hipFuncSetAttribute((const void*)gemm4p_bf16<2>, hipFuncAttributeMaxDynamicSharedMemorySize, G4_LDS);
  hipFuncSetAttribute((const void*)gemm8p_zc,      hipFuncAttributeMaxDynamicSharedMemorySize, G8_LDS);

  char* wsb = (char*)d_ws;
  size_t off = 0;
  auto alloc = [&](size_t bytes)->void*{ void* p = wsb + off; off += (bytes + 255) & ~(size_t)255; return p; };
  u16* WORDB = (u16*)alloc((size_t)M_PAD*HIDC*2);
  u16* BUFB  = (u16*)alloc((size_t)M_PAD*HIDC*2);
  u16* BUFX  = (u16*)alloc((size_t)M_PAD*HIDC*2);
  u16* ZWALL = (u16*)alloc((size_t)2*ZNC*HIDC*2);
  u16* WT2   = (u16*)alloc((size_t)2*3*HIDC*HIDC*2);
  u16* PNWB  = (u16*)alloc((size_t)HIDC*HIDC*2);
  u16* PNB   = (u16*)alloc((size_t)128*M_PAD*2);
  u16* TOKALL= (u16*)alloc((size_t)3*TOKM*HIDC*2);
  float2* TOKF = (float2*)alloc((size_t)TOKM*HIDC*4);
  float* GT   = (float*)alloc((size_t)HIDC*128*4);
  float* DEG2 = (float*)alloc((size_t)2*N_NODESC*4);
  int*   CNT2 = (int*)alloc((size_t)2*N_NODESC*4);
  float* DINVA = (float*)alloc((size_t)2*N_NODESC*4);
  float* DINVB = (float*)alloc((size_t)2*N_NODESC*4);
  int*   RP2  = (int*)alloc((size_t)2*NN1*4);
  int*   CUR2 = (int*)alloc((size_t)2*N_NODESC*4);
  int*   PART2= (int*)alloc((size_t)2*NBLK*4);
  float2* EMETA=(float2*)alloc((size_t)2*NEC*8);
  u32*   NEED = (u32*)alloc((size_t)N_NODESC*4);
  u32*   NEED1= (u32*)alloc((size_t)2*N_NODESC*4);
  int*   TMAP = (int*)alloc((size_t)N_NODESC*4);
  int*   NXT  = (int*)alloc((size_t)TOKM*4);
  float* INVM = (float*)alloc((size_t)TOKM*4);
  (void)ws_size; (void)in_sizes; (void)n_in; (void)out_size;

  const int GD_TOK = (TOKM*384 + 255)/256;
  const int GD_E   = (NEC + 255)/256;
  const int GD_N   = (N_NODESC + 255)/256;
  const int SPMM_GD  = (N_NODESC + 3)/4;
  const int PN_NCHUNKS = M_PAD/PN_KCHUNK;               // 60
  const int G_PN  = (HIDC/128)*PN_NCHUNKS;              // 360
  const int G4_GCN = (M_PAD/128)*(HIDC/128);            // 1440
  const int G4_CBT = (HIDC/128)*(M_PAD/128);            // 1440
  const int G8_ZC  = (TOKM/256)*(ZNC/256);              // 288

  // ---- prep ----
  hipMemsetAsync(NEED, 0, (size_t)N_NODESC*4, stream);
  hipMemsetAsync(TMAP, 0xFF, (size_t)N_NODESC*4, stream);
  hipMemsetAsync(DEG2, 0, (size_t)2*N_NODESC*4, stream);
  hipMemsetAsync(CNT2, 0, (size_t)2*N_NODESC*4, stream);
  hipMemsetAsync(TOKALL, 0, (size_t)2*TOKM*HIDC*2, stream);   // co/re segments (padding tokens stay 0)
  k_invmask<<<1,256,0,stream>>>(mask, INVM);
  k_needed<<<(TOKM+255)/256,256,0,stream>>>(ids, NEED, TMAP, NXT);
  k_need1_init<<<GD_N,256,0,stream>>>(NEED, NEED1);
  k_need_expand<<<dim3(GD_E,2),256,0,stream>>>(co_ei, re_ei, NEED, NEED1);
  k_conv<<<(HIDC*HIDC/2 + 255)/256,256,0,stream>>>(pn_W, PNWB, HIDC*HIDC/2);
  k_conv2<<<(2*(ZNC*HIDC/2) + 255)/256,256,0,stream>>>(zw, zwp, ZWALL, ZNC*HIDC/2);
  k_conv_pad<<<(M_PAD*384 + 255)/256,256,0,stream>>>(word, WORDB, N_NODESC, M_PAD);
  k_transposeW2<<<dim3((3*HIDC*384 + 255)/256, 2),256,0,stream>>>(co_W, re_W, WT2);

  // ---- batched CSR build ----
  k_degcnt2<<<dim3(GD_E,2),256,0,stream>>>(co_ei, re_ei, co_ew, re_ew, DEG2, CNT2);
  k_dinv2<<<dim3(GD_N,2),256,0,stream>>>(DEG2, DINVA, DINVB);
  k_scan1<<<dim3(NBLK,2),256,0,stream>>>(CNT2, PART2);
  k_scan2<<<2,128,0,stream>>>(PART2, RP2);
  k_scan3<<<dim3(NBLK,2),256,0,stream>>>(CNT2, PART2, RP2, CUR2);
  k_scatter2<<<dim3(GD_E,2),256,0,stream>>>(co_ei, re_ei, co_ew, re_ew, DINVA, CUR2, EMETA);

  // ---- pn path: cbT = pnW·word^T (+row bias), GT = cbT·pn^T (split-K), gather ----
  gemm4p_bf16<2><<<G4_CBT,256,G4_LDS,stream>>>(PNWB, WORDB, HIDC, M_PAD, HIDC, BUFX, pn_b);
  k_pnb<<<(128*(M_PAD/2) + 255)/256,256,0,stream>>>(png, PNB);
  hipMemsetAsync(GT, 0, (size_t)HIDC*128*4, stream);
  gemm_splitk<<<G_PN,256,0,stream>>>(BUFX, PNB, HIDC, 128, M_PAD, GT, PN_KCHUNK);
  k_gather_pn<<<GD_TOK,256,0,stream>>>(GT, cids, TOKALL + (size_t)2*TOKM*HIDC);

  // ---- GCN stacks ----
  // layer filters: L0 = none; L1 = NEED1; L2 = NEED.
  // token outputs fused into spmm epilogue (node->token chain); L2 skips hout.
  auto run_graph = [&](int g, const float* bf, u16* tokb){
    const int* rp = RP2 + (size_t)g*NN1;
    const float2* em = EMETA + (size_t)g*NEC;
    const float* di2 = DINVB + (size_t)g*N_NODESC;
    const u16* X = WORDB;
    for(int i=0;i<3;i++){
      gemm4p_bf16<0><<<G4_GCN,256,G4_LDS,stream>>>(X, WT2 + ((size_t)g*3 + i)*HIDC*HIDC,
                                                   M_PAD, HIDC, HIDC, BUFB, nullptr);
      const u32* flt = (i==2) ? NEED : (i==1 ? NEED1 + (size_t)g*N_NODESC : nullptr);
      k_spmm<<<SPMM_GD,256,0,stream>>>(BUFB, rp, em, di2, bf + i*HIDC, BUFX, flt,
                                       TMAP, NXT, TOKF, tokb, i);
      X = BUFX;
    }
  };
  run_graph(0, co_b, TOKALL);
  run_graph(1, re_b, TOKALL + (size_t)TOKM*HIDC);

  // ---- zero-convs -> outputs ----
  dim3 zgrid(G8_ZC, 1, 3);
  gemm8p_zc<<<zgrid,512,G8_LDS,stream>>>(TOKALL, ZWALL, zb, zbp, INVM, out);
  k_zerocol<<<(3*LLAY*4*HIDC + 255)/256,256,0,stream>>>(out);
}

// Round 7
// 1123.039 us; speedup vs baseline: 1.3635x; 1.0054x over previous
//
#include <hip/hip_runtime.h>
#include <stdint.h>

typedef unsigned int u32;
typedef unsigned short u16;
typedef __attribute__((ext_vector_type(8))) short short8;
typedef __attribute__((ext_vector_type(4))) float f32x4;

#define N_NODESC 30522
#define HIDC 768
#define NEC 488352
#define TOKM 2048
#define LLAY 12
#define NCLS 101
#define M_PAD 30720     // 120*256
#define ZNC (LLAY*HIDC) // 9216
#define OUT_SET (LLAY*4*513*HIDC)
#define PN_KCHUNK 512
#define NBLK 120
#define NN1 (N_NODESC+1)
#define G4_LDS 65536
#define G8_LDS 131072

// ---------- helpers ----------
__device__ __forceinline__ float bl(u32 u){ return __uint_as_float(u<<16); }
__device__ __forceinline__ float bh(u32 u){ return __uint_as_float(u & 0xffff0000u); }
__device__ __forceinline__ u32 f2b1(float f){ u32 x=__float_as_uint(f); return (x + 0x7fffu + ((x>>16)&1u))>>16; }
__device__ __forceinline__ u32 pack2(float a, float b){ return f2b1(a) | (f2b1(b)<<16); }

__device__ __forceinline__ void mfma16(f32x4& d, short8 a, short8 b){
  asm volatile("v_mfma_f32_16x16x32_bf16 %0, %1, %2, %0" : "+v"(d) : "v"(a), "v"(b));
}
__device__ __forceinline__ void async16(const void* g, void* l){
  __builtin_amdgcn_global_load_lds((const __attribute__((address_space(1))) u32*)g,
                                   (__attribute__((address_space(3))) u32*)l, 16, 0, 0);
}
// bit-identical decode of a float2 {src_as_float_bits, weight} loaded as one double
__device__ __forceinline__ void em_dec(double d, int& s, float& w){
  unsigned long long b = __double_as_longlong(d);
  s = (int)(u32)b;
  w = __uint_as_float((u32)(b>>32));
}

// ---------- mask normalize ----------
__global__ void k_invmask(const void* __restrict__ mask, float* __restrict__ invm){
  __shared__ int s_byte, s_flt;
  int t = threadIdx.x;
  const unsigned char* mb = (const unsigned char*)mask;
  const u32* mw = (const u32*)mask;
  int lb=0, lf=0;
  for(int i=t;i<2048;i+=256) if((i&3)!=0 && mb[i]!=0) lb=1;
  for(int i=t;i<512;i+=256) if(mw[i]==0x3F800000u) lf=1;
  if(t==0){ s_byte=0; s_flt=0; }
  __syncthreads();
  if(lb) s_byte=1;
  if(lf) s_flt=1;
  __syncthreads();
  int mode = s_flt ? 2 : (s_byte ? 1 : 0);
  for(int p=t;p<2048;p+=256){
    int mv = (mode==1) ? (int)mb[p] : (int)(mw[p]!=0u);
    invm[p] = mv ? 0.f : 1.f;
  }
}

// token->node marking + node->token inverted chain (TMAP pre-memset -1, NEED1 pre-memset 0)
// also seeds NEED1 (both graphs) with the token nodes.
__global__ void k_needed(const int* __restrict__ ids, u32* __restrict__ needed,
                         u32* __restrict__ need1,
                         int* __restrict__ tmap, int* __restrict__ nxt){
  int p = blockIdx.x*256 + threadIdx.x;
  if(p < TOKM){
    int id = ids[p];
    if(id < N_NODESC){
      needed[id] = 1u;
      need1[id] = 1u;
      need1[N_NODESC + id] = 1u;
      int old = atomicExch(&tmap[id], p);
      nxt[p] = old;
    }
  }
}

__global__ void k_need_expand(const int* __restrict__ coei, const int* __restrict__ reei,
                              const u32* __restrict__ needed, u32* __restrict__ need1){
  int g = blockIdx.y;
  const int* ei = g ? reei : coei;
  int e = blockIdx.x*256 + threadIdx.x;
  if(e < NEC){
    int d = ei[NEC+e];
    if(needed[d]) need1[(size_t)g*N_NODESC + ei[e]] = 1u;
  }
}

// ---------- converts (merged: pnW + zw + zwp) ----------
__global__ void k_convAll(const float* __restrict__ pnW, const float* __restrict__ zw,
                          const float* __restrict__ zwp,
                          u16* __restrict__ pnwb, u16* __restrict__ zwall){
  const int NP = HIDC*HIDC/2;
  const int NZ = ZNC*HIDC/2;
  int i = blockIdx.x*256 + threadIdx.x;
  if(i < NP){
    ((u32*)pnwb)[i] = pack2(pnW[2*i], pnW[2*i+1]);
  } else if(i < NP + NZ){
    int j = i - NP;
    ((u32*)zwall)[j] = pack2(zw[2*j], zw[2*j+1]);
  } else if(i < NP + 2*NZ){
    int j = i - NP - NZ;
    ((u32*)zwall)[NZ + j] = pack2(zwp[2*j], zwp[2*j+1]);
  }
}
__global__ void k_conv_pad(const float* __restrict__ src, u16* __restrict__ dst, int srcRows, int padRows){
  int i = blockIdx.x*256 + threadIdx.x;
  if(i >= padRows*384) return;
  int row = i/384; int c2 = (i - row*384)*2;
  float lo=0.f, hi=0.f;
  if(row < srcRows){ const float* s = src + (size_t)row*HIDC + c2; lo=s[0]; hi=s[1]; }
  ((u32*)dst)[i] = pack2(lo, hi);
}
__global__ void k_pnb(const float* __restrict__ png, u16* __restrict__ pnb){
  int i = blockIdx.x*256 + threadIdx.x;
  if(i >= 128*(M_PAD/2)) return;
  int row = i/(M_PAD/2); int k2 = (i - row*(M_PAD/2))*2;
  float lo=0.f, hi=0.f;
  if(row < NCLS){
    const float* s = png + (size_t)row*N_NODESC;
    if(k2 < N_NODESC) lo = s[k2];
    if(k2+1 < N_NODESC) hi = s[k2+1];
  }
  ((u32*)pnb)[i] = pack2(lo, hi);
}
__global__ void k_transposeW2(const float* __restrict__ coW, const float* __restrict__ reW,
                              u16* __restrict__ Wt2){
  int g = blockIdx.y;
  int i = blockIdx.x*256 + threadIdx.x;
  if(i >= 3*HIDC*384) return;
  const float* W = g ? reW : coW;
  int mat = i/(HIDC*384); int rem = i - mat*HIDC*384;
  int n = rem/384; int kd = rem - n*384;
  const float* Wm = W + (size_t)mat*HIDC*HIDC;
  float lo = Wm[(size_t)(2*kd)*HIDC + n];
  float hi = Wm[(size_t)(2*kd+1)*HIDC + n];
  ((u32*)Wt2)[(size_t)g*3*HIDC*384 + (size_t)mat*HIDC*384 + (size_t)n*384 + kd] = pack2(lo, hi);
}

// ---------- batched graph prep ----------
__global__ void k_degcnt2(const int* __restrict__ coei, const int* __restrict__ reei,
                          const float* __restrict__ coew, const float* __restrict__ reew,
                          float* __restrict__ deg2, int* __restrict__ cnt2){
  int g = blockIdx.y;
  const int* ei = g ? reei : coei;
  const float* ew = g ? reew : coew;
  int e = blockIdx.x*256 + threadIdx.x;
  if(e < NEC){ int d = ei[NEC+e]; atomicAdd(&deg2[(size_t)g*N_NODESC + d], ew[e]); atomicAdd(&cnt2[(size_t)g*N_NODESC + d], 1); }
}
// scan1 with fused dinv computation (same geometry, same DEG2/CNT2 dependency)
__global__ void k_scan1(const int* __restrict__ cnt2, int* __restrict__ part2,
                        const float* __restrict__ deg2,
                        float* __restrict__ dinvA, float* __restrict__ dinvB){
  __shared__ int wt[4];
  int g = blockIdx.y, b = blockIdx.x, t = threadIdx.x;
  int lane = t & 63, w = t >> 6;
  int i = b*256 + t;
  if(i < N_NODESC){
    float d = deg2[(size_t)g*N_NODESC + i] + 1.f;
    dinvA[(size_t)g*N_NODESC + i] = rsqrtf(d);
    dinvB[(size_t)g*N_NODESC + i] = 1.f/d;
  }
  int v = (i < N_NODESC) ? cnt2[(size_t)g*N_NODESC + i] : 0;
  int x = v;
  #pragma unroll
  for(int off=1; off<64; off<<=1){ int y = __shfl_up(x, off); if(lane>=off) x += y; }
  if(lane==63) wt[w] = x;
  __syncthreads();
  if(t==0) part2[g*NBLK + b] = wt[0]+wt[1]+wt[2]+wt[3];
}
__global__ void k_scan2(int* __restrict__ part2, int* __restrict__ rp2){
  __shared__ int w0tot;
  int g = blockIdx.x, t = threadIdx.x;   // 128 threads
  int lane = t & 63, w = t >> 6;
  int v = (t < NBLK) ? part2[g*NBLK + t] : 0;
  int x = v;
  #pragma unroll
  for(int off=1; off<64; off<<=1){ int y = __shfl_up(x, off); if(lane>=off) x += y; }
  if(w==0 && lane==63) w0tot = x;
  __syncthreads();
  int incl = x + (w ? w0tot : 0);
  int excl = incl - v;
  if(t < NBLK) part2[g*NBLK + t] = excl;
  if(t == 127) rp2[(size_t)g*NN1 + N_NODESC] = incl;
}
__global__ void k_scan3(const int* __restrict__ cnt2, const int* __restrict__ part2,
                        int* __restrict__ rp2, int* __restrict__ cur2){
  __shared__ int wt[4];
  int g = blockIdx.y, b = blockIdx.x, t = threadIdx.x;
  int lane = t & 63, w = t >> 6;
  int i = b*256 + t;
  int v = (i < N_NODESC) ? cnt2[(size_t)g*N_NODESC + i] : 0;
  int x = v;
  #pragma unroll
  for(int off=1; off<64; off<<=1){ int y = __shfl_up(x, off); if(lane>=off) x += y; }
  if(lane==63) wt[w] = x;
  __syncthreads();
  int wpre = 0;
  #pragma unroll
  for(int j=0;j<4;j++) if(j<w) wpre += wt[j];
  int excl = x - v + wpre + part2[g*NBLK + b];
  if(i < N_NODESC){ rp2[(size_t)g*NN1 + i] = excl; cur2[(size_t)g*N_NODESC + i] = excl; }
}
__global__ void k_scatter2(const int* __restrict__ coei, const int* __restrict__ reei,
                           const float* __restrict__ coew, const float* __restrict__ reew,
                           const float* __restrict__ dinvA, int* __restrict__ cur2,
                           float2* __restrict__ emeta){
  int g = blockIdx.y;
  const int* ei = g ? reei : coei;
  const float* ew = g ? reew : coew;
  int e = blockIdx.x*256 + threadIdx.x;
  if(e < NEC){
    int s = ei[e], d = ei[NEC+e];
    int pos = atomicAdd(&cur2[(size_t)g*N_NODESC + d], 1);
    float nrm = dinvA[(size_t)g*N_NODESC + s]*ew[e]*dinvA[(size_t)g*N_NODESC + d];
    emeta[(size_t)g*NEC + pos] = make_float2(__int_as_float(s), nrm);
  }
}

// ---------- SpMM with fused token scatter ----------
// 8-edge unroll (48 H-loads in flight) + nontemporal emeta (keeps L2 for H rows).
// FP add order identical to the 4-group version: each 4-product sum is one +=
// statement; 8-group = two consecutive += statements (same sequence as two
// 4-group iterations). Tail: one 4-group, then singles. Bit-identical.
__global__ __launch_bounds__(256)
void k_spmm(const u16* __restrict__ hW, const int* __restrict__ rp,
            const float2* __restrict__ emeta, const float* __restrict__ dinv2,
            const float* __restrict__ bias, u16* __restrict__ hout,
            const u32* __restrict__ needed,
            const int* __restrict__ tmap, const int* __restrict__ nxt,
            float2* __restrict__ tokf, u16* __restrict__ tokb, int phase){
  int v = blockIdx.x*4 + (threadIdx.x>>6);
  if(v >= N_NODESC) return;
  if(needed && !needed[v]) return;
  int lane = threadIdx.x & 63;
  const u32* H = (const u32*)hW;
  const double* em8 = (const double*)emeta;
  float acc[12];
  #pragma unroll
  for(int q=0;q<12;q++) acc[q]=0.f;
  int e0 = rp[v], e1 = rp[v+1];
  int e = e0;
  for(; e+8<=e1; e+=8){
    int s[8]; float w[8];
    #pragma unroll
    for(int j=0;j<8;j++) em_dec(__builtin_nontemporal_load(em8+e+j), s[j], w[j]);
    const u32* r[8];
    #pragma unroll
    for(int j=0;j<8;j++) r[j] = H + (size_t)s[j]*384 + lane;
    u32 u[8][6];
    #pragma unroll
    for(int j=0;j<8;j++){
      #pragma unroll
      for(int q=0;q<6;q++) u[j][q] = r[j][q*64];
    }
    #pragma unroll
    for(int q=0;q<6;q++){
      acc[2*q]   += w[0]*bl(u[0][q]) + w[1]*bl(u[1][q]) + w[2]*bl(u[2][q]) + w[3]*bl(u[3][q]);
      acc[2*q+1] += w[0]*bh(u[0][q]) + w[1]*bh(u[1][q]) + w[2]*bh(u[2][q]) + w[3]*bh(u[3][q]);
      acc[2*q]   += w[4]*bl(u[4][q]) + w[5]*bl(u[5][q]) + w[6]*bl(u[6][q]) + w[7]*bl(u[7][q]);
      acc[2*q+1] += w[4]*bh(u[4][q]) + w[5]*bh(u[5][q]) + w[6]*bh(u[6][q]) + w[7]*bh(u[7][q]);
    }
  }
  for(; e+4<=e1; e+=4){
    int s0,s1,s2,s3; float w0,w1,w2,w3;
    em_dec(__builtin_nontemporal_load(em8+e  ), s0, w0);
    em_dec(__builtin_nontemporal_load(em8+e+1), s1, w1);
    em_dec(__builtin_nontemporal_load(em8+e+2), s2, w2);
    em_dec(__builtin_nontemporal_load(em8+e+3), s3, w3);
    const u32* r0 = H + (size_t)s0*384 + lane;
    const u32* r1 = H + (size_t)s1*384 + lane;
    const u32* r2 = H + (size_t)s2*384 + lane;
    const u32* r3 = H + (size_t)s3*384 + lane;
    u32 u0[6],u1[6],u2[6],u3[6];
    #pragma unroll
    for(int q=0;q<6;q++){ u0[q]=r0[q*64]; u1[q]=r1[q*64]; u2[q]=r2[q*64]; u3[q]=r3[q*64]; }
    #pragma unroll
    for(int q=0;q<6;q++){
      acc[2*q]   += w0*bl(u0[q]) + w1*bl(u1[q]) + w2*bl(u2[q]) + w3*bl(u3[q]);
      acc[2*q+1] += w0*bh(u0[q]) + w1*bh(u1[q]) + w2*bh(u2[q]) + w3*bh(u3[q]);
    }
  }
  for(; e<e1; ++e){
    int ss; float ww;
    em_dec(__builtin_nontemporal_load(em8+e), ss, ww);
    const u32* r = H + (size_t)ss*384 + lane;
    #pragma unroll
    for(int q=0;q<6;q++){ u32 u = r[q*64]; acc[2*q] += ww*bl(u); acc[2*q+1] += ww*bh(u); }
  }
  { float wgt = dinv2[v];
    const u32* r = H + (size_t)v*384 + lane;
    #pragma unroll
    for(int q=0;q<6;q++){ u32 u = r[q*64]; acc[2*q] += wgt*bl(u); acc[2*q+1] += wgt*bh(u); }
  }
  const float2* B2 = (const float2*)bias;
  u32 wv[6];
  #pragma unroll
  for(int q=0;q<6;q++){
    float2 bb = B2[lane + 64*q];
    float x0 = fmaxf(acc[2*q]+bb.x, 0.f);
    float x1 = fmaxf(acc[2*q+1]+bb.y, 0.f);
    wv[q] = pack2(x0, x1);
  }
  if(phase != 2){
    u32* O = (u32*)hout + (size_t)v*384 + lane;
    #pragma unroll
    for(int q=0;q<6;q++) O[q*64] = wv[q];
  }
  int p = tmap[v];                       // wave-uniform; almost always -1
  while(p >= 0){
    float2* TF = tokf + (size_t)p*384 + lane;
    if(phase == 0){
      #pragma unroll
      for(int q=0;q<6;q++)
        TF[q*64] = make_float2(bl(wv[q])*(1.f/3.f), bh(wv[q])*(1.f/3.f));
    } else if(phase == 1){
      #pragma unroll
      for(int q=0;q<6;q++){
        float2 c = TF[q*64];
        c.x += bl(wv[q])*(1.f/3.f); c.y += bh(wv[q])*(1.f/3.f);
        TF[q*64] = c;
      }
    } else {
      u32* TB = (u32*)tokb + (size_t)p*384 + lane;
      #pragma unroll
      for(int q=0;q<6;q++){
        float2 c = TF[q*64];
        c.x += bl(wv[q])*(1.f/3.f); c.y += bh(wv[q])*(1.f/3.f);
        TB[q*64] = pack2(c.x, c.y);
      }
    }
    p = nxt[p];
  }
}

__global__ void k_gather_pn(const float* __restrict__ GT, const int* __restrict__ cids, u16* __restrict__ tokb){
  int d = blockIdx.x*256 + threadIdx.x;
  if(d >= TOKM*384) return;
  int p = d/384, q = d - p*384;
  int cid = cids[p];
  float lo = GT[(size_t)(2*q)*128 + cid];
  float hi = GT[(size_t)(2*q+1)*128 + cid];
  ((u32*)tokb)[d] = pack2(lo, hi);
}

__global__ void k_zerocol(float* __restrict__ out){
  int i = blockIdx.x*256 + threadIdx.x;
  if(i >= 3*LLAY*4*HIDC) return;
  int set = i/(LLAY*4*HIDC); int rem = i - set*(LLAY*4*HIDC);
  int l = rem/(4*HIDC); int rem2 = rem - l*(4*HIDC);
  int b = rem2/HIDC; int o = rem2 - b*HIDC;
  out[(size_t)set*OUT_SET + (size_t)(l*4+b)*513*HIDC + o] = 0.f;
}

// ---------- XCD-chunked bijective block split (shared) ----------
__device__ __forceinline__ void g_split(int ntM, int ntN, int& bm, int& bn){
  int nwg = ntM*ntN;                       // must be %8==0
  int bid = (int)blockIdx.x;
  int wg = (bid & 7)*(nwg>>3) + (bid>>3);  // XCD-chunked, bijective
  if(ntN <= ntM){ bm = wg/ntN; bn = wg - bm*ntN; }
  else          { bn = wg/ntM; bm = wg - bn*ntM; }
}

// ================= 256x256 8-phase GEMM core (1 block/CU) — used for zc =================
#define G8_AOFF(b) ((b)*65536)
#define G8_BOFF(b) ((b)*65536 + 32768)

__device__ __forceinline__ void g8_stage(const u16* __restrict__ src, int ldk, int g0, int kt,
                                         char* half_base, int tid){
  const int lane = tid & 63;
  const int csw = ((lane&7) ^ (lane>>3)) << 3;   // pre-swizzled source col (elements)
  const u16* s0 = src + (size_t)(g0 + (tid>>3))*ldk + (kt + csw);
  const u16* s1 = src + (size_t)(g0 + 64 + (tid>>3))*ldk + (kt + csw);
  async16(s0, half_base + (size_t)tid*16);
  async16(s1, half_base + 8192 + (size_t)tid*16);
}

__device__ __forceinline__ void g8_core(const u16* __restrict__ A, const u16* __restrict__ Bt,
                                        int K, int m0, int n0,
                                        f32x4 (&acc)[8][4], char* LDS, int tid){
  const int lane = tid & 63;
  const int wid = tid >> 6;
  const int wr = wid >> 2, wc = wid & 3;
  const int NK = K >> 6;   // K-tiles (BK=64); requires NK>=3, even

  g8_stage(Bt, K, n0,      0, LDS + G8_BOFF(0),         tid);
  g8_stage(Bt, K, n0+128,  0, LDS + G8_BOFF(0) + 16384, tid);
  g8_stage(A,  K, m0,      0, LDS + G8_AOFF(0),         tid);
  g8_stage(A,  K, m0+128,  0, LDS + G8_AOFF(0) + 16384, tid);
  g8_stage(Bt, K, n0,     64, LDS + G8_BOFF(1),         tid);
  g8_stage(Bt, K, n0+128, 64, LDS + G8_BOFF(1) + 16384, tid);
  asm volatile("s_waitcnt vmcnt(4)" ::: "memory");
  __builtin_amdgcn_sched_barrier(0);
  __builtin_amdgcn_s_barrier();
  __builtin_amdgcn_sched_barrier(0);

  short8 bf8[8];
  for(int T=0; T<NK; ++T){
    const int buf = T & 1;
    const char* Ab = LDS + G8_AOFF(buf) + wr*16384;
    const char* Bb = LDS + G8_BOFF(buf) + (wc>>1)*16384;
    #pragma unroll
    for(int q=0; q<4; ++q){
      if(q==0){
        #pragma unroll
        for(int n=0;n<4;n++){
          #pragma unroll
          for(int kk=0;kk<2;kk++){
            int row = ((wc&1)<<6) + (n<<4) + (lane&15);
            int cb = ((kk<<6) + ((lane>>4)<<4)) ^ ((lane&7)<<4);
            bf8[n*2+kk] = *(const short8*)(Bb + row*128 + cb);
          }
        }
      }
      short8 af[2][2];
      #pragma unroll
      for(int j=0;j<2;j++){
        #pragma unroll
        for(int kk=0;kk<2;kk++){
          int row = ((2*q+j)<<4) + (lane&15);
          int cb = ((kk<<6) + ((lane>>4)<<4)) ^ ((lane&7)<<4);
          af[j][kk] = *(const short8*)(Ab + row*128 + cb);
        }
      }
      if(q==0 && T+1<NK) g8_stage(A,  K, m0,      (T+1)<<6, LDS + G8_AOFF((T+1)&1),         tid);
      if(q==1 && T+1<NK) g8_stage(A,  K, m0+128,  (T+1)<<6, LDS + G8_AOFF((T+1)&1) + 16384, tid);
      if(q==2 && T+2<NK) g8_stage(Bt, K, n0,      (T+2)<<6, LDS + G8_BOFF(buf),             tid);
      if(q==3 && T+2<NK) g8_stage(Bt, K, n0+128,  (T+2)<<6, LDS + G8_BOFF(buf) + 16384,     tid);
      if(q==3){
        if(T <= NK-3)      asm volatile("s_waitcnt vmcnt(4)" ::: "memory");
        else if(T == NK-2) asm volatile("s_waitcnt vmcnt(0)" ::: "memory");
      }
      __builtin_amdgcn_sched_barrier(0);
      __builtin_amdgcn_s_barrier();
      __builtin_amdgcn_sched_barrier(0);
      __builtin_amdgcn_s_setprio(1);
      #pragma unroll
      for(int j=0;j<2;j++){
        #pragma unroll
        for(int n=0;n<4;n++){
          #pragma unroll
          for(int kk=0;kk<2;kk++) mfma16(acc[2*q+j][n], af[j][kk], bf8[n*2+kk]);
        }
      }
      __builtin_amdgcn_s_setprio(0);
      __builtin_amdgcn_sched_barrier(0);
      __builtin_amdgcn_s_barrier();
      __builtin_amdgcn_sched_barrier(0);
    }
  }
}

// zero-conv GEMM (3 sets via blockIdx.z), g8 core + LDS-staged coalesced fp32 stores
__global__ __launch_bounds__(512,2)
void gemm8p_zc(const u16* __restrict__ TOKALL, const u16* __restrict__ ZWALL,
               const float* __restrict__ zb, const float* __restrict__ zbp,
               const float* __restrict__ invm, float* __restrict__ out){
  extern __shared__ char LDS[];
  const int set = blockIdx.z;
  const u16* A  = TOKALL + (size_t)set*TOKM*HIDC;
  const u16* Bt = ZWALL + (set==2 ? (size_t)ZNC*HIDC : 0);
  const float* bias = (set==2) ? zbp : zb;
  const bool use_mask = (set != 2);
  float* o = out + (size_t)set*OUT_SET;

  const int tid = threadIdx.x;
  const int lane = tid & 63;
  const int wid = tid >> 6;
  const int wr = wid >> 2, wc = wid & 3;
  int bm, bn;
  g_split(TOKM>>8, ZNC>>8, bm, bn);     // 8 x 36
  const int m0 = bm << 8, n0 = bn << 8;

  f32x4 acc[8][4];
  f32x4 zv = {0.f,0.f,0.f,0.f};
  #pragma unroll
  for(int m=0;m<8;m++){
    #pragma unroll
    for(int n=0;n<4;n++) acc[m][n] = zv;
  }
  g8_core(A, Bt, HIDC, m0, n0, acc, LDS, tid);

  const int l = n0 / HIDC;
  const int oc0 = n0 - l*HIDC;
  const int lo = lane & 15, hi = lane >> 4;

  #pragma unroll
  for(int pass=0; pass<2; ++pass){
    __syncthreads();
    if(wr == pass){
      #pragma unroll
      for(int m=0;m<8;m++){
        #pragma unroll
        for(int n=0;n<4;n++){
          int col = (wc<<6) + (n<<4) + lo;      // 0..255
          float badd = bias[n0 + col];
          #pragma unroll
          for(int r=0;r<4;r++){
            int lr = (m<<4) + (hi<<2) + r;      // 0..127
            *(float*)(LDS + (size_t)lr*1024 + ((col<<2) ^ ((lr&7)<<4))) = acc[m][n][r] + badd;
          }
        }
      }
    }
    __syncthreads();
    #pragma unroll
    for(int i=0;i<16;i++){
      int lr = (i<<3) + wid;
      int rr = m0 + (pass<<7) + lr;             // global token row
      int b = rr >> 9, s = rr & 511;
      f32x4 v = *(const f32x4*)(LDS + (size_t)lr*1024 + ((lane<<4) ^ ((lr&7)<<4)));
      if(use_mask){ float w = invm[rr]; v = v * w; }
      *(f32x4*)(o + (size_t)((l*4+b)*513 + (s+1))*HIDC + oc0 + (lane<<2)) = v;
    }
  }
}

// ================= 128x128 2-phase GEMM core (2 blocks/CU) — used for GCN/CBT =================
#define G4_ABUF(b) ((b)*32768)
#define G4_BBUF(b) ((b)*32768 + 16384)

__device__ __forceinline__ void g4_stage(const u16* __restrict__ src, int ldk, int g0, int kt,
                                         char* base, int tid){
  const int lane = tid & 63;
  const int csw = ((lane&7) ^ (lane>>3)) << 3;   // pre-swizzled source col (elements)
  const int r = tid >> 3;                        // 0..31
  #pragma unroll
  for(int h=0; h<4; ++h)
    async16(src + (size_t)(g0 + h*32 + r)*ldk + (kt + csw), base + h*4096 + (size_t)tid*16);
}

__device__ __forceinline__ void g4_core(const u16* __restrict__ A, const u16* __restrict__ Bt,
                                        int K, int m0, int n0,
                                        f32x4 (&acc)[4][4], char* LDS, int tid){
  const int lane = tid & 63;
  const int wid = tid >> 6;
  const int wr = wid >> 1, wc = wid & 1;
  const int NK = K >> 6;   // requires NK>=2

  g4_stage(A,  K, m0,  0, LDS + G4_ABUF(0), tid);
  g4_stage(Bt, K, n0,  0, LDS + G4_BBUF(0), tid);
  g4_stage(A,  K, m0, 64, LDS + G4_ABUF(1), tid);
  g4_stage(Bt, K, n0, 64, LDS + G4_BBUF(1), tid);

  short8 af[4][2], bf[4][2];
  for(int T=0; T<NK; ++T){
    const int buf = T & 1;
    const char* Ab = LDS + G4_ABUF(buf) + wr*8192;
    const char* Bb = LDS + G4_BBUF(buf) + wc*8192;
    if(T+1 < NK) asm volatile("s_waitcnt vmcnt(8)" ::: "memory");
    else         asm volatile("s_waitcnt vmcnt(0)" ::: "memory");
    __builtin_amdgcn_sched_barrier(0);
    __builtin_amdgcn_s_barrier();
    __builtin_amdgcn_sched_barrier(0);
    #pragma unroll
    for(int m=0;m<4;m++){
      #pragma unroll
      for(int kk=0;kk<2;kk++){
        int row = (m<<4) + (lane&15);
        int cb = ((kk<<6) + ((lane>>4)<<4)) ^ ((lane&7)<<4);
        af[m][kk] = *(const short8*)(Ab + row*128 + cb);
        bf[m][kk] = *(const short8*)(Bb + row*128 + cb);
      }
    }
    asm volatile("s_waitcnt lgkmcnt(0)" ::: "memory");
    __builtin_amdgcn_sched_barrier(0);
    __builtin_amdgcn_s_setprio(1);
    #pragma unroll
    for(int m=0;m<2;m++){
      #pragma unroll
      for(int n=0;n<4;n++){
        #pragma unroll
        for(int kk=0;kk<2;kk++) mfma16(acc[m][n], af[m][kk], bf[n][kk]);
      }
    }
    __builtin_amdgcn_s_setprio(0);
    __builtin_amdgcn_sched_barrier(0);
    __builtin_amdgcn_s_barrier();     // all waves' ds_reads done -> buf free
    __builtin_amdgcn_sched_barrier(0);
    if(T+2 < NK){
      g4_stage(A,  K, m0, (T+2)<<6, LDS + G4_ABUF(buf), tid);
      g4_stage(Bt, K, n0, (T+2)<<6, LDS + G4_BBUF(buf), tid);
    }
    __builtin_amdgcn_s_setprio(1);
    #pragma unroll
    for(int m=2;m<4;m++){
      #pragma unroll
      for(int n=0;n<4;n++){
        #pragma unroll
        for(int kk=0;kk<2;kk++) mfma16(acc[m][n], af[m][kk], bf[n][kk]);
      }
    }
    __builtin_amdgcn_s_setprio(0);
    __builtin_amdgcn_sched_barrier(0);
  }
}

// MODE 0: bf16 out [M,N] ; MODE 2: bf16 out + per-row bias
template<int MODE>
__global__ __launch_bounds__(256,2)
void gemm4p_bf16(const u16* __restrict__ A, const u16* __restrict__ Bt,
                 int M, int N, int K,
                 u16* __restrict__ outB, const float* __restrict__ bias){
  extern __shared__ char LDS[];
  const int tid = threadIdx.x;
  const int lane = tid & 63;
  const int wid = tid >> 6;
  const int wr = wid >> 1, wc = wid & 1;
  int bm, bn;
  g_split(M>>7, N>>7, bm, bn);
  const int m0 = bm << 7, n0 = bn << 7;

  f32x4 acc[4][4];
  f32x4 zv = {0.f,0.f,0.f,0.f};
  #pragma unroll
  for(int m=0;m<4;m++){
    #pragma unroll
    for(int n=0;n<4;n++) acc[m][n] = zv;
  }
  g4_core(A, Bt, K, m0, n0, acc, LDS, tid);

  const int rbase = (lane>>4)<<2;
  const int cbase = lane & 15;
  #pragma unroll
  for(int m=0;m<4;m++){
    int row0 = m0 + (wr<<6) + (m<<4) + rbase;
    #pragma unroll
    for(int n=0;n<4;n++){
      int col = n0 + (wc<<6) + (n<<4) + cbase;
      #pragma unroll
      for(int r=0;r<4;r++){
        float v = acc[m][n][r];
        if(MODE==2) v += bias[row0+r];
        outB[(size_t)(row0+r)*N + col] = (u16)f2b1(v);
      }
    }
  }
}

// ---------- split-K GEMM (m97-style): atomics into GT ----------
__global__ __launch_bounds__(256,2)
void gemm_splitk(const u16* __restrict__ A, const u16* __restrict__ Bt,
                 int M, int N, int K, float* __restrict__ outF, int kchunk){
  __shared__ u16 As[128*64];
  __shared__ u16 Bs[128*64];
  const int t = threadIdx.x;
  const int lane = t & 63;
  const int w = t >> 6;
  const int wr = w >> 1, wc = w & 1;
  int nchunks = (K + kchunk - 1)/kchunk;
  int bm = (int)blockIdx.x / nchunks;
  int ch = (int)blockIdx.x - bm*nchunks;
  int k0 = ch*kchunk, k1 = k0 + kchunk; if(k1 > K) k1 = K;
  const int m0 = bm << 7, n0 = 0;

  f32x4 zv = {0.f,0.f,0.f,0.f};
  f32x4 acc[4][4];
  #pragma unroll
  for(int m=0;m<4;m++){
    #pragma unroll
    for(int n=0;n<4;n++) acc[m][n] = zv;
  }
  const int srow = t >> 3;
  const int scol = (t & 7) << 3;
  const u16* Ag = A + (size_t)(m0 + srow)*K + scol;
  const u16* Bg = Bt + (size_t)(n0 + srow)*K + scol;
  u16* Al = &As[t*8];
  u16* Bl = &Bs[t*8];

  for(int kt=k0; kt<k1; kt+=64){
    __syncthreads();
    #pragma unroll
    for(int i=0;i<4;i++){
      async16(Ag + (size_t)(i*32)*K + kt, Al + i*2048);
      async16(Bg + (size_t)(i*32)*K + kt, Bl + i*2048);
    }
    __syncthreads();
    #pragma unroll
    for(int kk=0; kk<64; kk+=32){
      const int ko = kk + ((lane>>4)<<3);
      short8 af[4], bfv[4];
      #pragma unroll
      for(int m=0;m<4;m++) af[m] = *(const short8*)&As[((wr<<6)+(m<<4)+(lane&15))*64 + ko];
      #pragma unroll
      for(int n=0;n<4;n++) bfv[n] = *(const short8*)&Bs[((wc<<6)+(n<<4)+(lane&15))*64 + ko];
      #pragma unroll
      for(int m=0;m<4;m++){
        #pragma unroll
        for(int n=0;n<4;n++) mfma16(acc[m][n], af[m], bfv[n]);
      }
    }
  }
  const int rbase = (lane>>4)<<2;
  const int cbase = lane & 15;
  #pragma unroll
  for(int m=0;m<4;m++){
    int row0 = m0 + (wr<<6) + (m<<4) + rbase;
    #pragma unroll
    for(int n=0;n<4;n++){
      int col = n0 + (wc<<6) + (n<<4) + cbase;
      #pragma unroll
      for(int r=0;r<4;r++) atomicAdd(&outF[(size_t)(row0+r)*N + col], acc[m][n][r]);
    }
  }
}

// ---------- host ----------
extern "C" void kernel_launch(void* const* d_in, const int* in_sizes, int n_in,
                              void* d_out, int out_size, void* d_ws, size_t ws_size,
                              hipStream_t stream){
  const float* word  = (const float*)d_in[0];
  const int*   ids   = (const int*)d_in[1];
  const int*   cids  = (const int*)d_in[2];
  const void*  mask  = d_in[3];
  const int*   co_ei = (const int*)d_in[4];
  const float* co_ew = (const float*)d_in[5];
  const int*   re_ei = (const int*)d_in[6];
  const float* re_ew = (const float*)d_in[7];
  const float* png   = (const float*)d_in[8];
  const float* co_W  = (const float*)d_in[9];
  const float* co_b  = (const float*)d_in[10];
  const float* re_W  = (const float*)d_in[11];
  const float* re_b  = (const float*)d_in[12];
  const float* pn_W  = (const float*)d_in[13];
  const float* pn_b  = (const float*)d_in[14];
  const float* zw    = (const float*)d_in[15];
  const float* zb    = (const float*)d_in[16];
  const float* zwp   = (const float*)d_in[17];
  const float* zbp   = (const float*)d_in[18];
  float* out = (float*)d_out;

  hipFuncSetAttribute((const void*)gemm4p_bf16<0>, hipFuncAttributeMaxDynamicSharedMemorySize, G4_LDS);
  hipFuncSetAttribute((const void*)gemm4p_bf16<2>, hipFuncAttributeMaxDynamicSharedMemorySize, G4_LDS);
  hipFuncSetAttribute((const void*)gemm8p_zc,      hipFuncAttributeMaxDynamicSharedMemorySize, G8_LDS);

  char* wsb = (char*)d_ws;
  size_t off = 0;
  auto alloc = [&](size_t bytes)->void*{ void* p = wsb + off; off += (bytes + 255) & ~(size_t)255; return p; };
  u16* WORDB = (u16*)alloc((size_t)M_PAD*HIDC*2);
  u16* BUFB  = (u16*)alloc((size_t)M_PAD*HIDC*2);
  u16* BUFX  = (u16*)alloc((size_t)M_PAD*HIDC*2);
  u16* ZWALL = (u16*)alloc((size_t)2*ZNC*HIDC*2);
  u16* WT2   = (u16*)alloc((size_t)2*3*HIDC*HIDC*2);
  u16* PNWB  = (u16*)alloc((size_t)HIDC*HIDC*2);
  u16* PNB   = (u16*)alloc((size_t)128*M_PAD*2);
  u16* TOKALL= (u16*)alloc((size_t)3*TOKM*HIDC*2);
  float2* TOKF = (float2*)alloc((size_t)TOKM*HIDC*4);
  float* GT   = (float*)alloc((size_t)HIDC*128*4);
  float* DEG2 = (float*)alloc((size_t)2*N_NODESC*4);
  int*   CNT2 = (int*)alloc((size_t)2*N_NODESC*4);
  float* DINVA = (float*)alloc((size_t)2*N_NODESC*4);
  float* DINVB = (float*)alloc((size_t)2*N_NODESC*4);
  int*   RP2  = (int*)alloc((size_t)2*NN1*4);
  int*   CUR2 = (int*)alloc((size_t)2*N_NODESC*4);
  int*   PART2= (int*)alloc((size_t)2*NBLK*4);
  float2* EMETA=(float2*)alloc((size_t)2*NEC*8);
  u32*   NEED = (u32*)alloc((size_t)N_NODESC*4);
  u32*   NEED1= (u32*)alloc((size_t)2*N_NODESC*4);
  int*   TMAP = (int*)alloc((size_t)N_NODESC*4);
  int*   NXT  = (int*)alloc((size_t)TOKM*4);
  float* INVM = (float*)alloc((size_t)TOKM*4);
  (void)ws_size; (void)in_sizes; (void)n_in; (void)out_size;

  const int GD_TOK = (TOKM*384 + 255)/256;
  const int GD_E   = (NEC + 255)/256;
  const int SPMM_GD  = (N_NODESC + 3)/4;
  const int PN_NCHUNKS = M_PAD/PN_KCHUNK;               // 60
  const int G_PN  = (HIDC/128)*PN_NCHUNKS;              // 360
  const int G4_GCN = (M_PAD/128)*(HIDC/128);            // 1440
  const int G4_CBT = (HIDC/128)*(M_PAD/128);            // 1440
  const int G8_ZC  = (TOKM/256)*(ZNC/256);              // 288
  const int NCONV  = HIDC*HIDC/2 + 2*(ZNC*HIDC/2);

  // ---- prep ----
  hipMemsetAsync(NEED, 0, (size_t)N_NODESC*4, stream);
  hipMemsetAsync(NEED1, 0, (size_t)2*N_NODESC*4, stream);
  hipMemsetAsync(TMAP, 0xFF, (size_t)N_NODESC*4, stream);
  hipMemsetAsync(DEG2, 0, (size_t)2*N_NODESC*4, stream);
  hipMemsetAsync(CNT2, 0, (size_t)2*N_NODESC*4, stream);
  hipMemsetAsync(TOKALL, 0, (size_t)2*TOKM*HIDC*2, stream);   // co/re segments (padding tokens stay 0)
  k_invmask<<<1,256,0,stream>>>(mask, INVM);
  k_needed<<<(TOKM+255)/256,256,0,stream>>>(ids, NEED, NEED1, TMAP, NXT);
  k_need_expand<<<dim3(GD_E,2),256,0,stream>>>(co_ei, re_ei, NEED, NEED1);
  k_convAll<<<(NCONV + 255)/256,256,0,stream>>>(pn_W, zw, zwp, PNWB, ZWALL);
  k_conv_pad<<<(M_PAD*384 + 255)/256,256,0,stream>>>(word, WORDB, N_NODESC, M_PAD);
  k_transposeW2<<<dim3((3*HIDC*384 + 255)/256, 2),256,0,stream>>>(co_W, re_W, WT2);

  // ---- batched CSR build ----
  k_degcnt2<<<dim3(GD_E,2),256,0,stream>>>(co_ei, re_ei, co_ew, re_ew, DEG2, CNT2);
  k_scan1<<<dim3(NBLK,2),256,0,stream>>>(CNT2, PART2, DEG2, DINVA, DINVB);
  k_scan2<<<2,128,0,stream>>>(PART2, RP2);
  k_scan3<<<dim3(NBLK,2),256,0,stream>>>(CNT2, PART2, RP2, CUR2);
  k_scatter2<<<dim3(GD_E,2),256,0,stream>>>(co_ei, re_ei, co_ew, re_ew, DINVA, CUR2, EMETA);

  // ---- pn path: cbT = pnW·word^T (+row bias), GT = cbT·pn^T (split-K), gather ----
  gemm4p_bf16<2><<<G4_CBT,256,G4_LDS,stream>>>(PNWB, WORDB, HIDC, M_PAD, HIDC, BUFX, pn_b);
  k_pnb<<<(128*(M_PAD/2) + 255)/256,256,0,stream>>>(png, PNB);
  hipMemsetAsync(GT, 0, (size_t)HIDC*128*4, stream);
  gemm_splitk<<<G_PN,256,0,stream>>>(BUFX, PNB, HIDC, 128, M_PAD, GT, PN_KCHUNK);
  k_gather_pn<<<GD_TOK,256,0,stream>>>(GT, cids, TOKALL + (size_t)2*TOKM*HIDC);

  // ---- GCN stacks ----
  // layer filters: L0 = none; L1 = NEED1; L2 = NEED.
  // token outputs fused into spmm epilogue (node->token chain); L2 skips hout.
  auto run_graph = [&](int g, const float* bf, u16* tokb){
    const int* rp = RP2 + (size_t)g*NN1;
    const float2* em = EMETA + (size_t)g*NEC;
    const float* di2 = DINVB + (size_t)g*N_NODESC;
    const u16* X = WORDB;
    for(int i=0;i<3;i++){
      gemm4p_bf16<0><<<G4_GCN,256,G4_LDS,stream>>>(X, WT2 + ((size_t)g*3 + i)*HIDC*HIDC,
                                                   M_PAD, HIDC, HIDC, BUFB, nullptr);
      const u32* flt = (i==2) ? NEED : (i==1 ? NEED1 + (size_t)g*N_NODESC : nullptr);
      k_spmm<<<SPMM_GD,256,0,stream>>>(BUFB, rp, em, di2, bf + i*HIDC, BUFX, flt,
                                       TMAP, NXT, TOKF, tokb, i);
      X = BUFX;
    }
  };
  run_graph(0, co_b, TOKALL);
  run_graph(1, re_b, TOKALL + (size_t)TOKM*HIDC);

  // ---- zero-convs -> outputs ----
  dim3 zgrid(G8_ZC, 1, 3);
  gemm8p_zc<<<zgrid,512,G8_LDS,stream>>>(TOKALL, ZWALL, zb, zbp, INVM, out);
  k_zerocol<<<(3*LLAY*4*HIDC + 255)/256,256,0,stream>>>(out);
}

// Round 8
// 1086.254 us; speedup vs baseline: 1.4097x; 1.0339x over previous
//
#include <hip/hip_runtime.h>
#include <stdint.h>

typedef unsigned int u32;
typedef unsigned short u16;
typedef __attribute__((ext_vector_type(8))) short short8;
typedef __attribute__((ext_vector_type(4))) float f32x4;

#define N_NODESC 30522
#define HIDC 768
#define NEC 488352
#define TOKM 2048
#define LLAY 12
#define NCLS 101
#define M_PAD 30720     // 120*256
#define ZNC (LLAY*HIDC) // 9216
#define OUT_SET (LLAY*4*513*HIDC)
#define PN_KCHUNK 512
#define NBLK 120
#define NN1 (N_NODESC+1)
#define G4_LDS 65536
#define G8_LDS 131072

// ---------- helpers ----------
__device__ __forceinline__ float bl(u32 u){ return __uint_as_float(u<<16); }
__device__ __forceinline__ float bh(u32 u){ return __uint_as_float(u & 0xffff0000u); }
__device__ __forceinline__ u32 f2b1(float f){ u32 x=__float_as_uint(f); return (x + 0x7fffu + ((x>>16)&1u))>>16; }
__device__ __forceinline__ u32 pack2(float a, float b){ return f2b1(a) | (f2b1(b)<<16); }

__device__ __forceinline__ void mfma16(f32x4& d, short8 a, short8 b){
  asm volatile("v_mfma_f32_16x16x32_bf16 %0, %1, %2, %0" : "+v"(d) : "v"(a), "v"(b));
}
__device__ __forceinline__ void async16(const void* g, void* l){
  __builtin_amdgcn_global_load_lds((const __attribute__((address_space(1))) u32*)g,
                                   (__attribute__((address_space(3))) u32*)l, 16, 0, 0);
}
// bit-identical decode of a float2 {src_as_float_bits, weight} loaded as one double
__device__ __forceinline__ void em_dec(double d, int& s, float& w){
  unsigned long long b = __double_as_longlong(d);
  s = (int)(u32)b;
  w = __uint_as_float((u32)(b>>32));
}

// ---------- mask normalize ----------
__global__ void k_invmask(const void* __restrict__ mask, float* __restrict__ invm){
  __shared__ int s_byte, s_flt;
  int t = threadIdx.x;
  const unsigned char* mb = (const unsigned char*)mask;
  const u32* mw = (const u32*)mask;
  int lb=0, lf=0;
  for(int i=t;i<2048;i+=256) if((i&3)!=0 && mb[i]!=0) lb=1;
  for(int i=t;i<512;i+=256) if(mw[i]==0x3F800000u) lf=1;
  if(t==0){ s_byte=0; s_flt=0; }
  __syncthreads();
  if(lb) s_byte=1;
  if(lf) s_flt=1;
  __syncthreads();
  int mode = s_flt ? 2 : (s_byte ? 1 : 0);
  for(int p=t;p<2048;p+=256){
    int mv = (mode==1) ? (int)mb[p] : (int)(mw[p]!=0u);
    invm[p] = mv ? 0.f : 1.f;
  }
}

// token->node marking + node->token inverted chain (TMAP pre-memset -1, NEED1 pre-memset 0)
__global__ void k_needed(const int* __restrict__ ids, u32* __restrict__ needed,
                         u32* __restrict__ need1,
                         int* __restrict__ tmap, int* __restrict__ nxt){
  int p = blockIdx.x*256 + threadIdx.x;
  if(p < TOKM){
    int id = ids[p];
    if(id < N_NODESC){
      needed[id] = 1u;
      need1[id] = 1u;
      need1[N_NODESC + id] = 1u;
      int old = atomicExch(&tmap[id], p);
      nxt[p] = old;
    }
  }
}

__global__ void k_need_expand(const int* __restrict__ coei, const int* __restrict__ reei,
                              const u32* __restrict__ needed, u32* __restrict__ need1){
  int g = blockIdx.y;
  const int* ei = g ? reei : coei;
  int e = blockIdx.x*256 + threadIdx.x;
  if(e < NEC){
    int d = ei[NEC+e];
    if(needed[d]) need1[(size_t)g*N_NODESC + ei[e]] = 1u;
  }
}

// ---------- converts (merged: pnW + zw + zwp + pn_graph) ----------
__global__ void k_convAll(const float* __restrict__ pnW, const float* __restrict__ zw,
                          const float* __restrict__ zwp, const float* __restrict__ png,
                          u16* __restrict__ pnwb, u16* __restrict__ zwall,
                          u16* __restrict__ pnb){
  const int NP = HIDC*HIDC/2;
  const int NZ = ZNC*HIDC/2;
  const int NB = 128*(M_PAD/2);
  int i = blockIdx.x*256 + threadIdx.x;
  if(i < NP){
    ((u32*)pnwb)[i] = pack2(pnW[2*i], pnW[2*i+1]);
  } else if(i < NP + NZ){
    int j = i - NP;
    ((u32*)zwall)[j] = pack2(zw[2*j], zw[2*j+1]);
  } else if(i < NP + 2*NZ){
    int j = i - NP - NZ;
    ((u32*)zwall)[NZ + j] = pack2(zwp[2*j], zwp[2*j+1]);
  } else if(i < NP + 2*NZ + NB){
    int j = i - NP - 2*NZ;
    int row = j/(M_PAD/2); int k2 = (j - row*(M_PAD/2))*2;
    float lo=0.f, hi=0.f;
    if(row < NCLS){
      const float* s = png + (size_t)row*N_NODESC;
      if(k2 < N_NODESC) lo = s[k2];
      if(k2+1 < N_NODESC) hi = s[k2+1];
    }
    ((u32*)pnb)[j] = pack2(lo, hi);
  }
}
__global__ void k_conv_pad(const float* __restrict__ src, u16* __restrict__ dst, int srcRows, int padRows){
  int i = blockIdx.x*256 + threadIdx.x;
  if(i >= padRows*384) return;
  int row = i/384; int c2 = (i - row*384)*2;
  float lo=0.f, hi=0.f;
  if(row < srcRows){ const float* s = src + (size_t)row*HIDC + c2; lo=s[0]; hi=s[1]; }
  ((u32*)dst)[i] = pack2(lo, hi);
}
__global__ void k_transposeW2(const float* __restrict__ coW, const float* __restrict__ reW,
                              u16* __restrict__ Wt2){
  int g = blockIdx.y;
  int i = blockIdx.x*256 + threadIdx.x;
  if(i >= 3*HIDC*384) return;
  const float* W = g ? reW : coW;
  int mat = i/(HIDC*384); int rem = i - mat*HIDC*384;
  int n = rem/384; int kd = rem - n*384;
  const float* Wm = W + (size_t)mat*HIDC*HIDC;
  float lo = Wm[(size_t)(2*kd)*HIDC + n];
  float hi = Wm[(size_t)(2*kd+1)*HIDC + n];
  ((u32*)Wt2)[(size_t)g*3*HIDC*384 + (size_t)mat*HIDC*384 + (size_t)n*384 + kd] = pack2(lo, hi);
}

// ---------- batched graph prep ----------
__global__ void k_degcnt2(const int* __restrict__ coei, const int* __restrict__ reei,
                          const float* __restrict__ coew, const float* __restrict__ reew,
                          float* __restrict__ deg2, int* __restrict__ cnt2){
  int g = blockIdx.y;
  const int* ei = g ? reei : coei;
  const float* ew = g ? reew : coew;
  int e = blockIdx.x*256 + threadIdx.x;
  if(e < NEC){ int d = ei[NEC+e]; atomicAdd(&deg2[(size_t)g*N_NODESC + d], ew[e]); atomicAdd(&cnt2[(size_t)g*N_NODESC + d], 1); }
}
// scan1 with fused dinv computation (same geometry, same DEG2/CNT2 dependency)
__global__ void k_scan1(const int* __restrict__ cnt2, int* __restrict__ part2,
                        const float* __restrict__ deg2,
                        float* __restrict__ dinvA, float* __restrict__ dinvB){
  __shared__ int wt[4];
  int g = blockIdx.y, b = blockIdx.x, t = threadIdx.x;
  int lane = t & 63, w = t >> 6;
  int i = b*256 + t;
  if(i < N_NODESC){
    float d = deg2[(size_t)g*N_NODESC + i] + 1.f;
    dinvA[(size_t)g*N_NODESC + i] = rsqrtf(d);
    dinvB[(size_t)g*N_NODESC + i] = 1.f/d;
  }
  int v = (i < N_NODESC) ? cnt2[(size_t)g*N_NODESC + i] : 0;
  int x = v;
  #pragma unroll
  for(int off=1; off<64; off<<=1){ int y = __shfl_up(x, off); if(lane>=off) x += y; }
  if(lane==63) wt[w] = x;
  __syncthreads();
  if(t==0) part2[g*NBLK + b] = wt[0]+wt[1]+wt[2]+wt[3];
}
__global__ void k_scan2(int* __restrict__ part2, int* __restrict__ rp2){
  __shared__ int w0tot;
  int g = blockIdx.x, t = threadIdx.x;   // 128 threads
  int lane = t & 63, w = t >> 6;
  int v = (t < NBLK) ? part2[g*NBLK + t] : 0;
  int x = v;
  #pragma unroll
  for(int off=1; off<64; off<<=1){ int y = __shfl_up(x, off); if(lane>=off) x += y; }
  if(w==0 && lane==63) w0tot = x;
  __syncthreads();
  int incl = x + (w ? w0tot : 0);
  int excl = incl - v;
  if(t < NBLK) part2[g*NBLK + t] = excl;
  if(t == 127) rp2[(size_t)g*NN1 + N_NODESC] = incl;
}
__global__ void k_scan3(const int* __restrict__ cnt2, const int* __restrict__ part2,
                        int* __restrict__ rp2, int* __restrict__ cur2){
  __shared__ int wt[4];
  int g = blockIdx.y, b = blockIdx.x, t = threadIdx.x;
  int lane = t & 63, w = t >> 6;
  int i = b*256 + t;
  int v = (i < N_NODESC) ? cnt2[(size_t)g*N_NODESC + i] : 0;
  int x = v;
  #pragma unroll
  for(int off=1; off<64; off<<=1){ int y = __shfl_up(x, off); if(lane>=off) x += y; }
  if(lane==63) wt[w] = x;
  __syncthreads();
  int wpre = 0;
  #pragma unroll
  for(int j=0;j<4;j++) if(j<w) wpre += wt[j];
  int excl = x - v + wpre + part2[g*NBLK + b];
  if(i < N_NODESC){ rp2[(size_t)g*NN1 + i] = excl; cur2[(size_t)g*N_NODESC + i] = excl; }
}
__global__ void k_scatter2(const int* __restrict__ coei, const int* __restrict__ reei,
                           const float* __restrict__ coew, const float* __restrict__ reew,
                           const float* __restrict__ dinvA, int* __restrict__ cur2,
                           float2* __restrict__ emeta){
  int g = blockIdx.y;
  const int* ei = g ? reei : coei;
  const float* ew = g ? reew : coew;
  int e = blockIdx.x*256 + threadIdx.x;
  if(e < NEC){
    int s = ei[e], d = ei[NEC+e];
    int pos = atomicAdd(&cur2[(size_t)g*N_NODESC + d], 1);
    float nrm = dinvA[(size_t)g*N_NODESC + s]*ew[e]*dinvA[(size_t)g*N_NODESC + d];
    emeta[(size_t)g*NEC + pos] = make_float2(__int_as_float(s), nrm);
  }
}

// ---------- SpMM with fused token scatter, graph-batched (y = graph when batched) ----------
// g = gbase + blockIdx.y selects shared per-graph arrays (rp/em/dinv/NEED1/tokb);
// hW/hout/tokf use blockIdx.y*stride (stride 0 in sequential fallback -> shared bufs).
// FP math identical to prior round (8/4/1-edge groups, same add order) -> bit-identical.
__global__ __launch_bounds__(256)
void k_spmm2(const u16* __restrict__ hWb, size_t hstride,
             const int* __restrict__ rp2, const float2* __restrict__ emb,
             const float* __restrict__ dinvb,
             const float* __restrict__ bias_co, const float* __restrict__ bias_re,
             u16* __restrict__ houtb, size_t ostride,
             const u32* __restrict__ needarr, const u32* __restrict__ need1,
             const int* __restrict__ tmap, const int* __restrict__ nxt,
             float2* __restrict__ tokfb, size_t tfstride,
             u16* __restrict__ tokall, int phase, int gbase){
  const int g = gbase + blockIdx.y;
  const u16* hW = hWb + (size_t)blockIdx.y*hstride;
  const int* rp = rp2 + (size_t)g*NN1;
  const double* em8 = (const double*)(emb + (size_t)g*NEC);
  const float* dinv2 = dinvb + (size_t)g*N_NODESC;
  const float* bias = (g ? bias_re : bias_co) + phase*HIDC;
  u16* hout = houtb + (size_t)blockIdx.y*ostride;
  const u32* flt = (phase==2) ? needarr : (phase==1 ? need1 + (size_t)g*N_NODESC : nullptr);
  float2* tokf = tokfb + (size_t)blockIdx.y*tfstride;
  u16* tokb = tokall + (size_t)g*TOKM*HIDC;

  int v = blockIdx.x*4 + (threadIdx.x>>6);
  if(v >= N_NODESC) return;
  if(flt && !flt[v]) return;
  int lane = threadIdx.x & 63;
  const u32* H = (const u32*)hW;
  float acc[12];
  #pragma unroll
  for(int q=0;q<12;q++) acc[q]=0.f;
  int e0 = rp[v], e1 = rp[v+1];
  int e = e0;
  for(; e+8<=e1; e+=8){
    int s[8]; float w[8];
    #pragma unroll
    for(int j=0;j<8;j++) em_dec(__builtin_nontemporal_load(em8+e+j), s[j], w[j]);
    const u32* r[8];
    #pragma unroll
    for(int j=0;j<8;j++) r[j] = H + (size_t)s[j]*384 + lane;
    u32 u[8][6];
    #pragma unroll
    for(int j=0;j<8;j++){
      #pragma unroll
      for(int q=0;q<6;q++) u[j][q] = r[j][q*64];
    }
    #pragma unroll
    for(int q=0;q<6;q++){
      acc[2*q]   += w[0]*bl(u[0][q]) + w[1]*bl(u[1][q]) + w[2]*bl(u[2][q]) + w[3]*bl(u[3][q]);
      acc[2*q+1] += w[0]*bh(u[0][q]) + w[1]*bh(u[1][q]) + w[2]*bh(u[2][q]) + w[3]*bh(u[3][q]);
      acc[2*q]   += w[4]*bl(u[4][q]) + w[5]*bl(u[5][q]) + w[6]*bl(u[6][q]) + w[7]*bl(u[7][q]);
      acc[2*q+1] += w[4]*bh(u[4][q]) + w[5]*bh(u[5][q]) + w[6]*bh(u[6][q]) + w[7]*bh(u[7][q]);
    }
  }
  for(; e+4<=e1; e+=4){
    int s0,s1,s2,s3; float w0,w1,w2,w3;
    em_dec(__builtin_nontemporal_load(em8+e  ), s0, w0);
    em_dec(__builtin_nontemporal_load(em8+e+1), s1, w1);
    em_dec(__builtin_nontemporal_load(em8+e+2), s2, w2);
    em_dec(__builtin_nontemporal_load(em8+e+3), s3, w3);
    const u32* r0 = H + (size_t)s0*384 + lane;
    const u32* r1 = H + (size_t)s1*384 + lane;
    const u32* r2 = H + (size_t)s2*384 + lane;
    const u32* r3 = H + (size_t)s3*384 + lane;
    u32 u0[6],u1[6],u2[6],u3[6];
    #pragma unroll
    for(int q=0;q<6;q++){ u0[q]=r0[q*64]; u1[q]=r1[q*64]; u2[q]=r2[q*64]; u3[q]=r3[q*64]; }
    #pragma unroll
    for(int q=0;q<6;q++){
      acc[2*q]   += w0*bl(u0[q]) + w1*bl(u1[q]) + w2*bl(u2[q]) + w3*bl(u3[q]);
      acc[2*q+1] += w0*bh(u0[q]) + w1*bh(u1[q]) + w2*bh(u2[q]) + w3*bh(u3[q]);
    }
  }
  for(; e<e1; ++e){
    int ss; float ww;
    em_dec(__builtin_nontemporal_load(em8+e), ss, ww);
    const u32* r = H + (size_t)ss*384 + lane;
    #pragma unroll
    for(int q=0;q<6;q++){ u32 u = r[q*64]; acc[2*q] += ww*bl(u); acc[2*q+1] += ww*bh(u); }
  }
  { float wgt = dinv2[v];
    const u32* r = H + (size_t)v*384 + lane;
    #pragma unroll
    for(int q=0;q<6;q++){ u32 u = r[q*64]; acc[2*q] += wgt*bl(u); acc[2*q+1] += wgt*bh(u); }
  }
  const float2* B2 = (const float2*)bias;
  u32 wv[6];
  #pragma unroll
  for(int q=0;q<6;q++){
    float2 bb = B2[lane + 64*q];
    float x0 = fmaxf(acc[2*q]+bb.x, 0.f);
    float x1 = fmaxf(acc[2*q+1]+bb.y, 0.f);
    wv[q] = pack2(x0, x1);
  }
  if(phase != 2){
    u32* O = (u32*)hout + (size_t)v*384 + lane;
    #pragma unroll
    for(int q=0;q<6;q++) O[q*64] = wv[q];
  }
  int p = tmap[v];                       // wave-uniform; almost always -1
  while(p >= 0){
    float2* TF = tokf + (size_t)p*384 + lane;
    if(phase == 0){
      #pragma unroll
      for(int q=0;q<6;q++)
        TF[q*64] = make_float2(bl(wv[q])*(1.f/3.f), bh(wv[q])*(1.f/3.f));
    } else if(phase == 1){
      #pragma unroll
      for(int q=0;q<6;q++){
        float2 c = TF[q*64];
        c.x += bl(wv[q])*(1.f/3.f); c.y += bh(wv[q])*(1.f/3.f);
        TF[q*64] = c;
      }
    } else {
      u32* TB = (u32*)tokb + (size_t)p*384 + lane;
      #pragma unroll
      for(int q=0;q<6;q++){
        float2 c = TF[q*64];
        c.x += bl(wv[q])*(1.f/3.f); c.y += bh(wv[q])*(1.f/3.f);
        TB[q*64] = pack2(c.x, c.y);
      }
    }
    p = nxt[p];
  }
}

__global__ void k_gather_pn(const float* __restrict__ GT, const int* __restrict__ cids, u16* __restrict__ tokb){
  int d = blockIdx.x*256 + threadIdx.x;
  if(d >= TOKM*384) return;
  int p = d/384, q = d - p*384;
  int cid = cids[p];
  float lo = GT[(size_t)(2*q)*128 + cid];
  float hi = GT[(size_t)(2*q+1)*128 + cid];
  ((u32*)tokb)[d] = pack2(lo, hi);
}

// ---------- XCD-chunked bijective block split (shared) ----------
__device__ __forceinline__ void g_split(int ntM, int ntN, int& bm, int& bn){
  int nwg = ntM*ntN;                       // must be %8==0
  int bid = (int)blockIdx.x;
  int wg = (bid & 7)*(nwg>>3) + (bid>>3);  // XCD-chunked, bijective
  if(ntN <= ntM){ bm = wg/ntN; bn = wg - bm*ntN; }
  else          { bn = wg/ntM; bm = wg - bn*ntM; }
}

// ================= 256x256 8-phase GEMM core (1 block/CU) — used for zc =================
#define G8_AOFF(b) ((b)*65536)
#define G8_BOFF(b) ((b)*65536 + 32768)

__device__ __forceinline__ void g8_stage(const u16* __restrict__ src, int ldk, int g0, int kt,
                                         char* half_base, int tid){
  const int lane = tid & 63;
  const int csw = ((lane&7) ^ (lane>>3)) << 3;   // pre-swizzled source col (elements)
  const u16* s0 = src + (size_t)(g0 + (tid>>3))*ldk + (kt + csw);
  const u16* s1 = src + (size_t)(g0 + 64 + (tid>>3))*ldk + (kt + csw);
  async16(s0, half_base + (size_t)tid*16);
  async16(s1, half_base + 8192 + (size_t)tid*16);
}

__device__ __forceinline__ void g8_core(const u16* __restrict__ A, const u16* __restrict__ Bt,
                                        int K, int m0, int n0,
                                        f32x4 (&acc)[8][4], char* LDS, int tid){
  const int lane = tid & 63;
  const int wid = tid >> 6;
  const int wr = wid >> 2, wc = wid & 3;
  const int NK = K >> 6;   // K-tiles (BK=64); requires NK>=3, even

  g8_stage(Bt, K, n0,      0, LDS + G8_BOFF(0),         tid);
  g8_stage(Bt, K, n0+128,  0, LDS + G8_BOFF(0) + 16384, tid);
  g8_stage(A,  K, m0,      0, LDS + G8_AOFF(0),         tid);
  g8_stage(A,  K, m0+128,  0, LDS + G8_AOFF(0) + 16384, tid);
  g8_stage(Bt, K, n0,     64, LDS + G8_BOFF(1),         tid);
  g8_stage(Bt, K, n0+128, 64, LDS + G8_BOFF(1) + 16384, tid);
  asm volatile("s_waitcnt vmcnt(4)" ::: "memory");
  __builtin_amdgcn_sched_barrier(0);
  __builtin_amdgcn_s_barrier();
  __builtin_amdgcn_sched_barrier(0);

  short8 bf8[8];
  for(int T=0; T<NK; ++T){
    const int buf = T & 1;
    const char* Ab = LDS + G8_AOFF(buf) + wr*16384;
    const char* Bb = LDS + G8_BOFF(buf) + (wc>>1)*16384;
    #pragma unroll
    for(int q=0; q<4; ++q){
      if(q==0){
        #pragma unroll
        for(int n=0;n<4;n++){
          #pragma unroll
          for(int kk=0;kk<2;kk++){
            int row = ((wc&1)<<6) + (n<<4) + (lane&15);
            int cb = ((kk<<6) + ((lane>>4)<<4)) ^ ((lane&7)<<4);
            bf8[n*2+kk] = *(const short8*)(Bb + row*128 + cb);
          }
        }
      }
      short8 af[2][2];
      #pragma unroll
      for(int j=0;j<2;j++){
        #pragma unroll
        for(int kk=0;kk<2;kk++){
          int row = ((2*q+j)<<4) + (lane&15);
          int cb = ((kk<<6) + ((lane>>4)<<4)) ^ ((lane&7)<<4);
          af[j][kk] = *(const short8*)(Ab + row*128 + cb);
        }
      }
      if(q==0 && T+1<NK) g8_stage(A,  K, m0,      (T+1)<<6, LDS + G8_AOFF((T+1)&1),         tid);
      if(q==1 && T+1<NK) g8_stage(A,  K, m0+128,  (T+1)<<6, LDS + G8_AOFF((T+1)&1) + 16384, tid);
      if(q==2 && T+2<NK) g8_stage(Bt, K, n0,      (T+2)<<6, LDS + G8_BOFF(buf),             tid);
      if(q==3 && T+2<NK) g8_stage(Bt, K, n0+128,  (T+2)<<6, LDS + G8_BOFF(buf) + 16384,     tid);
      if(q==3){
        if(T <= NK-3)      asm volatile("s_waitcnt vmcnt(4)" ::: "memory");
        else if(T == NK-2) asm volatile("s_waitcnt vmcnt(0)" ::: "memory");
      }
      __builtin_amdgcn_sched_barrier(0);
      __builtin_amdgcn_s_barrier();
      __builtin_amdgcn_sched_barrier(0);
      __builtin_amdgcn_s_setprio(1);
      #pragma unroll
      for(int j=0;j<2;j++){
        #pragma unroll
        for(int n=0;n<4;n++){
          #pragma unroll
          for(int kk=0;kk<2;kk++) mfma16(acc[2*q+j][n], af[j][kk], bf8[n*2+kk]);
        }
      }
      __builtin_amdgcn_s_setprio(0);
      __builtin_amdgcn_sched_barrier(0);
      __builtin_amdgcn_s_barrier();
      __builtin_amdgcn_sched_barrier(0);
    }
  }
}

// zero-conv GEMM (3 sets via blockIdx.z), g8 core + LDS-staged coalesced fp32 stores.
// Also fills the s=0 zero column inline (was k_zerocol).
__global__ __launch_bounds__(512,2)
void gemm8p_zc(const u16* __restrict__ TOKALL, const u16* __restrict__ ZWALL,
               const float* __restrict__ zb, const float* __restrict__ zbp,
               const float* __restrict__ invm, float* __restrict__ out){
  extern __shared__ char LDS[];
  const int set = blockIdx.z;
  const u16* A  = TOKALL + (size_t)set*TOKM*HIDC;
  const u16* Bt = ZWALL + (set==2 ? (size_t)ZNC*HIDC : 0);
  const float* bias = (set==2) ? zbp : zb;
  const bool use_mask = (set != 2);
  float* o = out + (size_t)set*OUT_SET;

  const int tid = threadIdx.x;
  const int lane = tid & 63;
  const int wid = tid >> 6;
  const int wr = wid >> 2, wc = wid & 3;
  int bm, bn;
  g_split(TOKM>>8, ZNC>>8, bm, bn);     // 8 x 36
  const int m0 = bm << 8, n0 = bn << 8;

  f32x4 acc[8][4];
  f32x4 zv = {0.f,0.f,0.f,0.f};
  #pragma unroll
  for(int m=0;m<8;m++){
    #pragma unroll
    for(int n=0;n<4;n++) acc[m][n] = zv;
  }
  g8_core(A, Bt, HIDC, m0, n0, acc, LDS, tid);

  const int l = n0 / HIDC;
  const int oc0 = n0 - l*HIDC;
  const int lo = lane & 15, hi = lane >> 4;

  #pragma unroll
  for(int pass=0; pass<2; ++pass){
    __syncthreads();
    if(wr == pass){
      #pragma unroll
      for(int m=0;m<8;m++){
        #pragma unroll
        for(int n=0;n<4;n++){
          int col = (wc<<6) + (n<<4) + lo;      // 0..255
          float badd = bias[n0 + col];
          #pragma unroll
          for(int r=0;r<4;r++){
            int lr = (m<<4) + (hi<<2) + r;      // 0..127
            *(float*)(LDS + (size_t)lr*1024 + ((col<<2) ^ ((lr&7)<<4))) = acc[m][n][r] + badd;
          }
        }
      }
    }
    __syncthreads();
    #pragma unroll
    for(int i=0;i<16;i++){
      int lr = (i<<3) + wid;
      int rr = m0 + (pass<<7) + lr;             // global token row
      int b = rr >> 9, s = rr & 511;
      f32x4 v = *(const f32x4*)(LDS + (size_t)lr*1024 + ((lane<<4) ^ ((lr&7)<<4)));
      if(use_mask){ float w = invm[rr]; v = v * w; }
      *(f32x4*)(o + (size_t)((l*4+b)*513 + (s+1))*HIDC + oc0 + (lane<<2)) = v;
      if(s == 0){
        f32x4 z4 = {0.f,0.f,0.f,0.f};
        *(f32x4*)(o + (size_t)((l*4+b)*513)*HIDC + oc0 + (lane<<2)) = z4;
      }
    }
  }
}

// ================= 128x128 2-phase GEMM core (2 blocks/CU) — used for GCN/CBT =================
#define G4_ABUF(b) ((b)*32768)
#define G4_BBUF(b) ((b)*32768 + 16384)

__device__ __forceinline__ void g4_stage(const u16* __restrict__ src, int ldk, int g0, int kt,
                                         char* base, int tid){
  const int lane = tid & 63;
  const int csw = ((lane&7) ^ (lane>>3)) << 3;   // pre-swizzled source col (elements)
  const int r = tid >> 3;                        // 0..31
  #pragma unroll
  for(int h=0; h<4; ++h)
    async16(src + (size_t)(g0 + h*32 + r)*ldk + (kt + csw), base + h*4096 + (size_t)tid*16);
}

__device__ __forceinline__ void g4_core(const u16* __restrict__ A, const u16* __restrict__ Bt,
                                        int K, int m0, int n0,
                                        f32x4 (&acc)[4][4], char* LDS, int tid){
  const int lane = tid & 63;
  const int wid = tid >> 6;
  const int wr = wid >> 1, wc = wid & 1;
  const int NK = K >> 6;   // requires NK>=2

  g4_stage(A,  K, m0,  0, LDS + G4_ABUF(0), tid);
  g4_stage(Bt, K, n0,  0, LDS + G4_BBUF(0), tid);
  g4_stage(A,  K, m0, 64, LDS + G4_ABUF(1), tid);
  g4_stage(Bt, K, n0, 64, LDS + G4_BBUF(1), tid);

  short8 af[4][2], bf[4][2];
  for(int T=0; T<NK; ++T){
    const int buf = T & 1;
    const char* Ab = LDS + G4_ABUF(buf) + wr*8192;
    const char* Bb = LDS + G4_BBUF(buf) + wc*8192;
    if(T+1 < NK) asm volatile("s_waitcnt vmcnt(8)" ::: "memory");
    else         asm volatile("s_waitcnt vmcnt(0)" ::: "memory");
    __builtin_amdgcn_sched_barrier(0);
    __builtin_amdgcn_s_barrier();
    __builtin_amdgcn_sched_barrier(0);
    #pragma unroll
    for(int m=0;m<4;m++){
      #pragma unroll
      for(int kk=0;kk<2;kk++){
        int row = (m<<4) + (lane&15);
        int cb = ((kk<<6) + ((lane>>4)<<4)) ^ ((lane&7)<<4);
        af[m][kk] = *(const short8*)(Ab + row*128 + cb);
        bf[m][kk] = *(const short8*)(Bb + row*128 + cb);
      }
    }
    asm volatile("s_waitcnt lgkmcnt(0)" ::: "memory");
    __builtin_amdgcn_sched_barrier(0);
    __builtin_amdgcn_s_setprio(1);
    #pragma unroll
    for(int m=0;m<2;m++){
      #pragma unroll
      for(int n=0;n<4;n++){
        #pragma unroll
        for(int kk=0;kk<2;kk++) mfma16(acc[m][n], af[m][kk], bf[n][kk]);
      }
    }
    __builtin_amdgcn_s_setprio(0);
    __builtin_amdgcn_sched_barrier(0);
    __builtin_amdgcn_s_barrier();     // all waves' ds_reads done -> buf free
    __builtin_amdgcn_sched_barrier(0);
    if(T+2 < NK){
      g4_stage(A,  K, m0, (T+2)<<6, LDS + G4_ABUF(buf), tid);
      g4_stage(Bt, K, n0, (T+2)<<6, LDS + G4_BBUF(buf), tid);
    }
    __builtin_amdgcn_s_setprio(1);
    #pragma unroll
    for(int m=2;m<4;m++){
      #pragma unroll
      for(int n=0;n<4;n++){
        #pragma unroll
        for(int kk=0;kk<2;kk++) mfma16(acc[m][n], af[m][kk], bf[n][kk]);
      }
    }
    __builtin_amdgcn_s_setprio(0);
    __builtin_amdgcn_sched_barrier(0);
  }
}

// bias + bf16 out, used for cbT (pn path)
__global__ __launch_bounds__(256,2)
void gemm4p_bias(const u16* __restrict__ A, const u16* __restrict__ Bt,
                 int M, int N, int K,
                 u16* __restrict__ outB, const float* __restrict__ bias){
  extern __shared__ char LDS[];
  const int tid = threadIdx.x;
  const int lane = tid & 63;
  const int wid = tid >> 6;
  const int wr = wid >> 1, wc = wid & 1;
  int bm, bn;
  g_split(M>>7, N>>7, bm, bn);
  const int m0 = bm << 7, n0 = bn << 7;

  f32x4 acc[4][4];
  f32x4 zv = {0.f,0.f,0.f,0.f};
  #pragma unroll
  for(int m=0;m<4;m++){
    #pragma unroll
    for(int n=0;n<4;n++) acc[m][n] = zv;
  }
  g4_core(A, Bt, K, m0, n0, acc, LDS, tid);

  const int rbase = (lane>>4)<<2;
  const int cbase = lane & 15;
  #pragma unroll
  for(int m=0;m<4;m++){
    int row0 = m0 + (wr<<6) + (m<<4) + rbase;
    #pragma unroll
    for(int n=0;n<4;n++){
      int col = n0 + (wc<<6) + (n<<4) + cbase;
      #pragma unroll
      for(int r=0;r<4;r++){
        float v = acc[m][n][r] + bias[row0+r];
        outB[(size_t)(row0+r)*N + col] = (u16)f2b1(v);
      }
    }
  }
}

// GCN layer GEMM, graph-batched via blockIdx.z (z stride 0 in sequential fallback)
__global__ __launch_bounds__(256,2)
void gemm4p_gcn(const u16* __restrict__ Xb, size_t xstride,
                const u16* __restrict__ wt2, int layer,
                u16* __restrict__ outb, size_t ostride, int gbase){
  extern __shared__ char LDS[];
  const int g = gbase + blockIdx.z;
  const u16* A = Xb + (size_t)blockIdx.z*xstride;
  const u16* Bt = wt2 + ((size_t)g*3 + layer)*HIDC*HIDC;
  u16* outB = outb + (size_t)blockIdx.z*ostride;

  const int tid = threadIdx.x;
  const int lane = tid & 63;
  const int wid = tid >> 6;
  const int wr = wid >> 1, wc = wid & 1;
  int bm, bn;
  g_split(M_PAD>>7, HIDC>>7, bm, bn);      // 240 x 6
  const int m0 = bm << 7, n0 = bn << 7;

  f32x4 acc[4][4];
  f32x4 zv = {0.f,0.f,0.f,0.f};
  #pragma unroll
  for(int m=0;m<4;m++){
    #pragma unroll
    for(int n=0;n<4;n++) acc[m][n] = zv;
  }
  g4_core(A, Bt, HIDC, m0, n0, acc, LDS, tid);

  const int rbase = (lane>>4)<<2;
  const int cbase = lane & 15;
  #pragma unroll
  for(int m=0;m<4;m++){
    int row0 = m0 + (wr<<6) + (m<<4) + rbase;
    #pragma unroll
    for(int n=0;n<4;n++){
      int col = n0 + (wc<<6) + (n<<4) + cbase;
      #pragma unroll
      for(int r=0;r<4;r++)
        outB[(size_t)(row0+r)*HIDC + col] = (u16)f2b1(acc[m][n][r]);
    }
  }
}

// ---------- split-K GEMM (m97-style): atomics into GT ----------
__global__ __launch_bounds__(256,2)
void gemm_splitk(const u16* __restrict__ A, const u16* __restrict__ Bt,
                 int M, int N, int K, float* __restrict__ outF, int kchunk){
  __shared__ u16 As[128*64];
  __shared__ u16 Bs[128*64];
  const int t = threadIdx.x;
  const int lane = t & 63;
  const int w = t >> 6;
  const int wr = w >> 1, wc = w & 1;
  int nchunks = (K + kchunk - 1)/kchunk;
  int bm = (int)blockIdx.x / nchunks;
  int ch = (int)blockIdx.x - bm*nchunks;
  int k0 = ch*kchunk, k1 = k0 + kchunk; if(k1 > K) k1 = K;
  const int m0 = bm << 7, n0 = 0;

  f32x4 zv = {0.f,0.f,0.f,0.f};
  f32x4 acc[4][4];
  #pragma unroll
  for(int m=0;m<4;m++){
    #pragma unroll
    for(int n=0;n<4;n++) acc[m][n] = zv;
  }
  const int srow = t >> 3;
  const int scol = (t & 7) << 3;
  const u16* Ag = A + (size_t)(m0 + srow)*K + scol;
  const u16* Bg = Bt + (size_t)(n0 + srow)*K + scol;
  u16* Al = &As[t*8];
  u16* Bl = &Bs[t*8];

  for(int kt=k0; kt<k1; kt+=64){
    __syncthreads();
    #pragma unroll
    for(int i=0;i<4;i++){
      async16(Ag + (size_t)(i*32)*K + kt, Al + i*2048);
      async16(Bg + (size_t)(i*32)*K + kt, Bl + i*2048);
    }
    __syncthreads();
    #pragma unroll
    for(int kk=0; kk<64; kk+=32){
      const int ko = kk + ((lane>>4)<<3);
      short8 af[4], bfv[4];
      #pragma unroll
      for(int m=0;m<4;m++) af[m] = *(const short8*)&As[((wr<<6)+(m<<4)+(lane&15))*64 + ko];
      #pragma unroll
      for(int n=0;n<4;n++) bfv[n] = *(const short8*)&Bs[((wc<<6)+(n<<4)+(lane&15))*64 + ko];
      #pragma unroll
      for(int m=0;m<4;m++){
        #pragma unroll
        for(int n=0;n<4;n++) mfma16(acc[m][n], af[m], bfv[n]);
      }
    }
  }
  const int rbase = (lane>>4)<<2;
  const int cbase = lane & 15;
  #pragma unroll
  for(int m=0;m<4;m++){
    int row0 = m0 + (wr<<6) + (m<<4) + rbase;
    #pragma unroll
    for(int n=0;n<4;n++){
      int col = n0 + (wc<<6) + (n<<4) + cbase;
      #pragma unroll
      for(int r=0;r<4;r++) atomicAdd(&outF[(size_t)(row0+r)*N + col], acc[m][n][r]);
    }
  }
}

// ---------- host ----------
extern "C" void kernel_launch(void* const* d_in, const int* in_sizes, int n_in,
                              void* d_out, int out_size, void* d_ws, size_t ws_size,
                              hipStream_t stream){
  const float* word  = (const float*)d_in[0];
  const int*   ids   = (const int*)d_in[1];
  const int*   cids  = (const int*)d_in[2];
  const void*  mask  = d_in[3];
  const int*   co_ei = (const int*)d_in[4];
  const float* co_ew = (const float*)d_in[5];
  const int*   re_ei = (const int*)d_in[6];
  const float* re_ew = (const float*)d_in[7];
  const float* png   = (const float*)d_in[8];
  const float* co_W  = (const float*)d_in[9];
  const float* co_b  = (const float*)d_in[10];
  const float* re_W  = (const float*)d_in[11];
  const float* re_b  = (const float*)d_in[12];
  const float* pn_W  = (const float*)d_in[13];
  const float* pn_b  = (const float*)d_in[14];
  const float* zw    = (const float*)d_in[15];
  const float* zb    = (const float*)d_in[16];
  const float* zwp   = (const float*)d_in[17];
  const float* zbp   = (const float*)d_in[18];
  float* out = (float*)d_out;

  hipFuncSetAttribute((const void*)gemm4p_bias, hipFuncAttributeMaxDynamicSharedMemorySize, G4_LDS);
  hipFuncSetAttribute((const void*)gemm4p_gcn,  hipFuncAttributeMaxDynamicSharedMemorySize, G4_LDS);
  hipFuncSetAttribute((const void*)gemm8p_zc,   hipFuncAttributeMaxDynamicSharedMemorySize, G8_LDS);

  const size_t MH = (size_t)M_PAD*HIDC;          // elements
  const size_t TFS = (size_t)TOKM*384;           // float2 elements
  // batched mode needs ~313MB of workspace; fall back to sequential otherwise
  const bool batched = ws_size >= ((size_t)340 << 20);

  char* wsb = (char*)d_ws;
  size_t off = 0;
  auto alloc = [&](size_t bytes)->void*{ void* p = wsb + off; off += (bytes + 255) & ~(size_t)255; return p; };
  u16* WORDB = (u16*)alloc(MH*2);
  u16* BUFB  = (u16*)alloc(MH*2*(batched?2:1));
  u16* BUFX  = (u16*)alloc(MH*2*(batched?2:1));
  u16* ZWALL = (u16*)alloc((size_t)2*ZNC*HIDC*2);
  u16* WT2   = (u16*)alloc((size_t)2*3*HIDC*HIDC*2);
  u16* PNWB  = (u16*)alloc((size_t)HIDC*HIDC*2);
  u16* PNB   = (u16*)alloc((size_t)128*M_PAD*2);
  u16* TOKALL= (u16*)alloc((size_t)3*TOKM*HIDC*2);
  float2* TOKF = (float2*)alloc(TFS*8*(batched?2:1));
  // ---- contiguous zero-init group (one memset) ----
  size_t zg0 = off;
  u32*   NEED = (u32*)alloc((size_t)N_NODESC*4);
  u32*   NEED1= (u32*)alloc((size_t)2*N_NODESC*4);
  float* DEG2 = (float*)alloc((size_t)2*N_NODESC*4);
  int*   CNT2 = (int*)alloc((size_t)2*N_NODESC*4);
  float* GT   = (float*)alloc((size_t)HIDC*128*4);
  size_t zg_bytes = off - zg0;
  // ------------------------------------------------
  float* DINVA = (float*)alloc((size_t)2*N_NODESC*4);
  float* DINVB = (float*)alloc((size_t)2*N_NODESC*4);
  int*   RP2  = (int*)alloc((size_t)2*NN1*4);
  int*   CUR2 = (int*)alloc((size_t)2*N_NODESC*4);
  int*   PART2= (int*)alloc((size_t)2*NBLK*4);
  float2* EMETA=(float2*)alloc((size_t)2*NEC*8);
  int*   TMAP = (int*)alloc((size_t)N_NODESC*4);
  int*   NXT  = (int*)alloc((size_t)TOKM*4);
  float* INVM = (float*)alloc((size_t)TOKM*4);
  (void)ws_size; (void)in_sizes; (void)n_in; (void)out_size;

  const int GD_TOK = (TOKM*384 + 255)/256;
  const int GD_E   = (NEC + 255)/256;
  const int SPMM_GD  = (N_NODESC + 3)/4;
  const int PN_NCHUNKS = M_PAD/PN_KCHUNK;               // 60
  const int G_PN  = (HIDC/128)*PN_NCHUNKS;              // 360
  const int G4_GCN = (M_PAD/128)*(HIDC/128);            // 1440
  const int G4_CBT = (HIDC/128)*(M_PAD/128);            // 1440
  const int G8_ZC  = (TOKM/256)*(ZNC/256);              // 288
  const int NCONVALL = HIDC*HIDC/2 + 2*(ZNC*HIDC/2) + 128*(M_PAD/2);

  // ---- prep ----
  hipMemsetAsync(wsb + zg0, 0, zg_bytes, stream);             // NEED,NEED1,DEG2,CNT2,GT
  hipMemsetAsync(TMAP, 0xFF, (size_t)N_NODESC*4, stream);
  hipMemsetAsync(TOKALL, 0, (size_t)2*TOKM*HIDC*2, stream);   // co/re segments (padding tokens stay 0)
  k_invmask<<<1,256,0,stream>>>(mask, INVM);
  k_needed<<<(TOKM+255)/256,256,0,stream>>>(ids, NEED, NEED1, TMAP, NXT);
  k_need_expand<<<dim3(GD_E,2),256,0,stream>>>(co_ei, re_ei, NEED, NEED1);
  k_convAll<<<(NCONVALL + 255)/256,256,0,stream>>>(pn_W, zw, zwp, png, PNWB, ZWALL, PNB);
  k_conv_pad<<<(M_PAD*384 + 255)/256,256,0,stream>>>(word, WORDB, N_NODESC, M_PAD);
  k_transposeW2<<<dim3((3*HIDC*384 + 255)/256, 2),256,0,stream>>>(co_W, re_W, WT2);

  // ---- batched CSR build ----
  k_degcnt2<<<dim3(GD_E,2),256,0,stream>>>(co_ei, re_ei, co_ew, re_ew, DEG2, CNT2);
  k_scan1<<<dim3(NBLK,2),256,0,stream>>>(CNT2, PART2, DEG2, DINVA, DINVB);
  k_scan2<<<2,128,0,stream>>>(PART2, RP2);
  k_scan3<<<dim3(NBLK,2),256,0,stream>>>(CNT2, PART2, RP2, CUR2);
  k_scatter2<<<dim3(GD_E,2),256,0,stream>>>(co_ei, re_ei, co_ew, re_ew, DINVA, CUR2, EMETA);

  // ---- pn path: cbT = pnW·word^T (+row bias), GT = cbT·pn^T (split-K), gather ----
  gemm4p_bias<<<G4_CBT,256,G4_LDS,stream>>>(PNWB, WORDB, HIDC, M_PAD, HIDC, BUFX, pn_b);
  gemm_splitk<<<G_PN,256,0,stream>>>(BUFX, PNB, HIDC, 128, M_PAD, GT, PN_KCHUNK);
  k_gather_pn<<<GD_TOK,256,0,stream>>>(GT, cids, TOKALL + (size_t)2*TOKM*HIDC);

  // ---- GCN stacks (graph-batched when workspace allows) ----
  // layer filters: L0 = none; L1 = NEED1; L2 = NEED. token writes fused in spmm.
  if(batched){
    for(int i=0;i<3;i++){
      gemm4p_gcn<<<dim3(G4_GCN,1,2),256,G4_LDS,stream>>>(
          (i==0)? WORDB : BUFX, (i==0)? 0 : MH, WT2, i, BUFB, MH, 0);
      k_spmm2<<<dim3(SPMM_GD,2),256,0,stream>>>(
          BUFB, MH, RP2, EMETA, DINVB, co_b, re_b, BUFX, MH,
          NEED, NEED1, TMAP, NXT, TOKF, TFS, TOKALL, i, 0);
    }
  } else {
    for(int g=0; g<2; ++g){
      const u16* X = WORDB;
      for(int i=0;i<3;i++){
        gemm4p_gcn<<<dim3(G4_GCN,1,1),256,G4_LDS,stream>>>(X, 0, WT2, i, BUFB, 0, g);
        k_spmm2<<<dim3(SPMM_GD,1),256,0,stream>>>(
            BUFB, 0, RP2, EMETA, DINVB, co_b, re_b, BUFX, 0,
            NEED, NEED1, TMAP, NXT, TOKF, 0, TOKALL, i, g);
        X = BUFX;
      }
    }
  }

  // ---- zero-convs -> outputs (zero column fused) ----
  dim3 zgrid(G8_ZC, 1, 3);
  gemm8p_zc<<<zgrid,512,G8_LDS,stream>>>(TOKALL, ZWALL, zb, zbp, INVM, out);
}